// Round 7
// baseline (2063.731 us; speedup 1.0000x reference)
//
#include <hip/hip_runtime.h>
#include <hip/hip_bf16.h>
#include <math.h>

#define L_   8
#define D_   768
#define H_   12
#define V_   32000
#define B_   2
#define S_   1024
#define HD_  64
#define BS_  2048      // B_*S_
#define DFF_ 3072      // MR*D

typedef __hip_bfloat16 bf16;
typedef __attribute__((ext_vector_type(8))) short bf16x8;
typedef __attribute__((ext_vector_type(4))) float f32x4;

#define CFUN(r) ((((r) & 3)) ^ (((r) >> 2) & 3))

__device__ __forceinline__ void cp16(void* lds, const void* g) {
  __builtin_amdgcn_global_load_lds(
      (const __attribute__((address_space(1))) void*)g,
      (__attribute__((address_space(3))) void*)lds, 16, 0, 0);
}

__device__ __forceinline__ unsigned short f2bf(float v) {
  __hip_bfloat16 h = __float2bfloat16(v);
  return *reinterpret_cast<unsigned short*>(&h);
}
__device__ __forceinline__ float bf2f(unsigned short u) {
  return __uint_as_float(((unsigned)u) << 16);
}

// ---------------------------------------------------------------- embedding
__global__ __launch_bounds__(256) void k_embed(const int* __restrict__ tokens,
    const float* __restrict__ tok_emb, const float* __restrict__ pos_emb,
    float* __restrict__ x) {
  int idx = blockIdx.x * 256 + threadIdx.x;
  int row = idx / D_;
  int d   = idx - row * D_;
  int s   = row & (S_ - 1);
  int t   = tokens[row];
  x[idx] = tok_emb[(size_t)t * D_ + d] + pos_emb[(size_t)s * D_ + d];
}

// ---------------------------------------------------------------- layernorm -> bf16
__global__ __launch_bounds__(256) void k_ln(const float* __restrict__ x,
    const float* __restrict__ g, const float* __restrict__ b,
    bf16* __restrict__ out) {
  int row = blockIdx.x;
  const float* xr = x + (size_t)row * D_;
  int t = threadIdx.x;
  float v0 = xr[t], v1 = xr[t + 256], v2 = xr[t + 512];
  float s  = v0 + v1 + v2;
  float s2 = v0 * v0 + v1 * v1 + v2 * v2;
#pragma unroll
  for (int off = 32; off; off >>= 1) {
    s  += __shfl_down(s, off);
    s2 += __shfl_down(s2, off);
  }
  __shared__ float rs[4], rs2[4];
  __shared__ float mean_s, rstd_s;
  int wid = t >> 6;
  if ((t & 63) == 0) { rs[wid] = s; rs2[wid] = s2; }
  __syncthreads();
  if (t == 0) {
    float S1 = rs[0] + rs[1] + rs[2] + rs[3];
    float S2 = rs2[0] + rs2[1] + rs2[2] + rs2[3];
    float m  = S1 / D_;
    float var = S2 / D_ - m * m;
    mean_s = m;
    rstd_s = rsqrtf(var + 1e-5f);
  }
  __syncthreads();
  float m = mean_s, r = rstd_s;
  bf16* orow = out + (size_t)row * D_;
  orow[t]       = __float2bfloat16((v0 - m) * r * g[t]       + b[t]);
  orow[t + 256] = __float2bfloat16((v1 - m) * r * g[t + 256] + b[t + 256]);
  orow[t + 512] = __float2bfloat16((v2 - m) * r * g[t + 512] + b[t + 512]);
}

// ------------------------------------------------- weight convert + transpose
__global__ __launch_bounds__(256) void k_w2bf_t(const float* __restrict__ W,
    bf16* __restrict__ Wt, int K, int N, size_t ils, size_t ols) {
  __shared__ float t[32][33];
  const float* Wm = W + (size_t)blockIdx.z * ils;
  bf16* Wtm = Wt + (size_t)blockIdx.z * ols;
  int n0 = blockIdx.x * 32, k0 = blockIdx.y * 32;
  int tx = threadIdx.x;
  for (int i = threadIdx.y; i < 32; i += 8)
    t[i][tx] = Wm[(size_t)(k0 + i) * N + n0 + tx];
  __syncthreads();
  for (int i = threadIdx.y; i < 32; i += 8)
    Wtm[(size_t)(n0 + i) * K + k0 + tx] = __float2bfloat16(t[tx][i]);
}

// ---------------------------------------------------------------- bias concat
__global__ __launch_bounds__(256) void k_bcat(const float* __restrict__ bq,
    const float* __restrict__ bk, const float* __restrict__ bqc,
    const float* __restrict__ bv, const float* __restrict__ bksh,
    const float* __restrict__ bvsh, float* __restrict__ b6) {
  int idx = blockIdx.x * 256 + threadIdx.x;
  if (idx >= L_ * 4608) return;
  int l = idx / 4608, c = idx - l * 4608;
  float v = (c < 768)  ? bq[l * 768 + c]
          : (c < 1536) ? bk[l * 768 + c - 768]
          : (c < 2304) ? bqc[l * 768 + c - 1536]
          : (c < 3072) ? bv[l * 768 + c - 2304]
          : (c < 3840) ? bksh[c - 3072]
                       : bvsh[c - 3840];
  b6[idx] = v;
}

// ---------------------------------------------------------------- bf16 MFMA GEMM
// C[M,N] = A[M,K](bf16) @ Wt[N,K](bf16)^T + bias. BMx128 tile, BK=32, 4 waves
// (2Mx2N; per-wave tile (BM/2)x64 -> MF=BM/32 fragment rows). 3-buffer
// circular LDS pipeline, depth-2 prefetch, counted vmcnt + raw s_barrier.
// 1-D grid, chunked XCD remap, m-fast decode.
template <int BM, int EPI>
__global__ __launch_bounds__(256) void k_bgemm(
    const bf16* __restrict__ A, const bf16* __restrict__ Wt,
    const float* __restrict__ bias, const float* __restrict__ resid,
    float* __restrict__ Cf, bf16* __restrict__ Cb, bf16* __restrict__ Cb2,
    bf16* __restrict__ Cb3, int NM, int M, int N, int K) {
  constexpr int ASZ = BM * 64;               // bytes per A sub-buffer
  constexpr int ALINES = BM / 64;            // cp16 lines for A per stage
  constexpr int BSTRIDE = ASZ + 8192;        // A + B per pipeline buffer
  constexpr int MF = BM / 32;
  __shared__ __align__(16) char smem[3 * BSTRIDE];
  const int tid = threadIdx.x;
  const int l = tid & 63, w = tid >> 6;
  const int wr = w >> 1, wc = w & 1;

  const int nwg = (int)gridDim.x;
  int id = (int)blockIdx.x;
  id = (id & 7) * (nwg >> 3) + (id >> 3);
  const int m0 = (id % NM) * BM;
  const int n0 = (id / NM) * 128;

  const int lane15 = l & 15, lg = l >> 4;

  const int r0 = tid >> 2, p0 = tid & 3;
  const char* aSrc[ALINES];
#pragma unroll
  for (int i = 0; i < ALINES; i++) {
    const int rr = i * 64 + r0;
    aSrc[i] = (const char*)(A + (size_t)(m0 + rr) * K) + ((p0 ^ CFUN(rr)) * 16);
  }
  const char* bSrc0 = (const char*)(Wt + (size_t)(n0 + r0) * K) + ((p0 ^ CFUN(r0)) * 16);
  const char* bSrc1 = (const char*)(Wt + (size_t)(n0 + 64 + r0) * K) + ((p0 ^ CFUN(64 + r0)) * 16);

  int aOff[MF], bOff[4];
#pragma unroll
  for (int mi = 0; mi < MF; mi++) {
    int r = wr * (BM / 2) + mi * 16 + lane15;
    aOff[mi] = r * 64 + ((lg ^ CFUN(r)) * 16);
  }
#pragma unroll
  for (int ni = 0; ni < 4; ni++) {
    int r = wc * 64 + ni * 16 + lane15;
    bOff[ni] = ASZ + r * 64 + ((lg ^ CFUN(r)) * 16);
  }

  f32x4 acc[MF][4];
#pragma unroll
  for (int mi = 0; mi < MF; mi++)
#pragma unroll
    for (int ni = 0; ni < 4; ni++) acc[mi][ni] = (f32x4){0.f, 0.f, 0.f, 0.f};

  auto stage = [&](int buf, int t) {
    const size_t kb = (size_t)t * 64;
    char* base = smem + buf * BSTRIDE;
#pragma unroll
    for (int i = 0; i < ALINES; i++)
      cp16(base + i * 4096 + w * 1024, aSrc[i] + kb);
    cp16(base + ASZ + w * 1024, bSrc0 + kb);
    cp16(base + ASZ + 4096 + w * 1024, bSrc1 + kb);
  };
  auto compute = [&](int buf) {
    const char* base = smem + buf * BSTRIDE;
    bf16x8 af[MF], bfr[4];
#pragma unroll
    for (int mi = 0; mi < MF; mi++) af[mi] = *(const bf16x8*)(base + aOff[mi]);
#pragma unroll
    for (int ni = 0; ni < 4; ni++) bfr[ni] = *(const bf16x8*)(base + bOff[ni]);
    __builtin_amdgcn_s_setprio(1);
#pragma unroll
    for (int mi = 0; mi < MF; mi++)
#pragma unroll
      for (int ni = 0; ni < 4; ni++)
        acc[mi][ni] = __builtin_amdgcn_mfma_f32_16x16x32_bf16(
            af[mi], bfr[ni], acc[mi][ni], 0, 0, 0);
    __builtin_amdgcn_s_setprio(0);
  };

  const int nk = K >> 5;                 // >= 3 always
  stage(0, 0);
  stage(1, 1);
  int buf = 0;
  for (int t = 0; t < nk; t++) {
    // wait for MY stage(t) loads; stage(t+1)'s stay in flight across barrier
    if (t + 1 < nk) {
      if constexpr (ALINES == 4)      asm volatile("s_waitcnt vmcnt(6)" ::: "memory");
      else if constexpr (ALINES == 2) asm volatile("s_waitcnt vmcnt(4)" ::: "memory");
      else                            asm volatile("s_waitcnt vmcnt(3)" ::: "memory");
    } else {
      asm volatile("s_waitcnt vmcnt(0)" ::: "memory");
    }
    __builtin_amdgcn_s_barrier();
    if (t + 2 < nk) {
      int nb = buf + 2; if (nb >= 3) nb -= 3;
      stage(nb, t + 2);
    }
    compute(buf);
    buf = (buf == 2) ? 0 : buf + 1;
  }

#pragma unroll
  for (int ni = 0; ni < 4; ni++) {
    const int col = n0 + wc * 64 + ni * 16 + lane15;
    const float bv = bias[col];
#pragma unroll
    for (int mi = 0; mi < MF; mi++) {
      const int rowb = m0 + wr * (BM / 2) + mi * 16 + lg * 4;
      if constexpr (EPI == 6) {
        if (col < 2304) {
#pragma unroll
          for (int j = 0; j < 4; j++)
            Cb[(size_t)(rowb + j) * 2304 + col] = __float2bfloat16(acc[mi][ni][j] + bv);
        } else if (col < 3072) {
          ushort4 pk;
          pk.x = f2bf(acc[mi][ni][0] + bv);
          pk.y = f2bf(acc[mi][ni][1] + bv);
          pk.z = f2bf(acc[mi][ni][2] + bv);
          pk.w = f2bf(acc[mi][ni][3] + bv);
          const int bq = rowb >> 10, s = rowb & (S_ - 1);
          *reinterpret_cast<ushort4*>(
              (unsigned short*)Cb2 + ((size_t)(bq * 768 + (col - 2304))) * S_ + s) = pk;
        } else {
#pragma unroll
          for (int j = 0; j < 4; j++)
            Cb3[(size_t)(rowb + j) * 1536 + (col - 3072)] =
                __float2bfloat16(acc[mi][ni][j] + bv);
        }
      } else {
#pragma unroll
        for (int j = 0; j < 4; j++) {
          const int row = rowb + j;
          float v = acc[mi][ni][j] + bv;
          if constexpr (EPI == 1) v += resid[(size_t)row * N + col];
          if constexpr (EPI == 2) {
            v = 0.5f * v * (1.0f + erff(v * 0.70710678118654752f));
            Cb[(size_t)row * N + col] = __float2bfloat16(v);
          } else if constexpr (EPI == 3) {
            Cb[(size_t)row * N + col] = __float2bfloat16(v);
          } else {
            Cf[(size_t)row * N + col] = v;
          }
        }
      }
    }
  }
}

// ---------------------------------------------------------------- flash attention
__global__ __launch_bounds__(256) void k_attn(
    const bf16* __restrict__ qkv, const bf16* __restrict__ vT,
    const bf16* __restrict__ memkv, bf16* __restrict__ ctx, int layer) {
  const int bh = blockIdx.x;
  const int b = bh / H_, h = bh % H_;
  const int qt = (int)gridDim.y - 1 - (int)blockIdx.y;   // big q first
  const int tid = threadIdx.x;
  const int w = tid >> 6, l = tid & 63;
  const int lane15 = l & 15, lg = l >> 4;
  const float inv = 0.125f;

  __shared__ char plds[4][2048];
  __shared__ float wlp[4][16][16];
  char* pl = plds[w];

  const int qrow0 = qt * 64 + w * 16;
  const size_t rowA = (size_t)(b * S_ + qrow0 + lane15);
  const bf16* qp = qkv + rowA * 2304 + h * 64 + lg * 8;
  const bf16x8 qf0 = *(const bf16x8*)(qp);
  const bf16x8 qf1 = *(const bf16x8*)(qp + 32);

  const bf16* kbase = qkv + (size_t)(b * S_) * 2304 + 768 + h * 64 + lg * 8;
  const bf16* vbase = vT + ((size_t)(b * 768 + h * 64 + lane15)) * S_;

  float mrow[4], dsum[4];
  f32x4 acc[4];
#pragma unroll
  for (int j = 0; j < 4; j++) { mrow[j] = -INFINITY; dsum[j] = 0.f; }
#pragma unroll
  for (int ni = 0; ni < 4; ni++) acc[ni] = (f32x4){0.f, 0.f, 0.f, 0.f};

  const int ntile = ((qrow0 + 15) >> 6) + 1;
  for (int kt64 = 0; kt64 < ntile; kt64++) {
    const int k0 = kt64 * 64;
    f32x4 sc[4];
#pragma unroll
    for (int kt = 0; kt < 4; kt++) {
      const bf16* kp = kbase + (size_t)(k0 + kt * 16 + lane15) * 2304;
      bf16x8 kf0 = *(const bf16x8*)(kp);
      bf16x8 kf1 = *(const bf16x8*)(kp + 32);
      f32x4 z = (f32x4){0.f, 0.f, 0.f, 0.f};
      z = __builtin_amdgcn_mfma_f32_16x16x32_bf16(qf0, kf0, z, 0, 0, 0);
      sc[kt] = __builtin_amdgcn_mfma_f32_16x16x32_bf16(qf1, kf1, z, 0, 0, 0);
    }
    float tmax[4];
#pragma unroll
    for (int j = 0; j < 4; j++) tmax[j] = -INFINITY;
#pragma unroll
    for (int kt = 0; kt < 4; kt++) {
      const int kabs = k0 + kt * 16 + lane15;
#pragma unroll
      for (int j = 0; j < 4; j++) {
        const int qabs = qrow0 + lg * 4 + j;
        float v = (kabs <= qabs) ? sc[kt][j] * inv : -INFINITY;
        sc[kt][j] = v;
        tmax[j] = fmaxf(tmax[j], v);
      }
    }
#pragma unroll
    for (int off = 1; off < 16; off <<= 1)
#pragma unroll
      for (int j = 0; j < 4; j++) tmax[j] = fmaxf(tmax[j], __shfl_xor(tmax[j], off, 16));

    float psum[4];
#pragma unroll
    for (int j = 0; j < 4; j++) {
      const float mnew = fmaxf(mrow[j], tmax[j]);
      const float alpha = __expf(mrow[j] - mnew);
      mrow[j] = mnew;
      dsum[j] *= alpha;
#pragma unroll
      for (int ni = 0; ni < 4; ni++) acc[ni][j] *= alpha;
      psum[j] = 0.f;
    }
#pragma unroll
    for (int kt = 0; kt < 4; kt++) {
      const int gsl = kt * 2 + (lane15 >> 3);
      const int ebyte = (lane15 & 7) * 2;
#pragma unroll
      for (int j = 0; j < 4; j++) {
        const float p = __expf(sc[kt][j] - mrow[j]);
        psum[j] += p;
        const int r = lg * 4 + j;
        *(unsigned short*)(pl + r * 128 + ((gsl ^ (r & 7)) << 4) + ebyte) = f2bf(p);
      }
    }
#pragma unroll
    for (int off = 1; off < 16; off <<= 1)
#pragma unroll
      for (int j = 0; j < 4; j++) psum[j] += __shfl_xor(psum[j], off, 16);
#pragma unroll
    for (int j = 0; j < 4; j++) dsum[j] += psum[j];

#pragma unroll
    for (int ks = 0; ks < 2; ks++) {
      bf16x8 pa = *(const bf16x8*)(pl + lane15 * 128 +
                                   ((((ks << 2) + lg) ^ (lane15 & 7)) << 4));
      const bf16* vp = vbase + k0 + ks * 32 + lg * 8;
#pragma unroll
      for (int ni = 0; ni < 4; ni++) {
        bf16x8 vf = *(const bf16x8*)(vp + (size_t)ni * 16 * S_);
        acc[ni] = __builtin_amdgcn_mfma_f32_16x16x32_bf16(pa, vf, acc[ni], 0, 0, 0);
      }
    }
  }

  const int r4 = lg * 4;
  if (lane15 < layer) {
    const int ml = lane15;
#pragma unroll
    for (int j = 0; j < 4; j++) {
      const size_t rowB = (size_t)(b * S_) + qrow0 + r4 + j;
      const bf16* qc = qkv + rowB * 2304 + 1536 + h * 64;
      const bf16* mk = memkv + ((size_t)ml * BS_ + rowB) * 1536 + h * 64;
      float d_ = 0.f;
#pragma unroll
      for (int t = 0; t < 8; t++) {
        bf16x8 qv = *(const bf16x8*)(qc + t * 8);
        bf16x8 kv = *(const bf16x8*)(mk + t * 8);
#pragma unroll
        for (int e = 0; e < 8; e++)
          d_ += bf2f((unsigned short)qv[e]) * bf2f((unsigned short)kv[e]);
      }
      wlp[w][r4 + j][ml] = d_ * inv;
    }
  }
  if (layer > 0) {
#pragma unroll
    for (int j = 0; j < 4; j++) {
      const int r = r4 + j;
      float mm = -INFINITY;
      for (int ml = 0; ml < layer; ml++) mm = fmaxf(mm, wlp[w][r][ml]);
      const float mnew = fmaxf(mrow[j], mm);
      const float alpha = __expf(mrow[j] - mnew);
      mrow[j] = mnew;
      dsum[j] *= alpha;
#pragma unroll
      for (int ni = 0; ni < 4; ni++) acc[ni][j] *= alpha;
      const size_t rowB = (size_t)(b * S_) + qrow0 + r;
      for (int ml = 0; ml < layer; ml++) {
        const float p = __expf(wlp[w][r][ml] - mnew);
        dsum[j] += p;
        const unsigned short* mv = (const unsigned short*)(memkv +
            ((size_t)ml * BS_ + rowB) * 1536 + 768 + h * 64 + lane15);
#pragma unroll
        for (int ni = 0; ni < 4; ni++)
          acc[ni][j] += p * bf2f(mv[ni * 16]);
      }
    }
  }

#pragma unroll
  for (int j = 0; j < 4; j++) {
    const float rd = 1.f / dsum[j];
    const size_t rowB = (size_t)(b * S_) + qrow0 + r4 + j;
    bf16* cp = ctx + rowB * 768 + h * 64 + lane15;
#pragma unroll
    for (int ni = 0; ni < 4; ni++)
      cp[ni * 16] = __float2bfloat16(acc[ni][j] * rd);
  }
}

// ---------------------------------------------------------------- launch
extern "C" void kernel_launch(void* const* d_in, const int* in_sizes, int n_in,
                              void* d_out, int out_size, void* d_ws, size_t ws_size,
                              hipStream_t stream) {
  const int*   tokens  = (const int*)d_in[0];
  const float* tok_emb = (const float*)d_in[1];
  const float* pos_emb = (const float*)d_in[2];
  const float *Wq_row, *Wk_row, *Wv_row, *Wq_col, *Wo;
  const float *bq_row, *bk_row, *bv_row, *bq_col, *bo;
  if (in_sizes[4] == L_ * D_ * D_) {  // dict order
    Wq_row = (const float*)d_in[3];  Wk_row = (const float*)d_in[4];
    Wv_row = (const float*)d_in[5];  Wq_col = (const float*)d_in[6];
    Wo     = (const float*)d_in[7];
    bq_row = (const float*)d_in[8];  bk_row = (const float*)d_in[9];
    bv_row = (const float*)d_in[10]; bq_col = (const float*)d_in[11];
    bo     = (const float*)d_in[12];
  } else {  // signature order fallback
    Wq_row = (const float*)d_in[3];  bq_row = (const float*)d_in[4];
    Wk_row = (const float*)d_in[5];  bk_row = (const float*)d_in[6];
    Wv_row = (const float*)d_in[7];  bv_row = (const float*)d_in[8];
    Wq_col = (const float*)d_in[9];  bq_col = (const float*)d_in[10];
    Wo     = (const float*)d_in[11]; bo     = (const float*)d_in[12];
  }
  const float* ln1_g = (const float*)d_in[13]; const float* ln1_b = (const float*)d_in[14];
  const float* ln2_g = (const float*)d_in[15]; const float* ln2_b = (const float*)d_in[16];
  const float* W1    = (const float*)d_in[17]; const float* b1    = (const float*)d_in[18];
  const float* W2    = (const float*)d_in[19]; const float* b2    = (const float*)d_in[20];
  const float* Wk_sh = (const float*)d_in[21]; const float* bk_sh = (const float*)d_in[22];
  const float* Wv_sh = (const float*)d_in[23]; const float* bv_sh = (const float*)d_in[24];
  const float* lnf_g = (const float*)d_in[25]; const float* lnf_b = (const float*)d_in[26];
  const float* Whead = (const float*)d_in[27]; const float* bhead = (const float*)d_in[28];

  // ---- workspace carve-up
  char* p = (char*)d_ws;
  float* x      = (float*)p; p += (size_t)BS_ * D_ * 4;
  bf16*  h_bf   = (bf16*)p;  p += (size_t)BS_ * D_ * 2;
  bf16*  qkv3   = (bf16*)p;  p += (size_t)BS_ * 2304 * 2;
  bf16*  vTb    = (bf16*)p;  p += (size_t)B_ * 768 * S_ * 2;
  bf16*  memkv  = (bf16*)p;  p += (size_t)L_ * BS_ * 1536 * 2;
  bf16*  ctx_bf = (bf16*)p;  p += (size_t)BS_ * D_ * 2;
  bf16*  mlp_bf = (bf16*)p;  p += (size_t)BS_ * DFF_ * 2;
  float* b6cat  = (float*)p; p += (size_t)L_ * 4608 * 4;
  bf16* tW6    = (bf16*)p; p += (size_t)L_ * 4608 * D_ * 2;   // q|k|qc|v|ksh|vsh
  bf16* tWo    = (bf16*)p; p += (size_t)L_ * D_ * D_ * 2;
  bf16* tW1    = (bf16*)p; p += (size_t)L_ * DFF_ * D_ * 2;
  bf16* tW2    = (bf16*)p; p += (size_t)L_ * D_ * DFF_ * 2;
  bf16* tWhead = (bf16*)p; p += (size_t)V_ * D_ * 2;

  // ---- weight conversion (transposed bf16), bias concat
  dim3 tb(32, 8);
  const size_t DD = (size_t)D_ * D_;
  const size_t W6S = (size_t)4608 * 768;
  k_w2bf_t<<<dim3(24, 24, L_), tb, 0, stream>>>(Wq_row, tW6,              768, 768, DD, W6S);
  k_w2bf_t<<<dim3(24, 24, L_), tb, 0, stream>>>(Wk_row, tW6 + 768 * 768,  768, 768, DD, W6S);
  k_w2bf_t<<<dim3(24, 24, L_), tb, 0, stream>>>(Wq_col, tW6 + 1536 * 768, 768, 768, DD, W6S);
  k_w2bf_t<<<dim3(24, 24, L_), tb, 0, stream>>>(Wv_row, tW6 + 2304 * 768, 768, 768, DD, W6S);
  k_w2bf_t<<<dim3(24, 24, L_), tb, 0, stream>>>(Wk_sh,  tW6 + 3072 * 768, 768, 768, 0, W6S);
  k_w2bf_t<<<dim3(24, 24, L_), tb, 0, stream>>>(Wv_sh,  tW6 + 3840 * 768, 768, 768, 0, W6S);
  k_w2bf_t<<<dim3(24, 24, L_), tb, 0, stream>>>(Wo,     tWo, 768, 768, DD, DD);
  k_w2bf_t<<<dim3(96, 24, L_), tb, 0, stream>>>(W1, tW1, 768, 3072, (size_t)768 * 3072, (size_t)3072 * 768);
  k_w2bf_t<<<dim3(24, 96, L_), tb, 0, stream>>>(W2, tW2, 3072, 768, (size_t)768 * 3072, (size_t)768 * 3072);
  k_w2bf_t<<<dim3(1000, 24, 1), tb, 0, stream>>>(Whead, tWhead, 768, 32000, 0, 0);
  k_bcat<<<dim3(144), 256, 0, stream>>>(bq_row, bk_row, bq_col, bv_row, bk_sh, bv_sh, b6cat);

  k_embed<<<dim3((BS_ * D_) / 256), 256, 0, stream>>>(tokens, tok_emb, pos_emb, x);

  for (int i = 0; i < L_; i++) {
    k_ln<<<dim3(BS_), 256, 0, stream>>>(x, ln1_g + i * D_, ln1_b + i * D_, h_bf);
    k_bgemm<256, 6><<<dim3(288), 256, 0, stream>>>(
        h_bf, tW6 + (size_t)i * W6S, b6cat + (size_t)i * 4608,
        nullptr, nullptr, qkv3, vTb, memkv + (size_t)i * BS_ * 1536,
        8, BS_, 4608, 768);
    k_attn<<<dim3(B_ * H_, S_ / 64), 256, 0, stream>>>(qkv3, vTb, memkv, ctx_bf, i);
    k_bgemm<64, 1><<<dim3(192), 256, 0, stream>>>(
        ctx_bf, tWo + (size_t)i * DD, bo + i * D_, x, x, nullptr, nullptr, nullptr,
        32, BS_, 768, 768);
    k_ln<<<dim3(BS_), 256, 0, stream>>>(x, ln2_g + i * D_, ln2_b + i * D_, h_bf);
    k_bgemm<256, 2><<<dim3(192), 256, 0, stream>>>(
        h_bf, tW1 + (size_t)i * 3072 * 768, b1 + (size_t)i * DFF_,
        nullptr, nullptr, mlp_bf, nullptr, nullptr, 8, BS_, 3072, 768);
    k_bgemm<64, 1><<<dim3(192), 256, 0, stream>>>(
        mlp_bf, tW2 + (size_t)i * 768 * 3072, b2 + i * D_, x, x, nullptr, nullptr,
        nullptr, 32, BS_, 768, 3072);
  }
  k_ln<<<dim3(BS_), 256, 0, stream>>>(x, lnf_g, lnf_b, h_bf);
  k_bgemm<256, 0><<<dim3(2000), 256, 0, stream>>>(
      h_bf, tWhead, bhead, nullptr, (float*)d_out, nullptr, nullptr, nullptr,
      8, BS_, V_, 768);
}

// Round 8
// 1875.897 us; speedup vs baseline: 1.1001x; 1.1001x over previous
//
#include <hip/hip_runtime.h>
#include <hip/hip_bf16.h>
#include <math.h>

#define L_   8
#define D_   768
#define H_   12
#define V_   32000
#define B_   2
#define S_   1024
#define HD_  64
#define BS_  2048      // B_*S_
#define DFF_ 3072      // MR*D

typedef __hip_bfloat16 bf16;
typedef __attribute__((ext_vector_type(8))) short bf16x8;
typedef __attribute__((ext_vector_type(4))) float f32x4;

// Balanced LDS slot swizzle: rows r..r+15 read by one lg-group hit each
// (row-parity, 16B-slot) cell exactly twice -> 2-way aliasing only (free).
#define CFUN(r) (((r) >> 1) & 3)

__device__ __forceinline__ void cp16(void* lds, const void* g) {
  __builtin_amdgcn_global_load_lds(
      (const __attribute__((address_space(1))) void*)g,
      (__attribute__((address_space(3))) void*)lds, 16, 0, 0);
}

__device__ __forceinline__ unsigned short f2bf(float v) {
  __hip_bfloat16 h = __float2bfloat16(v);
  return *reinterpret_cast<unsigned short*>(&h);
}
__device__ __forceinline__ float bf2f(unsigned short u) {
  return __uint_as_float(((unsigned)u) << 16);
}

// ---------------------------------------------------------------- embedding
__global__ __launch_bounds__(256) void k_embed(const int* __restrict__ tokens,
    const float* __restrict__ tok_emb, const float* __restrict__ pos_emb,
    float* __restrict__ x) {
  int idx = blockIdx.x * 256 + threadIdx.x;
  int row = idx / D_;
  int d   = idx - row * D_;
  int s   = row & (S_ - 1);
  int t   = tokens[row];
  x[idx] = tok_emb[(size_t)t * D_ + d] + pos_emb[(size_t)s * D_ + d];
}

// ---------------------------------------------------------------- layernorm -> bf16
__global__ __launch_bounds__(256) void k_ln(const float* __restrict__ x,
    const float* __restrict__ g, const float* __restrict__ b,
    bf16* __restrict__ out) {
  int row = blockIdx.x;
  const float* xr = x + (size_t)row * D_;
  int t = threadIdx.x;
  float v0 = xr[t], v1 = xr[t + 256], v2 = xr[t + 512];
  float s  = v0 + v1 + v2;
  float s2 = v0 * v0 + v1 * v1 + v2 * v2;
#pragma unroll
  for (int off = 32; off; off >>= 1) {
    s  += __shfl_down(s, off);
    s2 += __shfl_down(s2, off);
  }
  __shared__ float rs[4], rs2[4];
  __shared__ float mean_s, rstd_s;
  int wid = t >> 6;
  if ((t & 63) == 0) { rs[wid] = s; rs2[wid] = s2; }
  __syncthreads();
  if (t == 0) {
    float S1 = rs[0] + rs[1] + rs[2] + rs[3];
    float S2 = rs2[0] + rs2[1] + rs2[2] + rs2[3];
    float m  = S1 / D_;
    float var = S2 / D_ - m * m;
    mean_s = m;
    rstd_s = rsqrtf(var + 1e-5f);
  }
  __syncthreads();
  float m = mean_s, r = rstd_s;
  bf16* orow = out + (size_t)row * D_;
  orow[t]       = __float2bfloat16((v0 - m) * r * g[t]       + b[t]);
  orow[t + 256] = __float2bfloat16((v1 - m) * r * g[t + 256] + b[t + 256]);
  orow[t + 512] = __float2bfloat16((v2 - m) * r * g[t + 512] + b[t + 512]);
}

// ------------------------------------------------- weight convert + transpose
__global__ __launch_bounds__(256) void k_w2bf_t(const float* __restrict__ W,
    bf16* __restrict__ Wt, int K, int N, size_t ils, size_t ols) {
  __shared__ float t[32][33];
  const float* Wm = W + (size_t)blockIdx.z * ils;
  bf16* Wtm = Wt + (size_t)blockIdx.z * ols;
  int n0 = blockIdx.x * 32, k0 = blockIdx.y * 32;
  int tx = threadIdx.x;
  for (int i = threadIdx.y; i < 32; i += 8)
    t[i][tx] = Wm[(size_t)(k0 + i) * N + n0 + tx];
  __syncthreads();
  for (int i = threadIdx.y; i < 32; i += 8)
    Wtm[(size_t)(n0 + i) * K + k0 + tx] = __float2bfloat16(t[tx][i]);
}

// ---------------------------------------------------------------- bias concat
__global__ __launch_bounds__(256) void k_bcat(const float* __restrict__ bq,
    const float* __restrict__ bk, const float* __restrict__ bqc,
    const float* __restrict__ bv, const float* __restrict__ bksh,
    const float* __restrict__ bvsh, float* __restrict__ b6) {
  int idx = blockIdx.x * 256 + threadIdx.x;
  if (idx >= L_ * 4608) return;
  int l = idx / 4608, c = idx - l * 4608;
  float v = (c < 768)  ? bq[l * 768 + c]
          : (c < 1536) ? bk[l * 768 + c - 768]
          : (c < 2304) ? bqc[l * 768 + c - 1536]
          : (c < 3072) ? bv[l * 768 + c - 2304]
          : (c < 3840) ? bksh[c - 3072]
                       : bvsh[c - 3840];
  b6[idx] = v;
}

// ---------------------------------------------------------------- bf16 MFMA GEMM
// C[M,N] = A[M,K](bf16) @ Wt[N,K](bf16)^T + bias. BMx128 tile, BK=32, 4 waves.
// 3-buffer circular LDS pipeline, depth-2 prefetch, counted vmcnt + raw
// s_barrier. 1-D grid, chunked XCD remap, m-fast decode.
template <int BM, int EPI>
__global__ __launch_bounds__(256) void k_bgemm(
    const bf16* __restrict__ A, const bf16* __restrict__ Wt,
    const float* __restrict__ bias, const float* __restrict__ resid,
    float* __restrict__ Cf, bf16* __restrict__ Cb, bf16* __restrict__ Cb2,
    bf16* __restrict__ Cb3, int NM, int M, int N, int K) {
  constexpr int ASZ = BM * 64;               // bytes per A sub-buffer
  constexpr int ALINES = BM / 64;            // cp16 lines for A per stage
  constexpr int BSTRIDE = ASZ + 8192;        // A + B per pipeline buffer
  constexpr int MF = BM / 32;
  __shared__ __align__(16) char smem[3 * BSTRIDE];
  const int tid = threadIdx.x;
  const int l = tid & 63, w = tid >> 6;
  const int wr = w >> 1, wc = w & 1;

  const int nwg = (int)gridDim.x;
  int id = (int)blockIdx.x;
  id = (id & 7) * (nwg >> 3) + (id >> 3);
  const int m0 = (id % NM) * BM;
  const int n0 = (id / NM) * 128;

  const int lane15 = l & 15, lg = l >> 4;

  const int r0 = tid >> 2, p0 = tid & 3;
  const char* aSrc[ALINES];
#pragma unroll
  for (int i = 0; i < ALINES; i++) {
    const int rr = i * 64 + r0;
    aSrc[i] = (const char*)(A + (size_t)(m0 + rr) * K) + ((p0 ^ CFUN(rr)) * 16);
  }
  const char* bSrc0 = (const char*)(Wt + (size_t)(n0 + r0) * K) + ((p0 ^ CFUN(r0)) * 16);
  const char* bSrc1 = (const char*)(Wt + (size_t)(n0 + 64 + r0) * K) + ((p0 ^ CFUN(64 + r0)) * 16);

  int aOff[MF], bOff[4];
#pragma unroll
  for (int mi = 0; mi < MF; mi++) {
    int r = wr * (BM / 2) + mi * 16 + lane15;
    aOff[mi] = r * 64 + ((lg ^ CFUN(r)) * 16);
  }
#pragma unroll
  for (int ni = 0; ni < 4; ni++) {
    int r = wc * 64 + ni * 16 + lane15;
    bOff[ni] = ASZ + r * 64 + ((lg ^ CFUN(r)) * 16);
  }

  f32x4 acc[MF][4];
#pragma unroll
  for (int mi = 0; mi < MF; mi++)
#pragma unroll
    for (int ni = 0; ni < 4; ni++) acc[mi][ni] = (f32x4){0.f, 0.f, 0.f, 0.f};

  auto stage = [&](int buf, int t) {
    const size_t kb = (size_t)t * 64;
    char* base = smem + buf * BSTRIDE;
#pragma unroll
    for (int i = 0; i < ALINES; i++)
      cp16(base + i * 4096 + w * 1024, aSrc[i] + kb);
    cp16(base + ASZ + w * 1024, bSrc0 + kb);
    cp16(base + ASZ + 4096 + w * 1024, bSrc1 + kb);
  };
  auto compute = [&](int buf) {
    const char* base = smem + buf * BSTRIDE;
    bf16x8 af[MF], bfr[4];
#pragma unroll
    for (int mi = 0; mi < MF; mi++) af[mi] = *(const bf16x8*)(base + aOff[mi]);
#pragma unroll
    for (int ni = 0; ni < 4; ni++) bfr[ni] = *(const bf16x8*)(base + bOff[ni]);
    __builtin_amdgcn_s_setprio(1);
#pragma unroll
    for (int mi = 0; mi < MF; mi++)
#pragma unroll
      for (int ni = 0; ni < 4; ni++)
        acc[mi][ni] = __builtin_amdgcn_mfma_f32_16x16x32_bf16(
            af[mi], bfr[ni], acc[mi][ni], 0, 0, 0);
    __builtin_amdgcn_s_setprio(0);
  };

  const int nk = K >> 5;                 // >= 3 always
  stage(0, 0);
  stage(1, 1);
  int buf = 0;
  for (int t = 0; t < nk; t++) {
    if (t + 1 < nk) {
      if constexpr (ALINES == 2) asm volatile("s_waitcnt vmcnt(4)" ::: "memory");
      else                       asm volatile("s_waitcnt vmcnt(3)" ::: "memory");
    } else {
      asm volatile("s_waitcnt vmcnt(0)" ::: "memory");
    }
    __builtin_amdgcn_s_barrier();
    if (t + 2 < nk) {
      int nb = buf + 2; if (nb >= 3) nb -= 3;
      stage(nb, t + 2);
    }
    compute(buf);
    buf = (buf == 2) ? 0 : buf + 1;
  }

#pragma unroll
  for (int ni = 0; ni < 4; ni++) {
    const int col = n0 + wc * 64 + ni * 16 + lane15;
    const float bv = bias[col];
#pragma unroll
    for (int mi = 0; mi < MF; mi++) {
      const int rowb = m0 + wr * (BM / 2) + mi * 16 + lg * 4;
      if constexpr (EPI == 6) {
        if (col < 2304) {
#pragma unroll
          for (int j = 0; j < 4; j++)
            Cb[(size_t)(rowb + j) * 2304 + col] = __float2bfloat16(acc[mi][ni][j] + bv);
        } else if (col < 3072) {
          ushort4 pk;
          pk.x = f2bf(acc[mi][ni][0] + bv);
          pk.y = f2bf(acc[mi][ni][1] + bv);
          pk.z = f2bf(acc[mi][ni][2] + bv);
          pk.w = f2bf(acc[mi][ni][3] + bv);
          const int bq = rowb >> 10, s = rowb & (S_ - 1);
          *reinterpret_cast<ushort4*>(
              (unsigned short*)Cb2 + ((size_t)(bq * 768 + (col - 2304))) * S_ + s) = pk;
        } else {
#pragma unroll
          for (int j = 0; j < 4; j++)
            Cb3[(size_t)(rowb + j) * 1536 + (col - 3072)] =
                __float2bfloat16(acc[mi][ni][j] + bv);
        }
      } else {
#pragma unroll
        for (int j = 0; j < 4; j++) {
          const int row = rowb + j;
          float v = acc[mi][ni][j] + bv;
          if constexpr (EPI == 1) v += resid[(size_t)row * N + col];
          if constexpr (EPI == 2) {
            v = 0.5f * v * (1.0f + erff(v * 0.70710678118654752f));
            Cb[(size_t)row * N + col] = __float2bfloat16(v);
          } else if constexpr (EPI == 3) {
            Cb[(size_t)row * N + col] = __float2bfloat16(v);
          } else {
            Cf[(size_t)row * N + col] = v;
          }
        }
      }
    }
  }
}

// ---------------------------------------------------------------- flash attention
__global__ __launch_bounds__(256) void k_attn(
    const bf16* __restrict__ qkv, const bf16* __restrict__ vT,
    const bf16* __restrict__ memkv, bf16* __restrict__ ctx, int layer) {
  const int bh = blockIdx.x;
  const int b = bh / H_, h = bh % H_;
  const int qt = (int)gridDim.y - 1 - (int)blockIdx.y;   // big q first
  const int tid = threadIdx.x;
  const int w = tid >> 6, l = tid & 63;
  const int lane15 = l & 15, lg = l >> 4;
  const float inv = 0.125f;

  __shared__ char plds[4][2048];
  __shared__ float wlp[4][16][16];
  char* pl = plds[w];

  const int qrow0 = qt * 64 + w * 16;
  const size_t rowA = (size_t)(b * S_ + qrow0 + lane15);
  const bf16* qp = qkv + rowA * 2304 + h * 64 + lg * 8;
  const bf16x8 qf0 = *(const bf16x8*)(qp);
  const bf16x8 qf1 = *(const bf16x8*)(qp + 32);

  const bf16* kbase = qkv + (size_t)(b * S_) * 2304 + 768 + h * 64 + lg * 8;
  const bf16* vbase = vT + ((size_t)(b * 768 + h * 64 + lane15)) * S_;

  float mrow[4], dsum[4];
  f32x4 acc[4];
#pragma unroll
  for (int j = 0; j < 4; j++) { mrow[j] = -INFINITY; dsum[j] = 0.f; }
#pragma unroll
  for (int ni = 0; ni < 4; ni++) acc[ni] = (f32x4){0.f, 0.f, 0.f, 0.f};

  const int ntile = ((qrow0 + 15) >> 6) + 1;
  for (int kt64 = 0; kt64 < ntile; kt64++) {
    const int k0 = kt64 * 64;
    f32x4 sc[4];
#pragma unroll
    for (int kt = 0; kt < 4; kt++) {
      const bf16* kp = kbase + (size_t)(k0 + kt * 16 + lane15) * 2304;
      bf16x8 kf0 = *(const bf16x8*)(kp);
      bf16x8 kf1 = *(const bf16x8*)(kp + 32);
      f32x4 z = (f32x4){0.f, 0.f, 0.f, 0.f};
      z = __builtin_amdgcn_mfma_f32_16x16x32_bf16(qf0, kf0, z, 0, 0, 0);
      sc[kt] = __builtin_amdgcn_mfma_f32_16x16x32_bf16(qf1, kf1, z, 0, 0, 0);
    }
    float tmax[4];
#pragma unroll
    for (int j = 0; j < 4; j++) tmax[j] = -INFINITY;
#pragma unroll
    for (int kt = 0; kt < 4; kt++) {
      const int kabs = k0 + kt * 16 + lane15;
#pragma unroll
      for (int j = 0; j < 4; j++) {
        const int qabs = qrow0 + lg * 4 + j;
        float v = (kabs <= qabs) ? sc[kt][j] * inv : -INFINITY;
        sc[kt][j] = v;
        tmax[j] = fmaxf(tmax[j], v);
      }
    }
#pragma unroll
    for (int off = 1; off < 16; off <<= 1)
#pragma unroll
      for (int j = 0; j < 4; j++) tmax[j] = fmaxf(tmax[j], __shfl_xor(tmax[j], off, 16));

    float psum[4];
#pragma unroll
    for (int j = 0; j < 4; j++) {
      const float mnew = fmaxf(mrow[j], tmax[j]);
      const float alpha = __expf(mrow[j] - mnew);
      mrow[j] = mnew;
      dsum[j] *= alpha;
#pragma unroll
      for (int ni = 0; ni < 4; ni++) acc[ni][j] *= alpha;
      psum[j] = 0.f;
    }
#pragma unroll
    for (int kt = 0; kt < 4; kt++) {
      const int gsl = kt * 2 + (lane15 >> 3);
      const int ebyte = (lane15 & 7) * 2;
#pragma unroll
      for (int j = 0; j < 4; j++) {
        const float p = __expf(sc[kt][j] - mrow[j]);
        psum[j] += p;
        const int r = lg * 4 + j;
        *(unsigned short*)(pl + r * 128 + ((gsl ^ (r & 7)) << 4) + ebyte) = f2bf(p);
      }
    }
#pragma unroll
    for (int off = 1; off < 16; off <<= 1)
#pragma unroll
      for (int j = 0; j < 4; j++) psum[j] += __shfl_xor(psum[j], off, 16);
#pragma unroll
    for (int j = 0; j < 4; j++) dsum[j] += psum[j];

#pragma unroll
    for (int ks = 0; ks < 2; ks++) {
      bf16x8 pa = *(const bf16x8*)(pl + lane15 * 128 +
                                   ((((ks << 2) + lg) ^ (lane15 & 7)) << 4));
      const bf16* vp = vbase + k0 + ks * 32 + lg * 8;
#pragma unroll
      for (int ni = 0; ni < 4; ni++) {
        bf16x8 vf = *(const bf16x8*)(vp + (size_t)ni * 16 * S_);
        acc[ni] = __builtin_amdgcn_mfma_f32_16x16x32_bf16(pa, vf, acc[ni], 0, 0, 0);
      }
    }
  }

  const int r4 = lg * 4;
  if (lane15 < layer) {
    const int ml = lane15;
#pragma unroll
    for (int j = 0; j < 4; j++) {
      const size_t rowB = (size_t)(b * S_) + qrow0 + r4 + j;
      const bf16* qc = qkv + rowB * 2304 + 1536 + h * 64;
      const bf16* mk = memkv + ((size_t)ml * BS_ + rowB) * 1536 + h * 64;
      float d_ = 0.f;
#pragma unroll
      for (int t = 0; t < 8; t++) {
        bf16x8 qv = *(const bf16x8*)(qc + t * 8);
        bf16x8 kv = *(const bf16x8*)(mk + t * 8);
#pragma unroll
        for (int e = 0; e < 8; e++)
          d_ += bf2f((unsigned short)qv[e]) * bf2f((unsigned short)kv[e]);
      }
      wlp[w][r4 + j][ml] = d_ * inv;
    }
  }
  if (layer > 0) {
#pragma unroll
    for (int j = 0; j < 4; j++) {
      const int r = r4 + j;
      float mm = -INFINITY;
      for (int ml = 0; ml < layer; ml++) mm = fmaxf(mm, wlp[w][r][ml]);
      const float mnew = fmaxf(mrow[j], mm);
      const float alpha = __expf(mrow[j] - mnew);
      mrow[j] = mnew;
      dsum[j] *= alpha;
#pragma unroll
      for (int ni = 0; ni < 4; ni++) acc[ni][j] *= alpha;
      const size_t rowB = (size_t)(b * S_) + qrow0 + r;
      for (int ml = 0; ml < layer; ml++) {
        const float p = __expf(wlp[w][r][ml] - mnew);
        dsum[j] += p;
        const unsigned short* mv = (const unsigned short*)(memkv +
            ((size_t)ml * BS_ + rowB) * 1536 + 768 + h * 64 + lane15);
#pragma unroll
        for (int ni = 0; ni < 4; ni++)
          acc[ni][j] += p * bf2f(mv[ni * 16]);
      }
    }
  }

#pragma unroll
  for (int j = 0; j < 4; j++) {
    const float rd = 1.f / dsum[j];
    const size_t rowB = (size_t)(b * S_) + qrow0 + r4 + j;
    bf16* cp = ctx + rowB * 768 + h * 64 + lane15;
#pragma unroll
    for (int ni = 0; ni < 4; ni++)
      cp[ni * 16] = __float2bfloat16(acc[ni][j] * rd);
  }
}

// ---------------------------------------------------------------- launch
extern "C" void kernel_launch(void* const* d_in, const int* in_sizes, int n_in,
                              void* d_out, int out_size, void* d_ws, size_t ws_size,
                              hipStream_t stream) {
  const int*   tokens  = (const int*)d_in[0];
  const float* tok_emb = (const float*)d_in[1];
  const float* pos_emb = (const float*)d_in[2];
  const float *Wq_row, *Wk_row, *Wv_row, *Wq_col, *Wo;
  const float *bq_row, *bk_row, *bv_row, *bq_col, *bo;
  if (in_sizes[4] == L_ * D_ * D_) {  // dict order
    Wq_row = (const float*)d_in[3];  Wk_row = (const float*)d_in[4];
    Wv_row = (const float*)d_in[5];  Wq_col = (const float*)d_in[6];
    Wo     = (const float*)d_in[7];
    bq_row = (const float*)d_in[8];  bk_row = (const float*)d_in[9];
    bv_row = (const float*)d_in[10]; bq_col = (const float*)d_in[11];
    bo     = (const float*)d_in[12];
  } else {  // signature order fallback
    Wq_row = (const float*)d_in[3];  bq_row = (const float*)d_in[4];
    Wk_row = (const float*)d_in[5];  bk_row = (const float*)d_in[6];
    Wv_row = (const float*)d_in[7];  bv_row = (const float*)d_in[8];
    Wq_col = (const float*)d_in[9];  bq_col = (const float*)d_in[10];
    Wo     = (const float*)d_in[11]; bo     = (const float*)d_in[12];
  }
  const float* ln1_g = (const float*)d_in[13]; const float* ln1_b = (const float*)d_in[14];
  const float* ln2_g = (const float*)d_in[15]; const float* ln2_b = (const float*)d_in[16];
  const float* W1    = (const float*)d_in[17]; const float* b1    = (const float*)d_in[18];
  const float* W2    = (const float*)d_in[19]; const float* b2    = (const float*)d_in[20];
  const float* Wk_sh = (const float*)d_in[21]; const float* bk_sh = (const float*)d_in[22];
  const float* Wv_sh = (const float*)d_in[23]; const float* bv_sh = (const float*)d_in[24];
  const float* lnf_g = (const float*)d_in[25]; const float* lnf_b = (const float*)d_in[26];
  const float* Whead = (const float*)d_in[27]; const float* bhead = (const float*)d_in[28];

  // ---- workspace carve-up
  char* p = (char*)d_ws;
  float* x      = (float*)p; p += (size_t)BS_ * D_ * 4;
  bf16*  h_bf   = (bf16*)p;  p += (size_t)BS_ * D_ * 2;
  bf16*  qkv3   = (bf16*)p;  p += (size_t)BS_ * 2304 * 2;
  bf16*  vTb    = (bf16*)p;  p += (size_t)B_ * 768 * S_ * 2;
  bf16*  memkv  = (bf16*)p;  p += (size_t)L_ * BS_ * 1536 * 2;
  bf16*  ctx_bf = (bf16*)p;  p += (size_t)BS_ * D_ * 2;
  bf16*  mlp_bf = (bf16*)p;  p += (size_t)BS_ * DFF_ * 2;
  float* b6cat  = (float*)p; p += (size_t)L_ * 4608 * 4;
  bf16* tW6    = (bf16*)p; p += (size_t)L_ * 4608 * D_ * 2;   // q|k|qc|v|ksh|vsh
  bf16* tWo    = (bf16*)p; p += (size_t)L_ * D_ * D_ * 2;
  bf16* tW1    = (bf16*)p; p += (size_t)L_ * DFF_ * D_ * 2;
  bf16* tW2    = (bf16*)p; p += (size_t)L_ * D_ * DFF_ * 2;
  bf16* tWhead = (bf16*)p; p += (size_t)V_ * D_ * 2;

  // ---- weight conversion (transposed bf16), bias concat
  dim3 tb(32, 8);
  const size_t DD = (size_t)D_ * D_;
  const size_t W6S = (size_t)4608 * 768;
  k_w2bf_t<<<dim3(24, 24, L_), tb, 0, stream>>>(Wq_row, tW6,              768, 768, DD, W6S);
  k_w2bf_t<<<dim3(24, 24, L_), tb, 0, stream>>>(Wk_row, tW6 + 768 * 768,  768, 768, DD, W6S);
  k_w2bf_t<<<dim3(24, 24, L_), tb, 0, stream>>>(Wq_col, tW6 + 1536 * 768, 768, 768, DD, W6S);
  k_w2bf_t<<<dim3(24, 24, L_), tb, 0, stream>>>(Wv_row, tW6 + 2304 * 768, 768, 768, DD, W6S);
  k_w2bf_t<<<dim3(24, 24, L_), tb, 0, stream>>>(Wk_sh,  tW6 + 3072 * 768, 768, 768, 0, W6S);
  k_w2bf_t<<<dim3(24, 24, L_), tb, 0, stream>>>(Wv_sh,  tW6 + 3840 * 768, 768, 768, 0, W6S);
  k_w2bf_t<<<dim3(24, 24, L_), tb, 0, stream>>>(Wo,     tWo, 768, 768, DD, DD);
  k_w2bf_t<<<dim3(96, 24, L_), tb, 0, stream>>>(W1, tW1, 768, 3072, (size_t)768 * 3072, (size_t)3072 * 768);
  k_w2bf_t<<<dim3(24, 96, L_), tb, 0, stream>>>(W2, tW2, 3072, 768, (size_t)768 * 3072, (size_t)768 * 3072);
  k_w2bf_t<<<dim3(1000, 24, 1), tb, 0, stream>>>(Whead, tWhead, 768, 32000, 0, 0);
  k_bcat<<<dim3(144), 256, 0, stream>>>(bq_row, bk_row, bq_col, bv_row, bk_sh, bv_sh, b6cat);

  k_embed<<<dim3((BS_ * D_) / 256), 256, 0, stream>>>(tokens, tok_emb, pos_emb, x);

  for (int i = 0; i < L_; i++) {
    k_ln<<<dim3(BS_), 256, 0, stream>>>(x, ln1_g + i * D_, ln1_b + i * D_, h_bf);
    k_bgemm<128, 6><<<dim3(576), 256, 0, stream>>>(
        h_bf, tW6 + (size_t)i * W6S, b6cat + (size_t)i * 4608,
        nullptr, nullptr, qkv3, vTb, memkv + (size_t)i * BS_ * 1536,
        16, BS_, 4608, 768);
    k_attn<<<dim3(B_ * H_, S_ / 64), 256, 0, stream>>>(qkv3, vTb, memkv, ctx_bf, i);
    k_bgemm<64, 1><<<dim3(192), 256, 0, stream>>>(
        ctx_bf, tWo + (size_t)i * DD, bo + i * D_, x, x, nullptr, nullptr, nullptr,
        32, BS_, 768, 768);
    k_ln<<<dim3(BS_), 256, 0, stream>>>(x, ln2_g + i * D_, ln2_b + i * D_, h_bf);
    k_bgemm<128, 2><<<dim3(384), 256, 0, stream>>>(
        h_bf, tW1 + (size_t)i * 3072 * 768, b1 + (size_t)i * DFF_,
        nullptr, nullptr, mlp_bf, nullptr, nullptr, 16, BS_, 3072, 768);
    k_bgemm<64, 1><<<dim3(192), 256, 0, stream>>>(
        mlp_bf, tW2 + (size_t)i * 768 * 3072, b2 + i * D_, x, x, nullptr, nullptr,
        nullptr, 32, BS_, 768, 3072);
  }
  k_ln<<<dim3(BS_), 256, 0, stream>>>(x, lnf_g, lnf_b, h_bf);
  k_bgemm<128, 0><<<dim3(4000), 256, 0, stream>>>(
      h_bf, tWhead, bhead, nullptr, (float*)d_out, nullptr, nullptr, nullptr,
      16, BS_, V_, 768);
}

// Round 10
// 1843.517 us; speedup vs baseline: 1.1195x; 1.0176x over previous
//
#include <hip/hip_runtime.h>
#include <hip/hip_bf16.h>
#include <math.h>

#define L_   8
#define D_   768
#define H_   12
#define V_   32000
#define B_   2
#define S_   1024
#define HD_  64
#define BS_  2048      // B_*S_
#define DFF_ 3072      // MR*D

typedef __hip_bfloat16 bf16;
typedef __attribute__((ext_vector_type(8))) short bf16x8;
typedef __attribute__((ext_vector_type(4))) float f32x4;

// Balanced LDS slot swizzle for the 128x128 k_bgemm (BK=32, 4-slot rows)
#define CFUN(r) (((r) >> 1) & 3)

__device__ __forceinline__ void cp16(void* lds, const void* g) {
  __builtin_amdgcn_global_load_lds(
      (const __attribute__((address_space(1))) void*)g,
      (__attribute__((address_space(3))) void*)lds, 16, 0, 0);
}

__device__ __forceinline__ unsigned short f2bf(float v) {
  __hip_bfloat16 h = __float2bfloat16(v);
  return *reinterpret_cast<unsigned short*>(&h);
}
__device__ __forceinline__ float bf2f(unsigned short u) {
  return __uint_as_float(((unsigned)u) << 16);
}

// ---------------------------------------------------------------- embedding
__global__ __launch_bounds__(256) void k_embed(const int* __restrict__ tokens,
    const float* __restrict__ tok_emb, const float* __restrict__ pos_emb,
    float* __restrict__ x) {
  int idx = blockIdx.x * 256 + threadIdx.x;
  int row = idx / D_;
  int d   = idx - row * D_;
  int s   = row & (S_ - 1);
  int t   = tokens[row];
  x[idx] = tok_emb[(size_t)t * D_ + d] + pos_emb[(size_t)s * D_ + d];
}

// ---------------------------------------------------------------- layernorm -> bf16
__global__ __launch_bounds__(256) void k_ln(const float* __restrict__ x,
    const float* __restrict__ g, const float* __restrict__ b,
    bf16* __restrict__ out) {
  int row = blockIdx.x;
  const float* xr = x + (size_t)row * D_;
  int t = threadIdx.x;
  float v0 = xr[t], v1 = xr[t + 256], v2 = xr[t + 512];
  float s  = v0 + v1 + v2;
  float s2 = v0 * v0 + v1 * v1 + v2 * v2;
#pragma unroll
  for (int off = 32; off; off >>= 1) {
    s  += __shfl_down(s, off);
    s2 += __shfl_down(s2, off);
  }
  __shared__ float rs[4], rs2[4];
  __shared__ float mean_s, rstd_s;
  int wid = t >> 6;
  if ((t & 63) == 0) { rs[wid] = s; rs2[wid] = s2; }
  __syncthreads();
  if (t == 0) {
    float S1 = rs[0] + rs[1] + rs[2] + rs[3];
    float S2 = rs2[0] + rs2[1] + rs2[2] + rs2[3];
    float m  = S1 / D_;
    float var = S2 / D_ - m * m;
    mean_s = m;
    rstd_s = rsqrtf(var + 1e-5f);
  }
  __syncthreads();
  float m = mean_s, r = rstd_s;
  bf16* orow = out + (size_t)row * D_;
  orow[t]       = __float2bfloat16((v0 - m) * r * g[t]       + b[t]);
  orow[t + 256] = __float2bfloat16((v1 - m) * r * g[t + 256] + b[t + 256]);
  orow[t + 512] = __float2bfloat16((v2 - m) * r * g[t + 512] + b[t + 512]);
}

// ------------------------------------------------- weight convert + transpose
__global__ __launch_bounds__(256) void k_w2bf_t(const float* __restrict__ W,
    bf16* __restrict__ Wt, int K, int N, size_t ils, size_t ols) {
  __shared__ float t[32][33];
  const float* Wm = W + (size_t)blockIdx.z * ils;
  bf16* Wtm = Wt + (size_t)blockIdx.z * ols;
  int n0 = blockIdx.x * 32, k0 = blockIdx.y * 32;
  int tx = threadIdx.x;
  for (int i = threadIdx.y; i < 32; i += 8)
    t[i][tx] = Wm[(size_t)(k0 + i) * N + n0 + tx];
  __syncthreads();
  for (int i = threadIdx.y; i < 32; i += 8)
    Wtm[(size_t)(n0 + i) * K + k0 + tx] = __float2bfloat16(t[tx][i]);
}

// ---------------------------------------------------------------- bias concat
__global__ __launch_bounds__(256) void k_bcat(const float* __restrict__ bq,
    const float* __restrict__ bk, const float* __restrict__ bqc,
    const float* __restrict__ bv, const float* __restrict__ bksh,
    const float* __restrict__ bvsh, float* __restrict__ b6) {
  int idx = blockIdx.x * 256 + threadIdx.x;
  if (idx >= L_ * 4608) return;
  int l = idx / 4608, c = idx - l * 4608;
  float v = (c < 768)  ? bq[l * 768 + c]
          : (c < 1536) ? bk[l * 768 + c - 768]
          : (c < 2304) ? bqc[l * 768 + c - 1536]
          : (c < 3072) ? bv[l * 768 + c - 2304]
          : (c < 3840) ? bksh[c - 3072]
                       : bvsh[c - 3840];
  b6[idx] = v;
}

// ---------------------------------------------------------------- bf16 MFMA GEMM
// (per-layer GEMMs) 128x128 / 64x128 tile, BK=32, 3-buffer counted-vmcnt.
template <int BM, int EPI>
__global__ __launch_bounds__(256) void k_bgemm(
    const bf16* __restrict__ A, const bf16* __restrict__ Wt,
    const float* __restrict__ bias, const float* __restrict__ resid,
    float* __restrict__ Cf, bf16* __restrict__ Cb, bf16* __restrict__ Cb2,
    bf16* __restrict__ Cb3, int NM, int M, int N, int K) {
  constexpr int ASZ = BM * 64;
  constexpr int ALINES = BM / 64;
  constexpr int BSTRIDE = ASZ + 8192;
  constexpr int MF = BM / 32;
  __shared__ __align__(16) char smem[3 * BSTRIDE];
  const int tid = threadIdx.x;
  const int l = tid & 63, w = tid >> 6;
  const int wr = w >> 1, wc = w & 1;

  const int nwg = (int)gridDim.x;
  int id = (int)blockIdx.x;
  id = (id & 7) * (nwg >> 3) + (id >> 3);
  const int m0 = (id % NM) * BM;
  const int n0 = (id / NM) * 128;

  const int lane15 = l & 15, lg = l >> 4;

  const int r0 = tid >> 2, p0 = tid & 3;
  const char* aSrc[ALINES];
#pragma unroll
  for (int i = 0; i < ALINES; i++) {
    const int rr = i * 64 + r0;
    aSrc[i] = (const char*)(A + (size_t)(m0 + rr) * K) + ((p0 ^ CFUN(rr)) * 16);
  }
  const char* bSrc0 = (const char*)(Wt + (size_t)(n0 + r0) * K) + ((p0 ^ CFUN(r0)) * 16);
  const char* bSrc1 = (const char*)(Wt + (size_t)(n0 + 64 + r0) * K) + ((p0 ^ CFUN(64 + r0)) * 16);

  int aOff[MF], bOff[4];
#pragma unroll
  for (int mi = 0; mi < MF; mi++) {
    int r = wr * (BM / 2) + mi * 16 + lane15;
    aOff[mi] = r * 64 + ((lg ^ CFUN(r)) * 16);
  }
#pragma unroll
  for (int ni = 0; ni < 4; ni++) {
    int r = wc * 64 + ni * 16 + lane15;
    bOff[ni] = ASZ + r * 64 + ((lg ^ CFUN(r)) * 16);
  }

  f32x4 acc[MF][4];
#pragma unroll
  for (int mi = 0; mi < MF; mi++)
#pragma unroll
    for (int ni = 0; ni < 4; ni++) acc[mi][ni] = (f32x4){0.f, 0.f, 0.f, 0.f};

  auto stage = [&](int buf, int t) {
    const size_t kb = (size_t)t * 64;
    char* base = smem + buf * BSTRIDE;
#pragma unroll
    for (int i = 0; i < ALINES; i++)
      cp16(base + i * 4096 + w * 1024, aSrc[i] + kb);
    cp16(base + ASZ + w * 1024, bSrc0 + kb);
    cp16(base + ASZ + 4096 + w * 1024, bSrc1 + kb);
  };
  auto compute = [&](int buf) {
    const char* base = smem + buf * BSTRIDE;
    bf16x8 af[MF], bfr[4];
#pragma unroll
    for (int mi = 0; mi < MF; mi++) af[mi] = *(const bf16x8*)(base + aOff[mi]);
#pragma unroll
    for (int ni = 0; ni < 4; ni++) bfr[ni] = *(const bf16x8*)(base + bOff[ni]);
    __builtin_amdgcn_s_setprio(1);
#pragma unroll
    for (int mi = 0; mi < MF; mi++)
#pragma unroll
      for (int ni = 0; ni < 4; ni++)
        acc[mi][ni] = __builtin_amdgcn_mfma_f32_16x16x32_bf16(
            af[mi], bfr[ni], acc[mi][ni], 0, 0, 0);
    __builtin_amdgcn_s_setprio(0);
  };

  const int nk = K >> 5;
  stage(0, 0);
  stage(1, 1);
  int buf = 0;
  for (int t = 0; t < nk; t++) {
    if (t + 1 < nk) {
      if constexpr (ALINES == 2) asm volatile("s_waitcnt vmcnt(4)" ::: "memory");
      else                       asm volatile("s_waitcnt vmcnt(3)" ::: "memory");
    } else {
      asm volatile("s_waitcnt vmcnt(0)" ::: "memory");
    }
    __builtin_amdgcn_s_barrier();
    if (t + 2 < nk) {
      int nb = buf + 2; if (nb >= 3) nb -= 3;
      stage(nb, t + 2);
    }
    compute(buf);
    buf = (buf == 2) ? 0 : buf + 1;
  }

#pragma unroll
  for (int ni = 0; ni < 4; ni++) {
    const int col = n0 + wc * 64 + ni * 16 + lane15;
    const float bv = bias[col];
#pragma unroll
    for (int mi = 0; mi < MF; mi++) {
      const int rowb = m0 + wr * (BM / 2) + mi * 16 + lg * 4;
      if constexpr (EPI == 6) {
        if (col < 2304) {
#pragma unroll
          for (int j = 0; j < 4; j++)
            Cb[(size_t)(rowb + j) * 2304 + col] = __float2bfloat16(acc[mi][ni][j] + bv);
        } else if (col < 3072) {
          ushort4 pk;
          pk.x = f2bf(acc[mi][ni][0] + bv);
          pk.y = f2bf(acc[mi][ni][1] + bv);
          pk.z = f2bf(acc[mi][ni][2] + bv);
          pk.w = f2bf(acc[mi][ni][3] + bv);
          const int bq = rowb >> 10, s = rowb & (S_ - 1);
          *reinterpret_cast<ushort4*>(
              (unsigned short*)Cb2 + ((size_t)(bq * 768 + (col - 2304))) * S_ + s) = pk;
        } else {
#pragma unroll
          for (int j = 0; j < 4; j++)
            Cb3[(size_t)(rowb + j) * 1536 + (col - 3072)] =
                __float2bfloat16(acc[mi][ni][j] + bv);
        }
      } else {
#pragma unroll
        for (int j = 0; j < 4; j++) {
          const int row = rowb + j;
          float v = acc[mi][ni][j] + bv;
          if constexpr (EPI == 1) v += resid[(size_t)row * N + col];
          if constexpr (EPI == 2) {
            v = 0.5f * v * (1.0f + erff(v * 0.70710678118654752f));
            Cb[(size_t)row * N + col] = __float2bfloat16(v);
          } else if constexpr (EPI == 3) {
            Cb[(size_t)row * N + col] = __float2bfloat16(v);
          } else {
            Cf[(size_t)row * N + col] = v;
          }
        }
      }
    }
  }
}

// ------------------------------------------- head GEMM: 8-phase 256x256
// M=2048, N=32000, K=768. 512 thr / 8 waves (2Mx4N), BK=64, 128 KiB LDS dbuf.
// Race-safe issue schedule: a half-tile is overwritten only >=1 barrier after
// the phase whose MFMA consumed it. vmcnt(6) at P4/P8 only.
#define HBAR() asm volatile("s_barrier" ::: "memory")
#define MFMA16(AF, BF, MB, NB)                                               \
  do {                                                                       \
    __builtin_amdgcn_s_setprio(1);                                           \
    _Pragma("unroll") for (int mi_ = 0; mi_ < 4; mi_++)                      \
      _Pragma("unroll") for (int ni_ = 0; ni_ < 2; ni_++)                    \
        _Pragma("unroll") for (int ks_ = 0; ks_ < 2; ks_++)                  \
          acc[(MB) + mi_][(NB) + ni_] =                                      \
              __builtin_amdgcn_mfma_f32_16x16x32_bf16(                       \
                  AF[mi_][ks_], BF[ni_][ks_], acc[(MB) + mi_][(NB) + ni_],   \
                  0, 0, 0);                                                  \
    __builtin_amdgcn_s_setprio(0);                                           \
  } while (0)

__global__ __launch_bounds__(512, 1) void k_head8(const bf16* __restrict__ A,
    const bf16* __restrict__ Wt, const float* __restrict__ bias,
    float* __restrict__ C) {
  __shared__ __align__(16) char smem[131072];   // A: [0,64K) 2 bufs; B: [64K,128K)
  const int tid = threadIdx.x;
  const int l = tid & 63, w = tid >> 6;         // 8 waves
  const int wr = w >> 2, wc = w & 3;            // 2M x 4N
  const int lane15 = l & 15, lg = l >> 4;

  int id = (int)blockIdx.x;
  id = (id & 7) * 125 + (id >> 3);              // XCD chunk remap (1000 % 8 == 0)
  const int m0 = (id % 8) * 256;                // m-fast decode
  const int n0 = (id / 8) * 256;

  auto issueA = [&](int tile, int hb) {
#pragma unroll
    for (int j = 0; j < 2; j++) {
      const int idx = j * 512 + tid;
      const int rl = idx >> 3, sl = idx & 7;
      const bf16* g = A + (size_t)(m0 + hb + rl) * 768 + tile * 64 +
                      ((sl ^ (rl & 7)) << 3);
      cp16(smem + (tile & 1) * 32768 + hb * 128 + (j * 512 + w * 64) * 16, g);
    }
  };
  auto issueB = [&](int tile, int hb) {
#pragma unroll
    for (int j = 0; j < 2; j++) {
      const int idx = j * 512 + tid;
      const int rl = idx >> 3, sl = idx & 7;
      const bf16* g = Wt + (size_t)(n0 + hb + rl) * 768 + tile * 64 +
                      ((sl ^ (rl & 7)) << 3);
      cp16(smem + 65536 + (tile & 1) * 32768 + hb * 128 + (j * 512 + w * 64) * 16, g);
    }
  };
  auto ldA = [&](int buf, int mi, int ks) {
    const int r = wr * 128 + mi * 16 + lane15;
    return *(const bf16x8*)(smem + buf * 32768 + r * 128 +
                            ((((ks << 2) + lg) ^ (r & 7)) << 4));
  };
  auto ldB = [&](int buf, int ni, int ks) {
    const int r = wc * 64 + ni * 16 + lane15;
    return *(const bf16x8*)(smem + 65536 + buf * 32768 + r * 128 +
                            ((((ks << 2) + lg) ^ (r & 7)) << 4));
  };

  f32x4 acc[8][4];
#pragma unroll
  for (int i = 0; i < 8; i++)
#pragma unroll
    for (int j = 0; j < 4; j++) acc[i][j] = (f32x4){0.f, 0.f, 0.f, 0.f};
  bf16x8 alo[4][2], ahi[4][2], blo[2][2], bhi[2][2];

  // prologue: T0 fully + T1{B0,A0,B1}; vmcnt(6) -> T0 landed, 6 in flight
  issueA(0, 0);  issueA(0, 128);  issueB(0, 0);  issueB(0, 128);
  issueB(1, 0);  issueA(1, 0);    issueB(1, 128);
  asm volatile("s_waitcnt vmcnt(6)" ::: "memory");
  HBAR();

  for (int it = 0; it < 5; ++it) {
    const int Tb = 2 * it + 1, Tn = 2 * it + 2;
    // P1 (buf0): read alo,blo; issue A1(Tb)  [buf1 A-hi: consumed prev P7]
#pragma unroll
    for (int mi = 0; mi < 4; mi++) { alo[mi][0] = ldA(0, mi, 0); alo[mi][1] = ldA(0, mi, 1); }
#pragma unroll
    for (int ni = 0; ni < 2; ni++) { blo[ni][0] = ldB(0, ni, 0); blo[ni][1] = ldB(0, ni, 1); }
    issueA(Tb, 128);
    HBAR(); MFMA16(alo, blo, 0, 0); HBAR();
    // P2: read bhi; no issue
#pragma unroll
    for (int ni = 0; ni < 2; ni++) { bhi[ni][0] = ldB(0, ni + 2, 0); bhi[ni][1] = ldB(0, ni + 2, 1); }
    HBAR(); MFMA16(alo, bhi, 0, 2); HBAR();
    // P3: read ahi; issue B0(Tn)  [buf0 B-lo: consumed by P2's MFMA]
#pragma unroll
    for (int mi = 0; mi < 4; mi++) { ahi[mi][0] = ldA(0, mi + 4, 0); ahi[mi][1] = ldA(0, mi + 4, 1); }
    issueB(Tn, 0);
    HBAR(); MFMA16(ahi, bhi, 4, 2); HBAR();
    // P4: issue A0(Tn) [A-lo consumed by P3] + B1(Tn) [B-hi consumed by P2]; vmcnt(6)
    issueA(Tn, 0);
    issueB(Tn, 128);
    asm volatile("s_waitcnt vmcnt(6)" ::: "memory");
    HBAR(); MFMA16(ahi, blo, 4, 0); HBAR();
    // P5 (buf1): read alo,blo; issue A1(Tn)  [buf0 A-hi: consumed by P3]
#pragma unroll
    for (int mi = 0; mi < 4; mi++) { alo[mi][0] = ldA(1, mi, 0); alo[mi][1] = ldA(1, mi, 1); }
#pragma unroll
    for (int ni = 0; ni < 2; ni++) { blo[ni][0] = ldB(1, ni, 0); blo[ni][1] = ldB(1, ni, 1); }
    issueA(Tn, 128);
    HBAR(); MFMA16(alo, blo, 0, 0); HBAR();
    // P6: read bhi; no issue
#pragma unroll
    for (int ni = 0; ni < 2; ni++) { bhi[ni][0] = ldB(1, ni + 2, 0); bhi[ni][1] = ldB(1, ni + 2, 1); }
    HBAR(); MFMA16(alo, bhi, 0, 2); HBAR();
    // P7: read ahi; issue B0(Tn+1)
#pragma unroll
    for (int mi = 0; mi < 4; mi++) { ahi[mi][0] = ldA(1, mi + 4, 0); ahi[mi][1] = ldA(1, mi + 4, 1); }
    issueB(Tn + 1, 0);
    HBAR(); MFMA16(ahi, bhi, 4, 2); HBAR();
    // P8: issue A0(Tn+1) + B1(Tn+1); vmcnt(6)
    issueA(Tn + 1, 0);
    issueB(Tn + 1, 128);
    asm volatile("s_waitcnt vmcnt(6)" ::: "memory");
    HBAR(); MFMA16(ahi, blo, 4, 0); HBAR();
  }

  // last block: buf0 = T10 (landed); in flight T11{B0,A0,B1}
  {
#pragma unroll
    for (int mi = 0; mi < 4; mi++) { alo[mi][0] = ldA(0, mi, 0); alo[mi][1] = ldA(0, mi, 1); }
#pragma unroll
    for (int ni = 0; ni < 2; ni++) { blo[ni][0] = ldB(0, ni, 0); blo[ni][1] = ldB(0, ni, 1); }
    issueA(11, 128);
    HBAR(); MFMA16(alo, blo, 0, 0); HBAR();
#pragma unroll
    for (int ni = 0; ni < 2; ni++) { bhi[ni][0] = ldB(0, ni + 2, 0); bhi[ni][1] = ldB(0, ni + 2, 1); }
    HBAR(); MFMA16(alo, bhi, 0, 2); HBAR();
#pragma unroll
    for (int mi = 0; mi < 4; mi++) { ahi[mi][0] = ldA(0, mi + 4, 0); ahi[mi][1] = ldA(0, mi + 4, 1); }
    HBAR(); MFMA16(ahi, bhi, 4, 2); HBAR();
    asm volatile("s_waitcnt vmcnt(0)" ::: "memory");
    HBAR(); MFMA16(ahi, blo, 4, 0); HBAR();
    // T11 (buf1) — all landed, no further writes
#pragma unroll
    for (int mi = 0; mi < 4; mi++) { alo[mi][0] = ldA(1, mi, 0); alo[mi][1] = ldA(1, mi, 1); }
#pragma unroll
    for (int ni = 0; ni < 2; ni++) { blo[ni][0] = ldB(1, ni, 0); blo[ni][1] = ldB(1, ni, 1); }
    MFMA16(alo, blo, 0, 0);
#pragma unroll
    for (int ni = 0; ni < 2; ni++) { bhi[ni][0] = ldB(1, ni + 2, 0); bhi[ni][1] = ldB(1, ni + 2, 1); }
    MFMA16(alo, bhi, 0, 2);
#pragma unroll
    for (int mi = 0; mi < 4; mi++) { ahi[mi][0] = ldA(1, mi + 4, 0); ahi[mi][1] = ldA(1, mi + 4, 1); }
    MFMA16(ahi, bhi, 4, 2);
    MFMA16(ahi, blo, 4, 0);
  }

  // epilogue: bias + f32 store
#pragma unroll
  for (int ni = 0; ni < 4; ni++) {
    const int col = n0 + wc * 64 + ni * 16 + lane15;
    const float bv = bias[col];
#pragma unroll
    for (int mi = 0; mi < 8; mi++) {
      const int rowb = m0 + wr * 128 + mi * 16 + lg * 4;
#pragma unroll
      for (int j = 0; j < 4; j++)
        C[(size_t)(rowb + j) * 32000 + col] = acc[mi][ni][j] + bv;
    }
  }
}

// ---------------------------------------------------------------- flash attention
__global__ __launch_bounds__(256) void k_attn(
    const bf16* __restrict__ qkv, const bf16* __restrict__ vT,
    const bf16* __restrict__ memkv, bf16* __restrict__ ctx, int layer) {
  const int bh = blockIdx.x;
  const int b = bh / H_, h = bh % H_;
  const int qt = (int)gridDim.y - 1 - (int)blockIdx.y;   // big q first
  const int tid = threadIdx.x;
  const int w = tid >> 6, l = tid & 63;
  const int lane15 = l & 15, lg = l >> 4;
  const float inv = 0.125f;

  __shared__ char plds[4][2048];
  __shared__ float wlp[4][16][16];
  char* pl = plds[w];

  const int qrow0 = qt * 64 + w * 16;
  const size_t rowA = (size_t)(b * S_ + qrow0 + lane15);
  const bf16* qp = qkv + rowA * 2304 + h * 64 + lg * 8;
  const bf16x8 qf0 = *(const bf16x8*)(qp);
  const bf16x8 qf1 = *(const bf16x8*)(qp + 32);

  const bf16* kbase = qkv + (size_t)(b * S_) * 2304 + 768 + h * 64 + lg * 8;
  const bf16* vbase = vT + ((size_t)(b * 768 + h * 64 + lane15)) * S_;

  float mrow[4], dsum[4];
  f32x4 acc[4];
#pragma unroll
  for (int j = 0; j < 4; j++) { mrow[j] = -INFINITY; dsum[j] = 0.f; }
#pragma unroll
  for (int ni = 0; ni < 4; ni++) acc[ni] = (f32x4){0.f, 0.f, 0.f, 0.f};

  const int ntile = ((qrow0 + 15) >> 6) + 1;
  for (int kt64 = 0; kt64 < ntile; kt64++) {
    const int k0 = kt64 * 64;
    f32x4 sc[4];
#pragma unroll
    for (int kt = 0; kt < 4; kt++) {
      const bf16* kp = kbase + (size_t)(k0 + kt * 16 + lane15) * 2304;
      bf16x8 kf0 = *(const bf16x8*)(kp);
      bf16x8 kf1 = *(const bf16x8*)(kp + 32);
      f32x4 z = (f32x4){0.f, 0.f, 0.f, 0.f};
      z = __builtin_amdgcn_mfma_f32_16x16x32_bf16(qf0, kf0, z, 0, 0, 0);
      sc[kt] = __builtin_amdgcn_mfma_f32_16x16x32_bf16(qf1, kf1, z, 0, 0, 0);
    }
    float tmax[4];
#pragma unroll
    for (int j = 0; j < 4; j++) tmax[j] = -INFINITY;
#pragma unroll
    for (int kt = 0; kt < 4; kt++) {
      const int kabs = k0 + kt * 16 + lane15;
#pragma unroll
      for (int j = 0; j < 4; j++) {
        const int qabs = qrow0 + lg * 4 + j;
        float v = (kabs <= qabs) ? sc[kt][j] * inv : -INFINITY;
        sc[kt][j] = v;
        tmax[j] = fmaxf(tmax[j], v);
      }
    }
#pragma unroll
    for (int off = 1; off < 16; off <<= 1)
#pragma unroll
      for (int j = 0; j < 4; j++) tmax[j] = fmaxf(tmax[j], __shfl_xor(tmax[j], off, 16));

    float psum[4];
#pragma unroll
    for (int j = 0; j < 4; j++) {
      const float mnew = fmaxf(mrow[j], tmax[j]);
      const float alpha = __expf(mrow[j] - mnew);
      mrow[j] = mnew;
      dsum[j] *= alpha;
#pragma unroll
      for (int ni = 0; ni < 4; ni++) acc[ni][j] *= alpha;
      psum[j] = 0.f;
    }
#pragma unroll
    for (int kt = 0; kt < 4; kt++) {
      const int gsl = kt * 2 + (lane15 >> 3);
      const int ebyte = (lane15 & 7) * 2;
#pragma unroll
      for (int j = 0; j < 4; j++) {
        const float p = __expf(sc[kt][j] - mrow[j]);
        psum[j] += p;
        const int r = lg * 4 + j;
        *(unsigned short*)(pl + r * 128 + ((gsl ^ (r & 7)) << 4) + ebyte) = f2bf(p);
      }
    }
#pragma unroll
    for (int off = 1; off < 16; off <<= 1)
#pragma unroll
      for (int j = 0; j < 4; j++) psum[j] += __shfl_xor(psum[j], off, 16);
#pragma unroll
    for (int j = 0; j < 4; j++) dsum[j] += psum[j];

#pragma unroll
    for (int ks = 0; ks < 2; ks++) {
      bf16x8 pa = *(const bf16x8*)(pl + lane15 * 128 +
                                   ((((ks << 2) + lg) ^ (lane15 & 7)) << 4));
      const bf16* vp = vbase + k0 + ks * 32 + lg * 8;
#pragma unroll
      for (int ni = 0; ni < 4; ni++) {
        bf16x8 vf = *(const bf16x8*)(vp + (size_t)ni * 16 * S_);
        acc[ni] = __builtin_amdgcn_mfma_f32_16x16x32_bf16(pa, vf, acc[ni], 0, 0, 0);
      }
    }
  }

  const int r4 = lg * 4;
  if (lane15 < layer) {
    const int ml = lane15;
#pragma unroll
    for (int j = 0; j < 4; j++) {
      const size_t rowB = (size_t)(b * S_) + qrow0 + r4 + j;
      const bf16* qc = qkv + rowB * 2304 + 1536 + h * 64;
      const bf16* mk = memkv + ((size_t)ml * BS_ + rowB) * 1536 + h * 64;
      float d_ = 0.f;
#pragma unroll
      for (int t = 0; t < 8; t++) {
        bf16x8 qv = *(const bf16x8*)(qc + t * 8);
        bf16x8 kv = *(const bf16x8*)(mk + t * 8);
#pragma unroll
        for (int e = 0; e < 8; e++)
          d_ += bf2f((unsigned short)qv[e]) * bf2f((unsigned short)kv[e]);
      }
      wlp[w][r4 + j][ml] = d_ * inv;
    }
  }
  if (layer > 0) {
#pragma unroll
    for (int j = 0; j < 4; j++) {
      const int r = r4 + j;
      float mm = -INFINITY;
      for (int ml = 0; ml < layer; ml++) mm = fmaxf(mm, wlp[w][r][ml]);
      const float mnew = fmaxf(mrow[j], mm);
      const float alpha = __expf(mrow[j] - mnew);
      mrow[j] = mnew;
      dsum[j] *= alpha;
#pragma unroll
      for (int ni = 0; ni < 4; ni++) acc[ni][j] *= alpha;
      const size_t rowB = (size_t)(b * S_) + qrow0 + r;
      for (int ml = 0; ml < layer; ml++) {
        const float p = __expf(wlp[w][r][ml] - mnew);
        dsum[j] += p;
        const unsigned short* mv = (const unsigned short*)(memkv +
            ((size_t)ml * BS_ + rowB) * 1536 + 768 + h * 64 + lane15);
#pragma unroll
        for (int ni = 0; ni < 4; ni++)
          acc[ni][j] += p * bf2f(mv[ni * 16]);
      }
    }
  }

#pragma unroll
  for (int j = 0; j < 4; j++) {
    const float rd = 1.f / dsum[j];
    const size_t rowB = (size_t)(b * S_) + qrow0 + r4 + j;
    bf16* cp = ctx + rowB * 768 + h * 64 + lane15;
#pragma unroll
    for (int ni = 0; ni < 4; ni++)
      cp[ni * 16] = __float2bfloat16(acc[ni][j] * rd);
  }
}

// ---------------------------------------------------------------- launch
extern "C" void kernel_launch(void* const* d_in, const int* in_sizes, int n_in,
                              void* d_out, int out_size, void* d_ws, size_t ws_size,
                              hipStream_t stream) {
  const int*   tokens  = (const int*)d_in[0];
  const float* tok_emb = (const float*)d_in[1];
  const float* pos_emb = (const float*)d_in[2];
  const float *Wq_row, *Wk_row, *Wv_row, *Wq_col, *Wo;
  const float *bq_row, *bk_row, *bv_row, *bq_col, *bo;
  if (in_sizes[4] == L_ * D_ * D_) {  // dict order
    Wq_row = (const float*)d_in[3];  Wk_row = (const float*)d_in[4];
    Wv_row = (const float*)d_in[5];  Wq_col = (const float*)d_in[6];
    Wo     = (const float*)d_in[7];
    bq_row = (const float*)d_in[8];  bk_row = (const float*)d_in[9];
    bv_row = (const float*)d_in[10]; bq_col = (const float*)d_in[11];
    bo     = (const float*)d_in[12];
  } else {  // signature order fallback
    Wq_row = (const float*)d_in[3];  bq_row = (const float*)d_in[4];
    Wk_row = (const float*)d_in[5];  bk_row = (const float*)d_in[6];
    Wv_row = (const float*)d_in[7];  bv_row = (const float*)d_in[8];
    Wq_col = (const float*)d_in[9];  bq_col = (const float*)d_in[10];
    Wo     = (const float*)d_in[11]; bo     = (const float*)d_in[12];
  }
  const float* ln1_g = (const float*)d_in[13]; const float* ln1_b = (const float*)d_in[14];
  const float* ln2_g = (const float*)d_in[15]; const float* ln2_b = (const float*)d_in[16];
  const float* W1    = (const float*)d_in[17]; const float* b1    = (const float*)d_in[18];
  const float* W2    = (const float*)d_in[19]; const float* b2    = (const float*)d_in[20];
  const float* Wk_sh = (const float*)d_in[21]; const float* bk_sh = (const float*)d_in[22];
  const float* Wv_sh = (const float*)d_in[23]; const float* bv_sh = (const float*)d_in[24];
  const float* lnf_g = (const float*)d_in[25]; const float* lnf_b = (const float*)d_in[26];
  const float* Whead = (const float*)d_in[27]; const float* bhead = (const float*)d_in[28];

  // ---- workspace carve-up
  char* p = (char*)d_ws;
  float* x      = (float*)p; p += (size_t)BS_ * D_ * 4;
  bf16*  h_bf   = (bf16*)p;  p += (size_t)BS_ * D_ * 2;
  bf16*  qkv3   = (bf16*)p;  p += (size_t)BS_ * 2304 * 2;
  bf16*  vTb    = (bf16*)p;  p += (size_t)B_ * 768 * S_ * 2;
  bf16*  memkv  = (bf16*)p;  p += (size_t)L_ * BS_ * 1536 * 2;
  bf16*  ctx_bf = (bf16*)p;  p += (size_t)BS_ * D_ * 2;
  bf16*  mlp_bf = (bf16*)p;  p += (size_t)BS_ * DFF_ * 2;
  float* b6cat  = (float*)p; p += (size_t)L_ * 4608 * 4;
  bf16* tW6    = (bf16*)p; p += (size_t)L_ * 4608 * D_ * 2;   // q|k|qc|v|ksh|vsh
  bf16* tWo    = (bf16*)p; p += (size_t)L_ * D_ * D_ * 2;
  bf16* tW1    = (bf16*)p; p += (size_t)L_ * DFF_ * D_ * 2;
  bf16* tW2    = (bf16*)p; p += (size_t)L_ * D_ * DFF_ * 2;
  bf16* tWhead = (bf16*)p; p += (size_t)V_ * D_ * 2;

  // ---- weight conversion (transposed bf16), bias concat
  dim3 tb(32, 8);
  const size_t DD = (size_t)D_ * D_;
  const size_t W6S = (size_t)4608 * 768;
  k_w2bf_t<<<dim3(24, 24, L_), tb, 0, stream>>>(Wq_row, tW6,              768, 768, DD, W6S);
  k_w2bf_t<<<dim3(24, 24, L_), tb, 0, stream>>>(Wk_row, tW6 + 768 * 768,  768, 768, DD, W6S);
  k_w2bf_t<<<dim3(24, 24, L_), tb, 0, stream>>>(Wq_col, tW6 + 1536 * 768, 768, 768, DD, W6S);
  k_w2bf_t<<<dim3(24, 24, L_), tb, 0, stream>>>(Wv_row, tW6 + 2304 * 768, 768, 768, DD, W6S);
  k_w2bf_t<<<dim3(24, 24, L_), tb, 0, stream>>>(Wk_sh,  tW6 + 3072 * 768, 768, 768, 0, W6S);
  k_w2bf_t<<<dim3(24, 24, L_), tb, 0, stream>>>(Wv_sh,  tW6 + 3840 * 768, 768, 768, 0, W6S);
  k_w2bf_t<<<dim3(24, 24, L_), tb, 0, stream>>>(Wo,     tWo, 768, 768, DD, DD);
  k_w2bf_t<<<dim3(96, 24, L_), tb, 0, stream>>>(W1, tW1, 768, 3072, (size_t)768 * 3072, (size_t)3072 * 768);
  k_w2bf_t<<<dim3(24, 96, L_), tb, 0, stream>>>(W2, tW2, 3072, 768, (size_t)768 * 3072, (size_t)768 * 3072);
  k_w2bf_t<<<dim3(1000, 24, 1), tb, 0, stream>>>(Whead, tWhead, 768, 32000, 0, 0);
  k_bcat<<<dim3(144), 256, 0, stream>>>(bq_row, bk_row, bq_col, bv_row, bk_sh, bv_sh, b6cat);

  k_embed<<<dim3((BS_ * D_) / 256), 256, 0, stream>>>(tokens, tok_emb, pos_emb, x);

  for (int i = 0; i < L_; i++) {
    k_ln<<<dim3(BS_), 256, 0, stream>>>(x, ln1_g + i * D_, ln1_b + i * D_, h_bf);
    k_bgemm<128, 6><<<dim3(576), 256, 0, stream>>>(
        h_bf, tW6 + (size_t)i * W6S, b6cat + (size_t)i * 4608,
        nullptr, nullptr, qkv3, vTb, memkv + (size_t)i * BS_ * 1536,
        16, BS_, 4608, 768);
    k_attn<<<dim3(B_ * H_, S_ / 64), 256, 0, stream>>>(qkv3, vTb, memkv, ctx_bf, i);
    k_bgemm<64, 1><<<dim3(192), 256, 0, stream>>>(
        ctx_bf, tWo + (size_t)i * DD, bo + i * D_, x, x, nullptr, nullptr, nullptr,
        32, BS_, 768, 768);
    k_ln<<<dim3(BS_), 256, 0, stream>>>(x, ln2_g + i * D_, ln2_b + i * D_, h_bf);
    k_bgemm<128, 2><<<dim3(384), 256, 0, stream>>>(
        h_bf, tW1 + (size_t)i * 3072 * 768, b1 + (size_t)i * DFF_,
        nullptr, nullptr, mlp_bf, nullptr, nullptr, 16, BS_, 3072, 768);
    k_bgemm<64, 1><<<dim3(192), 256, 0, stream>>>(
        mlp_bf, tW2 + (size_t)i * 768 * 3072, b2 + i * D_, x, x, nullptr, nullptr,
        nullptr, 32, BS_, 768, 3072);
  }
  k_ln<<<dim3(BS_), 256, 0, stream>>>(x, lnf_g, lnf_b, h_bf);
  k_head8<<<dim3(1000), 512, 0, stream>>>(h_bf, tWhead, bhead, (float*)d_out);
}

// Round 11
// 1771.608 us; speedup vs baseline: 1.1649x; 1.0406x over previous
//
#include <hip/hip_runtime.h>
#include <hip/hip_bf16.h>
#include <math.h>

#define L_   8
#define D_   768
#define H_   12
#define V_   32000
#define B_   2
#define S_   1024
#define HD_  64
#define BS_  2048      // B_*S_
#define DFF_ 3072      // MR*D

typedef __hip_bfloat16 bf16;
typedef __attribute__((ext_vector_type(8))) short bf16x8;
typedef __attribute__((ext_vector_type(4))) float f32x4;

// Balanced LDS slot swizzle for the 128x128 k_bgemm (BK=32, 4-slot rows)
#define CFUN(r) (((r) >> 1) & 3)

__device__ __forceinline__ void cp16(void* lds, const void* g) {
  __builtin_amdgcn_global_load_lds(
      (const __attribute__((address_space(1))) void*)g,
      (__attribute__((address_space(3))) void*)lds, 16, 0, 0);
}

__device__ __forceinline__ unsigned short f2bf(float v) {
  __hip_bfloat16 h = __float2bfloat16(v);
  return *reinterpret_cast<unsigned short*>(&h);
}
__device__ __forceinline__ float bf2f(unsigned short u) {
  return __uint_as_float(((unsigned)u) << 16);
}

// ---------------------------------------------------------------- embedding
__global__ __launch_bounds__(256) void k_embed(const int* __restrict__ tokens,
    const float* __restrict__ tok_emb, const float* __restrict__ pos_emb,
    float* __restrict__ x) {
  int idx = blockIdx.x * 256 + threadIdx.x;
  int row = idx / D_;
  int d   = idx - row * D_;
  int s   = row & (S_ - 1);
  int t   = tokens[row];
  x[idx] = tok_emb[(size_t)t * D_ + d] + pos_emb[(size_t)s * D_ + d];
}

// ---------------------------------------------------------------- layernorm -> bf16
__global__ __launch_bounds__(256) void k_ln(const float* __restrict__ x,
    const float* __restrict__ g, const float* __restrict__ b,
    bf16* __restrict__ out) {
  int row = blockIdx.x;
  const float* xr = x + (size_t)row * D_;
  int t = threadIdx.x;
  float v0 = xr[t], v1 = xr[t + 256], v2 = xr[t + 512];
  float s  = v0 + v1 + v2;
  float s2 = v0 * v0 + v1 * v1 + v2 * v2;
#pragma unroll
  for (int off = 32; off; off >>= 1) {
    s  += __shfl_down(s, off);
    s2 += __shfl_down(s2, off);
  }
  __shared__ float rs[4], rs2[4];
  __shared__ float mean_s, rstd_s;
  int wid = t >> 6;
  if ((t & 63) == 0) { rs[wid] = s; rs2[wid] = s2; }
  __syncthreads();
  if (t == 0) {
    float S1 = rs[0] + rs[1] + rs[2] + rs[3];
    float S2 = rs2[0] + rs2[1] + rs2[2] + rs2[3];
    float m  = S1 / D_;
    float var = S2 / D_ - m * m;
    mean_s = m;
    rstd_s = rsqrtf(var + 1e-5f);
  }
  __syncthreads();
  float m = mean_s, r = rstd_s;
  bf16* orow = out + (size_t)row * D_;
  orow[t]       = __float2bfloat16((v0 - m) * r * g[t]       + b[t]);
  orow[t + 256] = __float2bfloat16((v1 - m) * r * g[t + 256] + b[t + 256]);
  orow[t + 512] = __float2bfloat16((v2 - m) * r * g[t + 512] + b[t + 512]);
}

// ------------------------------------------------- weight convert + transpose
__global__ __launch_bounds__(256) void k_w2bf_t(const float* __restrict__ W,
    bf16* __restrict__ Wt, int K, int N, size_t ils, size_t ols) {
  __shared__ float t[32][33];
  const float* Wm = W + (size_t)blockIdx.z * ils;
  bf16* Wtm = Wt + (size_t)blockIdx.z * ols;
  int n0 = blockIdx.x * 32, k0 = blockIdx.y * 32;
  int tx = threadIdx.x;
  for (int i = threadIdx.y; i < 32; i += 8)
    t[i][tx] = Wm[(size_t)(k0 + i) * N + n0 + tx];
  __syncthreads();
  for (int i = threadIdx.y; i < 32; i += 8)
    Wtm[(size_t)(n0 + i) * K + k0 + tx] = __float2bfloat16(t[tx][i]);
}

// ---------------------------------------------------------------- bias concat
__global__ __launch_bounds__(256) void k_bcat(const float* __restrict__ bq,
    const float* __restrict__ bk, const float* __restrict__ bqc,
    const float* __restrict__ bv, const float* __restrict__ bksh,
    const float* __restrict__ bvsh, float* __restrict__ b6) {
  int idx = blockIdx.x * 256 + threadIdx.x;
  if (idx >= L_ * 4608) return;
  int l = idx / 4608, c = idx - l * 4608;
  float v = (c < 768)  ? bq[l * 768 + c]
          : (c < 1536) ? bk[l * 768 + c - 768]
          : (c < 2304) ? bqc[l * 768 + c - 1536]
          : (c < 3072) ? bv[l * 768 + c - 2304]
          : (c < 3840) ? bksh[c - 3072]
                       : bvsh[c - 3840];
  b6[idx] = v;
}

// ---------------------------------------------------------------- split-K reduce
// x[i] += p0[i] + p1[i] + bias[i % N]
__global__ __launch_bounds__(256) void k_red(float* __restrict__ x,
    const float* __restrict__ pk, const float* __restrict__ bias, int N) {
  const int i = (blockIdx.x * 256 + threadIdx.x) * 4;
  const int col = i % N;
  const size_t MN = (size_t)BS_ * N;
  float4 a  = *reinterpret_cast<const float4*>(x + i);
  float4 p0 = *reinterpret_cast<const float4*>(pk + i);
  float4 p1 = *reinterpret_cast<const float4*>(pk + MN + i);
  a.x += p0.x + p1.x + bias[col];
  a.y += p0.y + p1.y + bias[col + 1];
  a.z += p0.z + p1.z + bias[col + 2];
  a.w += p0.w + p1.w + bias[col + 3];
  *reinterpret_cast<float4*>(x + i) = a;
}

// ---------------------------------------------------------------- bf16 MFMA GEMM
// (per-layer GEMMs) BMx128 tile, BK=32, 3-buffer counted-vmcnt pipeline.
// KSPL=2: grid doubled, block sk in {0,1} computes K-half, EPI=7 writes f32
// partial to Cf[sk*M*N + ...] (bias added in k_red).
// EPI=6 routing: col<2304 -> qkv; <3072 -> vT transposed; else memkv.
//   Wt2 (EPI=6 only): alternate B base for n0 >= 3072 (shared k/v weights).
template <int BM, int EPI, int KSPL>
__global__ __launch_bounds__(256) void k_bgemm(
    const bf16* __restrict__ A, const bf16* __restrict__ Wt,
    const bf16* __restrict__ Wt2,
    const float* __restrict__ bias, const float* __restrict__ resid,
    float* __restrict__ Cf, bf16* __restrict__ Cb, bf16* __restrict__ Cb2,
    bf16* __restrict__ Cb3, int NM, int M, int N, int K) {
  constexpr int ASZ = BM * 64;
  constexpr int ALINES = BM / 64;
  constexpr int BSTRIDE = ASZ + 8192;
  constexpr int MF = BM / 32;
  __shared__ __align__(16) char smem[3 * BSTRIDE];
  const int tid = threadIdx.x;
  const int l = tid & 63, w = tid >> 6;
  const int wr = w >> 1, wc = w & 1;

  const int nwg = (int)gridDim.x;
  int id = (int)blockIdx.x;
  id = (id & 7) * (nwg >> 3) + (id >> 3);
  int sk = 0;
  if constexpr (KSPL == 2) {
    const int TT = nwg >> 1;
    sk = id / TT;
    id -= sk * TT;
  }
  const int m0 = (id % NM) * BM;
  const int n0 = (id / NM) * 128;
  const int kstart = sk * (K / KSPL);

  const int lane15 = l & 15, lg = l >> 4;

  // B base selection (shared k/v weights live in a separate unreplicated buf)
  const bf16* WB = Wt;
  int nb0 = n0;
  if constexpr (EPI == 6) {
    if (n0 >= 3072) { WB = Wt2; nb0 = n0 - 3072; }
  }

  const int r0 = tid >> 2, p0 = tid & 3;
  const char* aSrc[ALINES];
#pragma unroll
  for (int i = 0; i < ALINES; i++) {
    const int rr = i * 64 + r0;
    aSrc[i] = (const char*)(A + (size_t)(m0 + rr) * K + kstart) + ((p0 ^ CFUN(rr)) * 16);
  }
  const char* bSrc0 = (const char*)(WB + (size_t)(nb0 + r0) * K + kstart) + ((p0 ^ CFUN(r0)) * 16);
  const char* bSrc1 = (const char*)(WB + (size_t)(nb0 + 64 + r0) * K + kstart) + ((p0 ^ CFUN(64 + r0)) * 16);

  int aOff[MF], bOff[4];
#pragma unroll
  for (int mi = 0; mi < MF; mi++) {
    int r = wr * (BM / 2) + mi * 16 + lane15;
    aOff[mi] = r * 64 + ((lg ^ CFUN(r)) * 16);
  }
#pragma unroll
  for (int ni = 0; ni < 4; ni++) {
    int r = wc * 64 + ni * 16 + lane15;
    bOff[ni] = ASZ + r * 64 + ((lg ^ CFUN(r)) * 16);
  }

  f32x4 acc[MF][4];
#pragma unroll
  for (int mi = 0; mi < MF; mi++)
#pragma unroll
    for (int ni = 0; ni < 4; ni++) acc[mi][ni] = (f32x4){0.f, 0.f, 0.f, 0.f};

  auto stage = [&](int buf, int t) {
    const size_t kb = (size_t)t * 64;
    char* base = smem + buf * BSTRIDE;
#pragma unroll
    for (int i = 0; i < ALINES; i++)
      cp16(base + i * 4096 + w * 1024, aSrc[i] + kb);
    cp16(base + ASZ + w * 1024, bSrc0 + kb);
    cp16(base + ASZ + 4096 + w * 1024, bSrc1 + kb);
  };
  auto compute = [&](int buf) {
    const char* base = smem + buf * BSTRIDE;
    bf16x8 af[MF], bfr[4];
#pragma unroll
    for (int mi = 0; mi < MF; mi++) af[mi] = *(const bf16x8*)(base + aOff[mi]);
#pragma unroll
    for (int ni = 0; ni < 4; ni++) bfr[ni] = *(const bf16x8*)(base + bOff[ni]);
    __builtin_amdgcn_s_setprio(1);
#pragma unroll
    for (int mi = 0; mi < MF; mi++)
#pragma unroll
      for (int ni = 0; ni < 4; ni++)
        acc[mi][ni] = __builtin_amdgcn_mfma_f32_16x16x32_bf16(
            af[mi], bfr[ni], acc[mi][ni], 0, 0, 0);
    __builtin_amdgcn_s_setprio(0);
  };

  const int nk = (K / KSPL) >> 5;
  stage(0, 0);
  stage(1, 1);
  int buf = 0;
  for (int t = 0; t < nk; t++) {
    if (t + 1 < nk) {
      if constexpr (ALINES == 2) asm volatile("s_waitcnt vmcnt(4)" ::: "memory");
      else                       asm volatile("s_waitcnt vmcnt(3)" ::: "memory");
    } else {
      asm volatile("s_waitcnt vmcnt(0)" ::: "memory");
    }
    __builtin_amdgcn_s_barrier();
    if (t + 2 < nk) {
      int nb = buf + 2; if (nb >= 3) nb -= 3;
      stage(nb, t + 2);
    }
    compute(buf);
    buf = (buf == 2) ? 0 : buf + 1;
  }

#pragma unroll
  for (int ni = 0; ni < 4; ni++) {
    const int col = n0 + wc * 64 + ni * 16 + lane15;
    const float bv = bias[col];
#pragma unroll
    for (int mi = 0; mi < MF; mi++) {
      const int rowb = m0 + wr * (BM / 2) + mi * 16 + lg * 4;
      if constexpr (EPI == 6) {
        if (col < 2304) {
#pragma unroll
          for (int j = 0; j < 4; j++)
            Cb[(size_t)(rowb + j) * 2304 + col] = __float2bfloat16(acc[mi][ni][j] + bv);
        } else if (col < 3072) {
          ushort4 pk;
          pk.x = f2bf(acc[mi][ni][0] + bv);
          pk.y = f2bf(acc[mi][ni][1] + bv);
          pk.z = f2bf(acc[mi][ni][2] + bv);
          pk.w = f2bf(acc[mi][ni][3] + bv);
          const int bq = rowb >> 10, s = rowb & (S_ - 1);
          *reinterpret_cast<ushort4*>(
              (unsigned short*)Cb2 + ((size_t)(bq * 768 + (col - 2304))) * S_ + s) = pk;
        } else {
#pragma unroll
          for (int j = 0; j < 4; j++)
            Cb3[(size_t)(rowb + j) * 1536 + (col - 3072)] =
                __float2bfloat16(acc[mi][ni][j] + bv);
        }
      } else if constexpr (EPI == 7) {
#pragma unroll
        for (int j = 0; j < 4; j++)
          Cf[(size_t)sk * M * N + (size_t)(rowb + j) * N + col] = acc[mi][ni][j];
      } else {
#pragma unroll
        for (int j = 0; j < 4; j++) {
          const int row = rowb + j;
          float v = acc[mi][ni][j] + bv;
          if constexpr (EPI == 1) v += resid[(size_t)row * N + col];
          if constexpr (EPI == 2) {
            v = 0.5f * v * (1.0f + erff(v * 0.70710678118654752f));
            Cb[(size_t)row * N + col] = __float2bfloat16(v);
          } else if constexpr (EPI == 3) {
            Cb[(size_t)row * N + col] = __float2bfloat16(v);
          } else {
            Cf[(size_t)row * N + col] = v;
          }
        }
      }
    }
  }
}

// ------------------------------------------- head GEMM: 8-phase 256x256
// Race-safe issue schedule; vmcnt(6) at P4/P8 only. (validated round 10)
#define HBAR() asm volatile("s_barrier" ::: "memory")
#define MFMA16(AF, BF, MB, NB)                                               \
  do {                                                                       \
    __builtin_amdgcn_s_setprio(1);                                           \
    _Pragma("unroll") for (int mi_ = 0; mi_ < 4; mi_++)                      \
      _Pragma("unroll") for (int ni_ = 0; ni_ < 2; ni_++)                    \
        _Pragma("unroll") for (int ks_ = 0; ks_ < 2; ks_++)                  \
          acc[(MB) + mi_][(NB) + ni_] =                                      \
              __builtin_amdgcn_mfma_f32_16x16x32_bf16(                       \
                  AF[mi_][ks_], BF[ni_][ks_], acc[(MB) + mi_][(NB) + ni_],   \
                  0, 0, 0);                                                  \
    __builtin_amdgcn_s_setprio(0);                                           \
  } while (0)

__global__ __launch_bounds__(512, 1) void k_head8(const bf16* __restrict__ A,
    const bf16* __restrict__ Wt, const float* __restrict__ bias,
    float* __restrict__ C) {
  __shared__ __align__(16) char smem[131072];   // A: [0,64K) 2 bufs; B: [64K,128K)
  const int tid = threadIdx.x;
  const int l = tid & 63, w = tid >> 6;         // 8 waves
  const int wr = w >> 2, wc = w & 3;            // 2M x 4N
  const int lane15 = l & 15, lg = l >> 4;

  int id = (int)blockIdx.x;
  id = (id & 7) * 125 + (id >> 3);              // XCD chunk remap (1000 % 8 == 0)
  const int m0 = (id % 8) * 256;                // m-fast decode
  const int n0 = (id / 8) * 256;

  auto issueA = [&](int tile, int hb) {
#pragma unroll
    for (int j = 0; j < 2; j++) {
      const int idx = j * 512 + tid;
      const int rl = idx >> 3, sl = idx & 7;
      const bf16* g = A + (size_t)(m0 + hb + rl) * 768 + tile * 64 +
                      ((sl ^ (rl & 7)) << 3);
      cp16(smem + (tile & 1) * 32768 + hb * 128 + (j * 512 + w * 64) * 16, g);
    }
  };
  auto issueB = [&](int tile, int hb) {
#pragma unroll
    for (int j = 0; j < 2; j++) {
      const int idx = j * 512 + tid;
      const int rl = idx >> 3, sl = idx & 7;
      const bf16* g = Wt + (size_t)(n0 + hb + rl) * 768 + tile * 64 +
                      ((sl ^ (rl & 7)) << 3);
      cp16(smem + 65536 + (tile & 1) * 32768 + hb * 128 + (j * 512 + w * 64) * 16, g);
    }
  };
  auto ldA = [&](int buf, int mi, int ks) {
    const int r = wr * 128 + mi * 16 + lane15;
    return *(const bf16x8*)(smem + buf * 32768 + r * 128 +
                            ((((ks << 2) + lg) ^ (r & 7)) << 4));
  };
  auto ldB = [&](int buf, int ni, int ks) {
    const int r = wc * 64 + ni * 16 + lane15;
    return *(const bf16x8*)(smem + 65536 + buf * 32768 + r * 128 +
                            ((((ks << 2) + lg) ^ (r & 7)) << 4));
  };

  f32x4 acc[8][4];
#pragma unroll
  for (int i = 0; i < 8; i++)
#pragma unroll
    for (int j = 0; j < 4; j++) acc[i][j] = (f32x4){0.f, 0.f, 0.f, 0.f};
  bf16x8 alo[4][2], ahi[4][2], blo[2][2], bhi[2][2];

  // prologue: T0 fully + T1{B0,A0,B1}; vmcnt(6) -> T0 landed, 6 in flight
  issueA(0, 0);  issueA(0, 128);  issueB(0, 0);  issueB(0, 128);
  issueB(1, 0);  issueA(1, 0);    issueB(1, 128);
  asm volatile("s_waitcnt vmcnt(6)" ::: "memory");
  HBAR();

  for (int it = 0; it < 5; ++it) {
    const int Tb = 2 * it + 1, Tn = 2 * it + 2;
#pragma unroll
    for (int mi = 0; mi < 4; mi++) { alo[mi][0] = ldA(0, mi, 0); alo[mi][1] = ldA(0, mi, 1); }
#pragma unroll
    for (int ni = 0; ni < 2; ni++) { blo[ni][0] = ldB(0, ni, 0); blo[ni][1] = ldB(0, ni, 1); }
    issueA(Tb, 128);
    HBAR(); MFMA16(alo, blo, 0, 0); HBAR();
#pragma unroll
    for (int ni = 0; ni < 2; ni++) { bhi[ni][0] = ldB(0, ni + 2, 0); bhi[ni][1] = ldB(0, ni + 2, 1); }
    HBAR(); MFMA16(alo, bhi, 0, 2); HBAR();
#pragma unroll
    for (int mi = 0; mi < 4; mi++) { ahi[mi][0] = ldA(0, mi + 4, 0); ahi[mi][1] = ldA(0, mi + 4, 1); }
    issueB(Tn, 0);
    HBAR(); MFMA16(ahi, bhi, 4, 2); HBAR();
    issueA(Tn, 0);
    issueB(Tn, 128);
    asm volatile("s_waitcnt vmcnt(6)" ::: "memory");
    HBAR(); MFMA16(ahi, blo, 4, 0); HBAR();
#pragma unroll
    for (int mi = 0; mi < 4; mi++) { alo[mi][0] = ldA(1, mi, 0); alo[mi][1] = ldA(1, mi, 1); }
#pragma unroll
    for (int ni = 0; ni < 2; ni++) { blo[ni][0] = ldB(1, ni, 0); blo[ni][1] = ldB(1, ni, 1); }
    issueA(Tn, 128);
    HBAR(); MFMA16(alo, blo, 0, 0); HBAR();
#pragma unroll
    for (int ni = 0; ni < 2; ni++) { bhi[ni][0] = ldB(1, ni + 2, 0); bhi[ni][1] = ldB(1, ni + 2, 1); }
    HBAR(); MFMA16(alo, bhi, 0, 2); HBAR();
#pragma unroll
    for (int mi = 0; mi < 4; mi++) { ahi[mi][0] = ldA(1, mi + 4, 0); ahi[mi][1] = ldA(1, mi + 4, 1); }
    issueB(Tn + 1, 0);
    HBAR(); MFMA16(ahi, bhi, 4, 2); HBAR();
    issueA(Tn + 1, 0);
    issueB(Tn + 1, 128);
    asm volatile("s_waitcnt vmcnt(6)" ::: "memory");
    HBAR(); MFMA16(ahi, blo, 4, 0); HBAR();
  }

  {
#pragma unroll
    for (int mi = 0; mi < 4; mi++) { alo[mi][0] = ldA(0, mi, 0); alo[mi][1] = ldA(0, mi, 1); }
#pragma unroll
    for (int ni = 0; ni < 2; ni++) { blo[ni][0] = ldB(0, ni, 0); blo[ni][1] = ldB(0, ni, 1); }
    issueA(11, 128);
    HBAR(); MFMA16(alo, blo, 0, 0); HBAR();
#pragma unroll
    for (int ni = 0; ni < 2; ni++) { bhi[ni][0] = ldB(0, ni + 2, 0); bhi[ni][1] = ldB(0, ni + 2, 1); }
    HBAR(); MFMA16(alo, bhi, 0, 2); HBAR();
#pragma unroll
    for (int mi = 0; mi < 4; mi++) { ahi[mi][0] = ldA(0, mi + 4, 0); ahi[mi][1] = ldA(0, mi + 4, 1); }
    HBAR(); MFMA16(ahi, bhi, 4, 2); HBAR();
    asm volatile("s_waitcnt vmcnt(0)" ::: "memory");
    HBAR(); MFMA16(ahi, blo, 4, 0); HBAR();
#pragma unroll
    for (int mi = 0; mi < 4; mi++) { alo[mi][0] = ldA(1, mi, 0); alo[mi][1] = ldA(1, mi, 1); }
#pragma unroll
    for (int ni = 0; ni < 2; ni++) { blo[ni][0] = ldB(1, ni, 0); blo[ni][1] = ldB(1, ni, 1); }
    MFMA16(alo, blo, 0, 0);
#pragma unroll
    for (int ni = 0; ni < 2; ni++) { bhi[ni][0] = ldB(1, ni + 2, 0); bhi[ni][1] = ldB(1, ni + 2, 1); }
    MFMA16(alo, bhi, 0, 2);
#pragma unroll
    for (int mi = 0; mi < 4; mi++) { ahi[mi][0] = ldA(1, mi + 4, 0); ahi[mi][1] = ldA(1, mi + 4, 1); }
    MFMA16(ahi, bhi, 4, 2);
    MFMA16(ahi, blo, 4, 0);
  }

#pragma unroll
  for (int ni = 0; ni < 4; ni++) {
    const int col = n0 + wc * 64 + ni * 16 + lane15;
    const float bv = bias[col];
#pragma unroll
    for (int mi = 0; mi < 8; mi++) {
      const int rowb = m0 + wr * 128 + mi * 16 + lg * 4;
#pragma unroll
      for (int j = 0; j < 4; j++)
        C[(size_t)(rowb + j) * 32000 + col] = acc[mi][ni][j] + bv;
    }
  }
}

// ---------------------------------------------------------------- flash attention
__global__ __launch_bounds__(256) void k_attn(
    const bf16* __restrict__ qkv, const bf16* __restrict__ vT,
    const bf16* __restrict__ memkv, bf16* __restrict__ ctx, int layer) {
  const int bh = blockIdx.x;
  const int b = bh / H_, h = bh % H_;
  const int qt = (int)gridDim.y - 1 - (int)blockIdx.y;   // big q first
  const int tid = threadIdx.x;
  const int w = tid >> 6, l = tid & 63;
  const int lane15 = l & 15, lg = l >> 4;
  const float inv = 0.125f;

  __shared__ char plds[4][2048];
  __shared__ float wlp[4][16][16];
  char* pl = plds[w];

  const int qrow0 = qt * 64 + w * 16;
  const size_t rowA = (size_t)(b * S_ + qrow0 + lane15);
  const bf16* qp = qkv + rowA * 2304 + h * 64 + lg * 8;
  const bf16x8 qf0 = *(const bf16x8*)(qp);
  const bf16x8 qf1 = *(const bf16x8*)(qp + 32);

  const bf16* kbase = qkv + (size_t)(b * S_) * 2304 + 768 + h * 64 + lg * 8;
  const bf16* vbase = vT + ((size_t)(b * 768 + h * 64 + lane15)) * S_;

  float mrow[4], dsum[4];
  f32x4 acc[4];
#pragma unroll
  for (int j = 0; j < 4; j++) { mrow[j] = -INFINITY; dsum[j] = 0.f; }
#pragma unroll
  for (int ni = 0; ni < 4; ni++) acc[ni] = (f32x4){0.f, 0.f, 0.f, 0.f};

  const int ntile = ((qrow0 + 15) >> 6) + 1;
  for (int kt64 = 0; kt64 < ntile; kt64++) {
    const int k0 = kt64 * 64;
    f32x4 sc[4];
#pragma unroll
    for (int kt = 0; kt < 4; kt++) {
      const bf16* kp = kbase + (size_t)(k0 + kt * 16 + lane15) * 2304;
      bf16x8 kf0 = *(const bf16x8*)(kp);
      bf16x8 kf1 = *(const bf16x8*)(kp + 32);
      f32x4 z = (f32x4){0.f, 0.f, 0.f, 0.f};
      z = __builtin_amdgcn_mfma_f32_16x16x32_bf16(qf0, kf0, z, 0, 0, 0);
      sc[kt] = __builtin_amdgcn_mfma_f32_16x16x32_bf16(qf1, kf1, z, 0, 0, 0);
    }
    float tmax[4];
#pragma unroll
    for (int j = 0; j < 4; j++) tmax[j] = -INFINITY;
#pragma unroll
    for (int kt = 0; kt < 4; kt++) {
      const int kabs = k0 + kt * 16 + lane15;
#pragma unroll
      for (int j = 0; j < 4; j++) {
        const int qabs = qrow0 + lg * 4 + j;
        float v = (kabs <= qabs) ? sc[kt][j] * inv : -INFINITY;
        sc[kt][j] = v;
        tmax[j] = fmaxf(tmax[j], v);
      }
    }
#pragma unroll
    for (int off = 1; off < 16; off <<= 1)
#pragma unroll
      for (int j = 0; j < 4; j++) tmax[j] = fmaxf(tmax[j], __shfl_xor(tmax[j], off, 16));

    float psum[4];
#pragma unroll
    for (int j = 0; j < 4; j++) {
      const float mnew = fmaxf(mrow[j], tmax[j]);
      const float alpha = __expf(mrow[j] - mnew);
      mrow[j] = mnew;
      dsum[j] *= alpha;
#pragma unroll
      for (int ni = 0; ni < 4; ni++) acc[ni][j] *= alpha;
      psum[j] = 0.f;
    }
#pragma unroll
    for (int kt = 0; kt < 4; kt++) {
      const int gsl = kt * 2 + (lane15 >> 3);
      const int ebyte = (lane15 & 7) * 2;
#pragma unroll
      for (int j = 0; j < 4; j++) {
        const float p = __expf(sc[kt][j] - mrow[j]);
        psum[j] += p;
        const int r = lg * 4 + j;
        *(unsigned short*)(pl + r * 128 + ((gsl ^ (r & 7)) << 4) + ebyte) = f2bf(p);
      }
    }
#pragma unroll
    for (int off = 1; off < 16; off <<= 1)
#pragma unroll
      for (int j = 0; j < 4; j++) psum[j] += __shfl_xor(psum[j], off, 16);
#pragma unroll
    for (int j = 0; j < 4; j++) dsum[j] += psum[j];

#pragma unroll
    for (int ks = 0; ks < 2; ks++) {
      bf16x8 pa = *(const bf16x8*)(pl + lane15 * 128 +
                                   ((((ks << 2) + lg) ^ (lane15 & 7)) << 4));
      const bf16* vp = vbase + k0 + ks * 32 + lg * 8;
#pragma unroll
      for (int ni = 0; ni < 4; ni++) {
        bf16x8 vf = *(const bf16x8*)(vp + (size_t)ni * 16 * S_);
        acc[ni] = __builtin_amdgcn_mfma_f32_16x16x32_bf16(pa, vf, acc[ni], 0, 0, 0);
      }
    }
  }

  const int r4 = lg * 4;
  if (lane15 < layer) {
    const int ml = lane15;
#pragma unroll
    for (int j = 0; j < 4; j++) {
      const size_t rowB = (size_t)(b * S_) + qrow0 + r4 + j;
      const bf16* qc = qkv + rowB * 2304 + 1536 + h * 64;
      const bf16* mk = memkv + ((size_t)ml * BS_ + rowB) * 1536 + h * 64;
      float d_ = 0.f;
#pragma unroll
      for (int t = 0; t < 8; t++) {
        bf16x8 qv = *(const bf16x8*)(qc + t * 8);
        bf16x8 kv = *(const bf16x8*)(mk + t * 8);
#pragma unroll
        for (int e = 0; e < 8; e++)
          d_ += bf2f((unsigned short)qv[e]) * bf2f((unsigned short)kv[e]);
      }
      wlp[w][r4 + j][ml] = d_ * inv;
    }
  }
  if (layer > 0) {
#pragma unroll
    for (int j = 0; j < 4; j++) {
      const int r = r4 + j;
      float mm = -INFINITY;
      for (int ml = 0; ml < layer; ml++) mm = fmaxf(mm, wlp[w][r][ml]);
      const float mnew = fmaxf(mrow[j], mm);
      const float alpha = __expf(mrow[j] - mnew);
      mrow[j] = mnew;
      dsum[j] *= alpha;
#pragma unroll
      for (int ni = 0; ni < 4; ni++) acc[ni][j] *= alpha;
      const size_t rowB = (size_t)(b * S_) + qrow0 + r;
      for (int ml = 0; ml < layer; ml++) {
        const float p = __expf(wlp[w][r][ml] - mnew);
        dsum[j] += p;
        const unsigned short* mv = (const unsigned short*)(memkv +
            ((size_t)ml * BS_ + rowB) * 1536 + 768 + h * 64 + lane15);
#pragma unroll
        for (int ni = 0; ni < 4; ni++)
          acc[ni][j] += p * bf2f(mv[ni * 16]);
      }
    }
  }

#pragma unroll
  for (int j = 0; j < 4; j++) {
    const float rd = 1.f / dsum[j];
    const size_t rowB = (size_t)(b * S_) + qrow0 + r4 + j;
    bf16* cp = ctx + rowB * 768 + h * 64 + lane15;
#pragma unroll
    for (int ni = 0; ni < 4; ni++)
      cp[ni * 16] = __float2bfloat16(acc[ni][j] * rd);
  }
}

// ---------------------------------------------------------------- launch
extern "C" void kernel_launch(void* const* d_in, const int* in_sizes, int n_in,
                              void* d_out, int out_size, void* d_ws, size_t ws_size,
                              hipStream_t stream) {
  const int*   tokens  = (const int*)d_in[0];
  const float* tok_emb = (const float*)d_in[1];
  const float* pos_emb = (const float*)d_in[2];
  const float *Wq_row, *Wk_row, *Wv_row, *Wq_col, *Wo;
  const float *bq_row, *bk_row, *bv_row, *bq_col, *bo;
  if (in_sizes[4] == L_ * D_ * D_) {  // dict order
    Wq_row = (const float*)d_in[3];  Wk_row = (const float*)d_in[4];
    Wv_row = (const float*)d_in[5];  Wq_col = (const float*)d_in[6];
    Wo     = (const float*)d_in[7];
    bq_row = (const float*)d_in[8];  bk_row = (const float*)d_in[9];
    bv_row = (const float*)d_in[10]; bq_col = (const float*)d_in[11];
    bo     = (const float*)d_in[12];
  } else {  // signature order fallback
    Wq_row = (const float*)d_in[3];  bq_row = (const float*)d_in[4];
    Wk_row = (const float*)d_in[5];  bk_row = (const float*)d_in[6];
    Wv_row = (const float*)d_in[7];  bv_row = (const float*)d_in[8];
    Wq_col = (const float*)d_in[9];  bq_col = (const float*)d_in[10];
    Wo     = (const float*)d_in[11]; bo     = (const float*)d_in[12];
  }
  const float* ln1_g = (const float*)d_in[13]; const float* ln1_b = (const float*)d_in[14];
  const float* ln2_g = (const float*)d_in[15]; const float* ln2_b = (const float*)d_in[16];
  const float* W1    = (const float*)d_in[17]; const float* b1    = (const float*)d_in[18];
  const float* W2    = (const float*)d_in[19]; const float* b2    = (const float*)d_in[20];
  const float* Wk_sh = (const float*)d_in[21]; const float* bk_sh = (const float*)d_in[22];
  const float* Wv_sh = (const float*)d_in[23]; const float* bv_sh = (const float*)d_in[24];
  const float* lnf_g = (const float*)d_in[25]; const float* lnf_b = (const float*)d_in[26];
  const float* Whead = (const float*)d_in[27]; const float* bhead = (const float*)d_in[28];

  // ---- workspace carve-up
  char* p = (char*)d_ws;
  float* x      = (float*)p; p += (size_t)BS_ * D_ * 4;
  bf16*  h_bf   = (bf16*)p;  p += (size_t)BS_ * D_ * 2;
  bf16*  qkv3   = (bf16*)p;  p += (size_t)BS_ * 2304 * 2;
  bf16*  vTb    = (bf16*)p;  p += (size_t)B_ * 768 * S_ * 2;
  bf16*  memkv  = (bf16*)p;  p += (size_t)L_ * BS_ * 1536 * 2;
  bf16*  ctx_bf = (bf16*)p;  p += (size_t)BS_ * D_ * 2;
  bf16*  mlp_bf = (bf16*)p;  p += (size_t)BS_ * DFF_ * 2;
  float* pkbuf  = (float*)p; p += (size_t)2 * BS_ * D_ * 4;   // split-K partials
  float* b6cat  = (float*)p; p += (size_t)L_ * 4608 * 4;
  bf16* tW6    = (bf16*)p; p += (size_t)L_ * 3072 * D_ * 2;   // q|k|qc|v rows
  bf16* tWsh   = (bf16*)p; p += (size_t)1536 * D_ * 2;        // ksh|vsh rows
  bf16* tWo    = (bf16*)p; p += (size_t)L_ * D_ * D_ * 2;
  bf16* tW1    = (bf16*)p; p += (size_t)L_ * DFF_ * D_ * 2;
  bf16* tW2    = (bf16*)p; p += (size_t)L_ * D_ * DFF_ * 2;
  bf16* tWhead = (bf16*)p; p += (size_t)V_ * D_ * 2;

  // ---- weight conversion (transposed bf16), bias concat
  dim3 tb(32, 8);
  const size_t DD = (size_t)D_ * D_;
  const size_t W6S = (size_t)3072 * 768;
  k_w2bf_t<<<dim3(24, 24, L_), tb, 0, stream>>>(Wq_row, tW6,              768, 768, DD, W6S);
  k_w2bf_t<<<dim3(24, 24, L_), tb, 0, stream>>>(Wk_row, tW6 + 768 * 768,  768, 768, DD, W6S);
  k_w2bf_t<<<dim3(24, 24, L_), tb, 0, stream>>>(Wq_col, tW6 + 1536 * 768, 768, 768, DD, W6S);
  k_w2bf_t<<<dim3(24, 24, L_), tb, 0, stream>>>(Wv_row, tW6 + 2304 * 768, 768, 768, DD, W6S);
  k_w2bf_t<<<dim3(24, 24, 1), tb, 0, stream>>>(Wk_sh, tWsh,             768, 768, 0, 0);
  k_w2bf_t<<<dim3(24, 24, 1), tb, 0, stream>>>(Wv_sh, tWsh + 768 * 768, 768, 768, 0, 0);
  k_w2bf_t<<<dim3(24, 24, L_), tb, 0, stream>>>(Wo,     tWo, 768, 768, DD, DD);
  k_w2bf_t<<<dim3(96, 24, L_), tb, 0, stream>>>(W1, tW1, 768, 3072, (size_t)768 * 3072, (size_t)3072 * 768);
  k_w2bf_t<<<dim3(24, 96, L_), tb, 0, stream>>>(W2, tW2, 3072, 768, (size_t)768 * 3072, (size_t)768 * 3072);
  k_w2bf_t<<<dim3(1000, 24, 1), tb, 0, stream>>>(Whead, tWhead, 768, 32000, 0, 0);
  k_bcat<<<dim3(144), 256, 0, stream>>>(bq_row, bk_row, bq_col, bv_row, bk_sh, bv_sh, b6cat);

  k_embed<<<dim3((BS_ * D_) / 256), 256, 0, stream>>>(tokens, tok_emb, pos_emb, x);

  for (int i = 0; i < L_; i++) {
    k_ln<<<dim3(BS_), 256, 0, stream>>>(x, ln1_g + i * D_, ln1_b + i * D_, h_bf);
    k_bgemm<128, 6, 1><<<dim3(576), 256, 0, stream>>>(
        h_bf, tW6 + (size_t)i * W6S, tWsh, b6cat + (size_t)i * 4608,
        nullptr, nullptr, qkv3, vTb, memkv + (size_t)i * BS_ * 1536,
        16, BS_, 4608, 768);
    k_attn<<<dim3(B_ * H_, S_ / 64), 256, 0, stream>>>(qkv3, vTb, memkv, ctx_bf, i);
    k_bgemm<64, 1, 1><<<dim3(192), 256, 0, stream>>>(
        ctx_bf, tWo + (size_t)i * DD, nullptr, bo + i * D_, x, x,
        nullptr, nullptr, nullptr, 32, BS_, 768, 768);
    k_ln<<<dim3(BS_), 256, 0, stream>>>(x, ln2_g + i * D_, ln2_b + i * D_, h_bf);
    k_bgemm<128, 2, 1><<<dim3(384), 256, 0, stream>>>(
        h_bf, tW1 + (size_t)i * 3072 * 768, nullptr, b1 + (size_t)i * DFF_,
        nullptr, nullptr, mlp_bf, nullptr, nullptr, 16, BS_, 3072, 768);
    k_bgemm<64, 7, 2><<<dim3(384), 256, 0, stream>>>(
        mlp_bf, tW2 + (size_t)i * 768 * 3072, nullptr, b2 + i * D_,
        nullptr, pkbuf, nullptr, nullptr, nullptr, 32, BS_, 768, 3072);
    k_red<<<dim3((BS_ * D_) / 1024), 256, 0, stream>>>(x, pkbuf, b2 + i * D_, D_);
  }
  k_ln<<<dim3(BS_), 256, 0, stream>>>(x, lnf_g, lnf_b, h_bf);
  k_head8<<<dim3(1000), 512, 0, stream>>>(h_bf, tWhead, bhead, (float*)d_out);
}

// Round 12
// 1637.892 us; speedup vs baseline: 1.2600x; 1.0816x over previous
//
#include <hip/hip_runtime.h>
#include <hip/hip_bf16.h>
#include <math.h>

#define L_   8
#define D_   768
#define H_   12
#define V_   32000
#define B_   2
#define S_   1024
#define HD_  64
#define BS_  2048      // B_*S_
#define DFF_ 3072      // MR*D

typedef __hip_bfloat16 bf16;
typedef __attribute__((ext_vector_type(8))) short bf16x8;
typedef __attribute__((ext_vector_type(4))) float f32x4;

// Balanced LDS slot swizzle for the 128x128 k_bgemm (BK=32, 4-slot rows)
#define CFUN(r) (((r) >> 1) & 3)

__device__ __forceinline__ void cp16(void* lds, const void* g) {
  __builtin_amdgcn_global_load_lds(
      (const __attribute__((address_space(1))) void*)g,
      (__attribute__((address_space(3))) void*)lds, 16, 0, 0);
}

__device__ __forceinline__ unsigned short f2bf(float v) {
  __hip_bfloat16 h = __float2bfloat16(v);
  return *reinterpret_cast<unsigned short*>(&h);
}
__device__ __forceinline__ float bf2f(unsigned short u) {
  return __uint_as_float(((unsigned)u) << 16);
}

// ---------------------------------------------------------------- embedding
__global__ __launch_bounds__(256) void k_embed(const int* __restrict__ tokens,
    const float* __restrict__ tok_emb, const float* __restrict__ pos_emb,
    float* __restrict__ x) {
  int idx = blockIdx.x * 256 + threadIdx.x;
  int row = idx / D_;
  int d   = idx - row * D_;
  int s   = row & (S_ - 1);
  int t   = tokens[row];
  x[idx] = tok_emb[(size_t)t * D_ + d] + pos_emb[(size_t)s * D_ + d];
}

// ---------------------------------------------------------------- layernorm -> bf16
__global__ __launch_bounds__(256) void k_ln(const float* __restrict__ x,
    const float* __restrict__ g, const float* __restrict__ b,
    bf16* __restrict__ out) {
  int row = blockIdx.x;
  const float* xr = x + (size_t)row * D_;
  int t = threadIdx.x;
  float v0 = xr[t], v1 = xr[t + 256], v2 = xr[t + 512];
  float s  = v0 + v1 + v2;
  float s2 = v0 * v0 + v1 * v1 + v2 * v2;
#pragma unroll
  for (int off = 32; off; off >>= 1) {
    s  += __shfl_down(s, off);
    s2 += __shfl_down(s2, off);
  }
  __shared__ float rs[4], rs2[4];
  __shared__ float mean_s, rstd_s;
  int wid = t >> 6;
  if ((t & 63) == 0) { rs[wid] = s; rs2[wid] = s2; }
  __syncthreads();
  if (t == 0) {
    float S1 = rs[0] + rs[1] + rs[2] + rs[3];
    float S2 = rs2[0] + rs2[1] + rs2[2] + rs2[3];
    float m  = S1 / D_;
    float var = S2 / D_ - m * m;
    mean_s = m;
    rstd_s = rsqrtf(var + 1e-5f);
  }
  __syncthreads();
  float m = mean_s, r = rstd_s;
  bf16* orow = out + (size_t)row * D_;
  orow[t]       = __float2bfloat16((v0 - m) * r * g[t]       + b[t]);
  orow[t + 256] = __float2bfloat16((v1 - m) * r * g[t + 256] + b[t + 256]);
  orow[t + 512] = __float2bfloat16((v2 - m) * r * g[t + 512] + b[t + 512]);
}

// ---------------------------------- fused split-K reduce + residual + LN
// x[row] += p0 + p1 + b2 ; out = LN(x[row]) * g + b   (one block per row)
__global__ __launch_bounds__(256) void k_redln(float* __restrict__ x,
    const float* __restrict__ pk, const float* __restrict__ b2,
    const float* __restrict__ g, const float* __restrict__ b,
    bf16* __restrict__ out) {
  const int row = blockIdx.x;
  const int t = threadIdx.x;
  const size_t base = (size_t)row * D_;
  const size_t MN = (size_t)BS_ * D_;
  float v0, v1, v2;
  {
    int c0 = t, c1 = t + 256, c2 = t + 512;
    v0 = x[base + c0] + pk[base + c0] + pk[MN + base + c0] + b2[c0];
    v1 = x[base + c1] + pk[base + c1] + pk[MN + base + c1] + b2[c1];
    v2 = x[base + c2] + pk[base + c2] + pk[MN + base + c2] + b2[c2];
    x[base + c0] = v0; x[base + c1] = v1; x[base + c2] = v2;
  }
  float s  = v0 + v1 + v2;
  float s2 = v0 * v0 + v1 * v1 + v2 * v2;
#pragma unroll
  for (int off = 32; off; off >>= 1) {
    s  += __shfl_down(s, off);
    s2 += __shfl_down(s2, off);
  }
  __shared__ float rs[4], rs2[4];
  __shared__ float mean_s, rstd_s;
  int wid = t >> 6;
  if ((t & 63) == 0) { rs[wid] = s; rs2[wid] = s2; }
  __syncthreads();
  if (t == 0) {
    float S1 = rs[0] + rs[1] + rs[2] + rs[3];
    float S2 = rs2[0] + rs2[1] + rs2[2] + rs2[3];
    float m  = S1 / D_;
    float var = S2 / D_ - m * m;
    mean_s = m;
    rstd_s = rsqrtf(var + 1e-5f);
  }
  __syncthreads();
  float m = mean_s, r = rstd_s;
  bf16* orow = out + base;
  orow[t]       = __float2bfloat16((v0 - m) * r * g[t]       + b[t]);
  orow[t + 256] = __float2bfloat16((v1 - m) * r * g[t + 256] + b[t + 256]);
  orow[t + 512] = __float2bfloat16((v2 - m) * r * g[t + 512] + b[t + 512]);
}

// ------------------------------------------------- weight convert + transpose
__global__ __launch_bounds__(256) void k_w2bf_t(const float* __restrict__ W,
    bf16* __restrict__ Wt, int K, int N, size_t ils, size_t ols) {
  __shared__ float t[32][33];
  const float* Wm = W + (size_t)blockIdx.z * ils;
  bf16* Wtm = Wt + (size_t)blockIdx.z * ols;
  int n0 = blockIdx.x * 32, k0 = blockIdx.y * 32;
  int tx = threadIdx.x;
  for (int i = threadIdx.y; i < 32; i += 8)
    t[i][tx] = Wm[(size_t)(k0 + i) * N + n0 + tx];
  __syncthreads();
  for (int i = threadIdx.y; i < 32; i += 8)
    Wtm[(size_t)(n0 + i) * K + k0 + tx] = __float2bfloat16(t[tx][i]);
}

// ---------------------------------------------------------------- bias concat
__global__ __launch_bounds__(256) void k_bcat(const float* __restrict__ bq,
    const float* __restrict__ bk, const float* __restrict__ bqc,
    const float* __restrict__ bv, const float* __restrict__ bksh,
    const float* __restrict__ bvsh, float* __restrict__ b6) {
  int idx = blockIdx.x * 256 + threadIdx.x;
  if (idx >= L_ * 4608) return;
  int l = idx / 4608, c = idx - l * 4608;
  float v = (c < 768)  ? bq[l * 768 + c]
          : (c < 1536) ? bk[l * 768 + c - 768]
          : (c < 2304) ? bqc[l * 768 + c - 1536]
          : (c < 3072) ? bv[l * 768 + c - 2304]
          : (c < 3840) ? bksh[c - 3072]
                       : bvsh[c - 3840];
  b6[idx] = v;
}

// ---------------------------------------------------------------- bf16 MFMA GEMM
// (per-layer GEMMs) BMx128 tile, BK=32, 3-buffer counted-vmcnt pipeline.
template <int BM, int EPI, int KSPL>
__global__ __launch_bounds__(256) void k_bgemm(
    const bf16* __restrict__ A, const bf16* __restrict__ Wt,
    const bf16* __restrict__ Wt2,
    const float* __restrict__ bias, const float* __restrict__ resid,
    float* __restrict__ Cf, bf16* __restrict__ Cb, bf16* __restrict__ Cb2,
    bf16* __restrict__ Cb3, int NM, int M, int N, int K) {
  constexpr int ASZ = BM * 64;
  constexpr int ALINES = BM / 64;
  constexpr int BSTRIDE = ASZ + 8192;
  constexpr int MF = BM / 32;
  __shared__ __align__(16) char smem[3 * BSTRIDE];
  const int tid = threadIdx.x;
  const int l = tid & 63, w = tid >> 6;
  const int wr = w >> 1, wc = w & 1;

  const int nwg = (int)gridDim.x;
  int id = (int)blockIdx.x;
  id = (id & 7) * (nwg >> 3) + (id >> 3);
  int sk = 0;
  if constexpr (KSPL == 2) {
    const int TT = nwg >> 1;
    sk = id / TT;
    id -= sk * TT;
  }
  const int m0 = (id % NM) * BM;
  const int n0 = (id / NM) * 128;
  const int kstart = sk * (K / KSPL);

  const int lane15 = l & 15, lg = l >> 4;

  const bf16* WB = Wt;
  int nb0 = n0;
  if constexpr (EPI == 6) {
    if (n0 >= 3072) { WB = Wt2; nb0 = n0 - 3072; }
  }

  const int r0 = tid >> 2, p0 = tid & 3;
  const char* aSrc[ALINES];
#pragma unroll
  for (int i = 0; i < ALINES; i++) {
    const int rr = i * 64 + r0;
    aSrc[i] = (const char*)(A + (size_t)(m0 + rr) * K + kstart) + ((p0 ^ CFUN(rr)) * 16);
  }
  const char* bSrc0 = (const char*)(WB + (size_t)(nb0 + r0) * K + kstart) + ((p0 ^ CFUN(r0)) * 16);
  const char* bSrc1 = (const char*)(WB + (size_t)(nb0 + 64 + r0) * K + kstart) + ((p0 ^ CFUN(64 + r0)) * 16);

  int aOff[MF], bOff[4];
#pragma unroll
  for (int mi = 0; mi < MF; mi++) {
    int r = wr * (BM / 2) + mi * 16 + lane15;
    aOff[mi] = r * 64 + ((lg ^ CFUN(r)) * 16);
  }
#pragma unroll
  for (int ni = 0; ni < 4; ni++) {
    int r = wc * 64 + ni * 16 + lane15;
    bOff[ni] = ASZ + r * 64 + ((lg ^ CFUN(r)) * 16);
  }

  f32x4 acc[MF][4];
#pragma unroll
  for (int mi = 0; mi < MF; mi++)
#pragma unroll
    for (int ni = 0; ni < 4; ni++) acc[mi][ni] = (f32x4){0.f, 0.f, 0.f, 0.f};

  auto stage = [&](int buf, int t) {
    const size_t kb = (size_t)t * 64;
    char* base = smem + buf * BSTRIDE;
#pragma unroll
    for (int i = 0; i < ALINES; i++)
      cp16(base + i * 4096 + w * 1024, aSrc[i] + kb);
    cp16(base + ASZ + w * 1024, bSrc0 + kb);
    cp16(base + ASZ + 4096 + w * 1024, bSrc1 + kb);
  };
  auto compute = [&](int buf) {
    const char* base = smem + buf * BSTRIDE;
    bf16x8 af[MF], bfr[4];
#pragma unroll
    for (int mi = 0; mi < MF; mi++) af[mi] = *(const bf16x8*)(base + aOff[mi]);
#pragma unroll
    for (int ni = 0; ni < 4; ni++) bfr[ni] = *(const bf16x8*)(base + bOff[ni]);
    __builtin_amdgcn_s_setprio(1);
#pragma unroll
    for (int mi = 0; mi < MF; mi++)
#pragma unroll
      for (int ni = 0; ni < 4; ni++)
        acc[mi][ni] = __builtin_amdgcn_mfma_f32_16x16x32_bf16(
            af[mi], bfr[ni], acc[mi][ni], 0, 0, 0);
    __builtin_amdgcn_s_setprio(0);
  };

  const int nk = (K / KSPL) >> 5;
  stage(0, 0);
  stage(1, 1);
  int buf = 0;
  for (int t = 0; t < nk; t++) {
    if (t + 1 < nk) {
      if constexpr (ALINES == 2) asm volatile("s_waitcnt vmcnt(4)" ::: "memory");
      else                       asm volatile("s_waitcnt vmcnt(3)" ::: "memory");
    } else {
      asm volatile("s_waitcnt vmcnt(0)" ::: "memory");
    }
    __builtin_amdgcn_s_barrier();
    if (t + 2 < nk) {
      int nb = buf + 2; if (nb >= 3) nb -= 3;
      stage(nb, t + 2);
    }
    compute(buf);
    buf = (buf == 2) ? 0 : buf + 1;
  }

#pragma unroll
  for (int ni = 0; ni < 4; ni++) {
    const int col = n0 + wc * 64 + ni * 16 + lane15;
    const float bv = bias[col];
#pragma unroll
    for (int mi = 0; mi < MF; mi++) {
      const int rowb = m0 + wr * (BM / 2) + mi * 16 + lg * 4;
      if constexpr (EPI == 6) {
        if (col < 2304) {
#pragma unroll
          for (int j = 0; j < 4; j++)
            Cb[(size_t)(rowb + j) * 2304 + col] = __float2bfloat16(acc[mi][ni][j] + bv);
        } else if (col < 3072) {
          ushort4 pk;
          pk.x = f2bf(acc[mi][ni][0] + bv);
          pk.y = f2bf(acc[mi][ni][1] + bv);
          pk.z = f2bf(acc[mi][ni][2] + bv);
          pk.w = f2bf(acc[mi][ni][3] + bv);
          const int bq = rowb >> 10, s = rowb & (S_ - 1);
          *reinterpret_cast<ushort4*>(
              (unsigned short*)Cb2 + ((size_t)(bq * 768 + (col - 2304))) * S_ + s) = pk;
        } else {
#pragma unroll
          for (int j = 0; j < 4; j++)
            Cb3[(size_t)(rowb + j) * 1536 + (col - 3072)] =
                __float2bfloat16(acc[mi][ni][j] + bv);
        }
      } else if constexpr (EPI == 7) {
#pragma unroll
        for (int j = 0; j < 4; j++)
          Cf[(size_t)sk * M * N + (size_t)(rowb + j) * N + col] = acc[mi][ni][j];
      } else {
#pragma unroll
        for (int j = 0; j < 4; j++) {
          const int row = rowb + j;
          float v = acc[mi][ni][j] + bv;
          if constexpr (EPI == 1) v += resid[(size_t)row * N + col];
          if constexpr (EPI == 2) {
            v = 0.5f * v * (1.0f + erff(v * 0.70710678118654752f));
            Cb[(size_t)row * N + col] = __float2bfloat16(v);
          } else if constexpr (EPI == 3) {
            Cb[(size_t)row * N + col] = __float2bfloat16(v);
          } else {
            Cf[(size_t)row * N + col] = v;
          }
        }
      }
    }
  }
}

// ------------------------------------------- head GEMM: 8-phase 256x256
#define HBAR() asm volatile("s_barrier" ::: "memory")
#define MFMA16(AF, BF, MB, NB)                                               \
  do {                                                                       \
    __builtin_amdgcn_s_setprio(1);                                           \
    _Pragma("unroll") for (int mi_ = 0; mi_ < 4; mi_++)                      \
      _Pragma("unroll") for (int ni_ = 0; ni_ < 2; ni_++)                    \
        _Pragma("unroll") for (int ks_ = 0; ks_ < 2; ks_++)                  \
          acc[(MB) + mi_][(NB) + ni_] =                                      \
              __builtin_amdgcn_mfma_f32_16x16x32_bf16(                       \
                  AF[mi_][ks_], BF[ni_][ks_], acc[(MB) + mi_][(NB) + ni_],   \
                  0, 0, 0);                                                  \
    __builtin_amdgcn_s_setprio(0);                                           \
  } while (0)

__global__ __launch_bounds__(512, 1) void k_head8(const bf16* __restrict__ A,
    const bf16* __restrict__ Wt, const float* __restrict__ bias,
    float* __restrict__ C) {
  __shared__ __align__(16) char smem[131072];
  const int tid = threadIdx.x;
  const int l = tid & 63, w = tid >> 6;
  const int wr = w >> 2, wc = w & 3;
  const int lane15 = l & 15, lg = l >> 4;

  int id = (int)blockIdx.x;
  id = (id & 7) * 125 + (id >> 3);
  const int m0 = (id % 8) * 256;
  const int n0 = (id / 8) * 256;

  auto issueA = [&](int tile, int hb) {
#pragma unroll
    for (int j = 0; j < 2; j++) {
      const int idx = j * 512 + tid;
      const int rl = idx >> 3, sl = idx & 7;
      const bf16* g = A + (size_t)(m0 + hb + rl) * 768 + tile * 64 +
                      ((sl ^ (rl & 7)) << 3);
      cp16(smem + (tile & 1) * 32768 + hb * 128 + (j * 512 + w * 64) * 16, g);
    }
  };
  auto issueB = [&](int tile, int hb) {
#pragma unroll
    for (int j = 0; j < 2; j++) {
      const int idx = j * 512 + tid;
      const int rl = idx >> 3, sl = idx & 7;
      const bf16* g = Wt + (size_t)(n0 + hb + rl) * 768 + tile * 64 +
                      ((sl ^ (rl & 7)) << 3);
      cp16(smem + 65536 + (tile & 1) * 32768 + hb * 128 + (j * 512 + w * 64) * 16, g);
    }
  };
  auto ldA = [&](int buf, int mi, int ks) {
    const int r = wr * 128 + mi * 16 + lane15;
    return *(const bf16x8*)(smem + buf * 32768 + r * 128 +
                            ((((ks << 2) + lg) ^ (r & 7)) << 4));
  };
  auto ldB = [&](int buf, int ni, int ks) {
    const int r = wc * 64 + ni * 16 + lane15;
    return *(const bf16x8*)(smem + 65536 + buf * 32768 + r * 128 +
                            ((((ks << 2) + lg) ^ (r & 7)) << 4));
  };

  f32x4 acc[8][4];
#pragma unroll
  for (int i = 0; i < 8; i++)
#pragma unroll
    for (int j = 0; j < 4; j++) acc[i][j] = (f32x4){0.f, 0.f, 0.f, 0.f};
  bf16x8 alo[4][2], ahi[4][2], blo[2][2], bhi[2][2];

  issueA(0, 0);  issueA(0, 128);  issueB(0, 0);  issueB(0, 128);
  issueB(1, 0);  issueA(1, 0);    issueB(1, 128);
  asm volatile("s_waitcnt vmcnt(6)" ::: "memory");
  HBAR();

  for (int it = 0; it < 5; ++it) {
    const int Tb = 2 * it + 1, Tn = 2 * it + 2;
#pragma unroll
    for (int mi = 0; mi < 4; mi++) { alo[mi][0] = ldA(0, mi, 0); alo[mi][1] = ldA(0, mi, 1); }
#pragma unroll
    for (int ni = 0; ni < 2; ni++) { blo[ni][0] = ldB(0, ni, 0); blo[ni][1] = ldB(0, ni, 1); }
    issueA(Tb, 128);
    HBAR(); MFMA16(alo, blo, 0, 0); HBAR();
#pragma unroll
    for (int ni = 0; ni < 2; ni++) { bhi[ni][0] = ldB(0, ni + 2, 0); bhi[ni][1] = ldB(0, ni + 2, 1); }
    HBAR(); MFMA16(alo, bhi, 0, 2); HBAR();
#pragma unroll
    for (int mi = 0; mi < 4; mi++) { ahi[mi][0] = ldA(0, mi + 4, 0); ahi[mi][1] = ldA(0, mi + 4, 1); }
    issueB(Tn, 0);
    HBAR(); MFMA16(ahi, bhi, 4, 2); HBAR();
    issueA(Tn, 0);
    issueB(Tn, 128);
    asm volatile("s_waitcnt vmcnt(6)" ::: "memory");
    HBAR(); MFMA16(ahi, blo, 4, 0); HBAR();
#pragma unroll
    for (int mi = 0; mi < 4; mi++) { alo[mi][0] = ldA(1, mi, 0); alo[mi][1] = ldA(1, mi, 1); }
#pragma unroll
    for (int ni = 0; ni < 2; ni++) { blo[ni][0] = ldB(1, ni, 0); blo[ni][1] = ldB(1, ni, 1); }
    issueA(Tn, 128);
    HBAR(); MFMA16(alo, blo, 0, 0); HBAR();
#pragma unroll
    for (int ni = 0; ni < 2; ni++) { bhi[ni][0] = ldB(1, ni + 2, 0); bhi[ni][1] = ldB(1, ni + 2, 1); }
    HBAR(); MFMA16(alo, bhi, 0, 2); HBAR();
#pragma unroll
    for (int mi = 0; mi < 4; mi++) { ahi[mi][0] = ldA(1, mi + 4, 0); ahi[mi][1] = ldA(1, mi + 4, 1); }
    issueB(Tn + 1, 0);
    HBAR(); MFMA16(ahi, bhi, 4, 2); HBAR();
    issueA(Tn + 1, 0);
    issueB(Tn + 1, 128);
    asm volatile("s_waitcnt vmcnt(6)" ::: "memory");
    HBAR(); MFMA16(ahi, blo, 4, 0); HBAR();
  }

  {
#pragma unroll
    for (int mi = 0; mi < 4; mi++) { alo[mi][0] = ldA(0, mi, 0); alo[mi][1] = ldA(0, mi, 1); }
#pragma unroll
    for (int ni = 0; ni < 2; ni++) { blo[ni][0] = ldB(0, ni, 0); blo[ni][1] = ldB(0, ni, 1); }
    issueA(11, 128);
    HBAR(); MFMA16(alo, blo, 0, 0); HBAR();
#pragma unroll
    for (int ni = 0; ni < 2; ni++) { bhi[ni][0] = ldB(0, ni + 2, 0); bhi[ni][1] = ldB(0, ni + 2, 1); }
    HBAR(); MFMA16(alo, bhi, 0, 2); HBAR();
#pragma unroll
    for (int mi = 0; mi < 4; mi++) { ahi[mi][0] = ldA(0, mi + 4, 0); ahi[mi][1] = ldA(0, mi + 4, 1); }
    HBAR(); MFMA16(ahi, bhi, 4, 2); HBAR();
    asm volatile("s_waitcnt vmcnt(0)" ::: "memory");
    HBAR(); MFMA16(ahi, blo, 4, 0); HBAR();
#pragma unroll
    for (int mi = 0; mi < 4; mi++) { alo[mi][0] = ldA(1, mi, 0); alo[mi][1] = ldA(1, mi, 1); }
#pragma unroll
    for (int ni = 0; ni < 2; ni++) { blo[ni][0] = ldB(1, ni, 0); blo[ni][1] = ldB(1, ni, 1); }
    MFMA16(alo, blo, 0, 0);
#pragma unroll
    for (int ni = 0; ni < 2; ni++) { bhi[ni][0] = ldB(1, ni + 2, 0); bhi[ni][1] = ldB(1, ni + 2, 1); }
    MFMA16(alo, bhi, 0, 2);
#pragma unroll
    for (int mi = 0; mi < 4; mi++) { ahi[mi][0] = ldA(1, mi + 4, 0); ahi[mi][1] = ldA(1, mi + 4, 1); }
    MFMA16(ahi, bhi, 4, 2);
    MFMA16(ahi, blo, 4, 0);
  }

#pragma unroll
  for (int ni = 0; ni < 4; ni++) {
    const int col = n0 + wc * 64 + ni * 16 + lane15;
    const float bv = bias[col];
#pragma unroll
    for (int mi = 0; mi < 8; mi++) {
      const int rowb = m0 + wr * 128 + mi * 16 + lg * 4;
#pragma unroll
      for (int j = 0; j < 4; j++)
        C[(size_t)(rowb + j) * 32000 + col] = acc[mi][ni][j] + bv;
    }
  }
}

// ---------------------------------------------------------------- flash attention
__global__ __launch_bounds__(256) void k_attn(
    const bf16* __restrict__ qkv, const bf16* __restrict__ vT,
    const bf16* __restrict__ memkv, bf16* __restrict__ ctx, int layer) {
  const int bh = blockIdx.x;
  const int b = bh / H_, h = bh % H_;
  const int qt = (int)gridDim.y - 1 - (int)blockIdx.y;   // big q first
  const int tid = threadIdx.x;
  const int w = tid >> 6, l = tid & 63;
  const int lane15 = l & 15, lg = l >> 4;
  const float inv = 0.125f;

  __shared__ char plds[4][2048];
  __shared__ float wlp[4][16][16];
  char* pl = plds[w];

  const int qrow0 = qt * 64 + w * 16;
  const size_t rowA = (size_t)(b * S_ + qrow0 + lane15);
  const bf16* qp = qkv + rowA * 2304 + h * 64 + lg * 8;
  // pre-scale Q by 1/sqrt(64) = 0.125 (power of two -> exact in bf16)
  auto scale8 = [](bf16x8 v) {
    bf16x8 r;
#pragma unroll
    for (int e = 0; e < 8; e++)
      r[e] = (short)f2bf(bf2f((unsigned short)v[e]) * 0.125f);
    return r;
  };
  const bf16x8 qf0 = scale8(*(const bf16x8*)(qp));
  const bf16x8 qf1 = scale8(*(const bf16x8*)(qp + 32));

  const bf16* kbase = qkv + (size_t)(b * S_) * 2304 + 768 + h * 64 + lg * 8;
  const bf16* vbase = vT + ((size_t)(b * 768 + h * 64 + lane15)) * S_;

  float mrow[4], dsum[4];
  f32x4 acc[4];
#pragma unroll
  for (int j = 0; j < 4; j++) { mrow[j] = -INFINITY; dsum[j] = 0.f; }
#pragma unroll
  for (int ni = 0; ni < 4; ni++) acc[ni] = (f32x4){0.f, 0.f, 0.f, 0.f};

  const int ntile = ((qrow0 + 15) >> 6) + 1;
  for (int kt64 = 0; kt64 < ntile; kt64++) {
    const int k0 = kt64 * 64;
    f32x4 sc[4];
#pragma unroll
    for (int kt = 0; kt < 4; kt++) {
      const bf16* kp = kbase + (size_t)(k0 + kt * 16 + lane15) * 2304;
      bf16x8 kf0 = *(const bf16x8*)(kp);
      bf16x8 kf1 = *(const bf16x8*)(kp + 32);
      f32x4 z = (f32x4){0.f, 0.f, 0.f, 0.f};
      z = __builtin_amdgcn_mfma_f32_16x16x32_bf16(qf0, kf0, z, 0, 0, 0);
      sc[kt] = __builtin_amdgcn_mfma_f32_16x16x32_bf16(qf1, kf1, z, 0, 0, 0);
    }
    float tmax[4];
#pragma unroll
    for (int j = 0; j < 4; j++) tmax[j] = -INFINITY;
    const bool needMask = (k0 + 63 > qrow0);     // wave-uniform: diagonal tile
    if (needMask) {
#pragma unroll
      for (int kt = 0; kt < 4; kt++) {
        const int kabs = k0 + kt * 16 + lane15;
#pragma unroll
        for (int j = 0; j < 4; j++) {
          const int qabs = qrow0 + lg * 4 + j;
          float v = (kabs <= qabs) ? sc[kt][j] : -INFINITY;
          sc[kt][j] = v;
          tmax[j] = fmaxf(tmax[j], v);
        }
      }
    } else {
#pragma unroll
      for (int kt = 0; kt < 4; kt++)
#pragma unroll
        for (int j = 0; j < 4; j++) tmax[j] = fmaxf(tmax[j], sc[kt][j]);
    }
#pragma unroll
    for (int off = 1; off < 16; off <<= 1)
#pragma unroll
      for (int j = 0; j < 4; j++) tmax[j] = fmaxf(tmax[j], __shfl_xor(tmax[j], off, 16));

    // defer-max: skip rescale when no row's max grows (wave-uniform)
    bool grow = false;
#pragma unroll
    for (int j = 0; j < 4; j++) grow |= (tmax[j] > mrow[j]);
    if (__ballot(grow) != 0ull) {
#pragma unroll
      for (int j = 0; j < 4; j++) {
        const float mnew = fmaxf(mrow[j], tmax[j]);
        const float alpha = __expf(mrow[j] - mnew);
        mrow[j] = mnew;
        dsum[j] *= alpha;
#pragma unroll
        for (int ni = 0; ni < 4; ni++) acc[ni][j] *= alpha;
      }
    }
    float psum[4] = {0.f, 0.f, 0.f, 0.f};
#pragma unroll
    for (int kt = 0; kt < 4; kt++) {
      const int gsl = kt * 2 + (lane15 >> 3);
      const int ebyte = (lane15 & 7) * 2;
#pragma unroll
      for (int j = 0; j < 4; j++) {
        const float p = __expf(sc[kt][j] - mrow[j]);
        psum[j] += p;
        const int r = lg * 4 + j;
        *(unsigned short*)(pl + r * 128 + ((gsl ^ (r & 7)) << 4) + ebyte) = f2bf(p);
      }
    }
#pragma unroll
    for (int off = 1; off < 16; off <<= 1)
#pragma unroll
      for (int j = 0; j < 4; j++) psum[j] += __shfl_xor(psum[j], off, 16);
#pragma unroll
    for (int j = 0; j < 4; j++) dsum[j] += psum[j];

#pragma unroll
    for (int ks = 0; ks < 2; ks++) {
      bf16x8 pa = *(const bf16x8*)(pl + lane15 * 128 +
                                   ((((ks << 2) + lg) ^ (lane15 & 7)) << 4));
      const bf16* vp = vbase + k0 + ks * 32 + lg * 8;
#pragma unroll
      for (int ni = 0; ni < 4; ni++) {
        bf16x8 vf = *(const bf16x8*)(vp + (size_t)ni * 16 * S_);
        acc[ni] = __builtin_amdgcn_mfma_f32_16x16x32_bf16(pa, vf, acc[ni], 0, 0, 0);
      }
    }
  }

  const int r4 = lg * 4;
  if (lane15 < layer) {
    const int ml = lane15;
#pragma unroll
    for (int j = 0; j < 4; j++) {
      const size_t rowB = (size_t)(b * S_) + qrow0 + r4 + j;
      const bf16* qc = qkv + rowB * 2304 + 1536 + h * 64;
      const bf16* mk = memkv + ((size_t)ml * BS_ + rowB) * 1536 + h * 64;
      float d_ = 0.f;
#pragma unroll
      for (int t = 0; t < 8; t++) {
        bf16x8 qv = *(const bf16x8*)(qc + t * 8);
        bf16x8 kv = *(const bf16x8*)(mk + t * 8);
#pragma unroll
        for (int e = 0; e < 8; e++)
          d_ += bf2f((unsigned short)qv[e]) * bf2f((unsigned short)kv[e]);
      }
      wlp[w][r4 + j][ml] = d_ * inv;
    }
  }
  if (layer > 0) {
#pragma unroll
    for (int j = 0; j < 4; j++) {
      const int r = r4 + j;
      float mm = -INFINITY;
      for (int ml = 0; ml < layer; ml++) mm = fmaxf(mm, wlp[w][r][ml]);
      const float mnew = fmaxf(mrow[j], mm);
      const float alpha = __expf(mrow[j] - mnew);
      mrow[j] = mnew;
      dsum[j] *= alpha;
#pragma unroll
      for (int ni = 0; ni < 4; ni++) acc[ni][j] *= alpha;
      const size_t rowB = (size_t)(b * S_) + qrow0 + r;
      for (int ml = 0; ml < layer; ml++) {
        const float p = __expf(wlp[w][r][ml] - mnew);
        dsum[j] += p;
        const unsigned short* mv = (const unsigned short*)(memkv +
            ((size_t)ml * BS_ + rowB) * 1536 + 768 + h * 64 + lane15);
#pragma unroll
        for (int ni = 0; ni < 4; ni++)
          acc[ni][j] += p * bf2f(mv[ni * 16]);
      }
    }
  }

#pragma unroll
  for (int j = 0; j < 4; j++) {
    const float rd = 1.f / dsum[j];
    const size_t rowB = (size_t)(b * S_) + qrow0 + r4 + j;
    bf16* cp = ctx + rowB * 768 + h * 64 + lane15;
#pragma unroll
    for (int ni = 0; ni < 4; ni++)
      cp[ni * 16] = __float2bfloat16(acc[ni][j] * rd);
  }
}

// ---------------------------------------------------------------- launch
extern "C" void kernel_launch(void* const* d_in, const int* in_sizes, int n_in,
                              void* d_out, int out_size, void* d_ws, size_t ws_size,
                              hipStream_t stream) {
  const int*   tokens  = (const int*)d_in[0];
  const float* tok_emb = (const float*)d_in[1];
  const float* pos_emb = (const float*)d_in[2];
  const float *Wq_row, *Wk_row, *Wv_row, *Wq_col, *Wo;
  const float *bq_row, *bk_row, *bv_row, *bq_col, *bo;
  if (in_sizes[4] == L_ * D_ * D_) {  // dict order
    Wq_row = (const float*)d_in[3];  Wk_row = (const float*)d_in[4];
    Wv_row = (const float*)d_in[5];  Wq_col = (const float*)d_in[6];
    Wo     = (const float*)d_in[7];
    bq_row = (const float*)d_in[8];  bk_row = (const float*)d_in[9];
    bv_row = (const float*)d_in[10]; bq_col = (const float*)d_in[11];
    bo     = (const float*)d_in[12];
  } else {  // signature order fallback
    Wq_row = (const float*)d_in[3];  bq_row = (const float*)d_in[4];
    Wk_row = (const float*)d_in[5];  bk_row = (const float*)d_in[6];
    Wv_row = (const float*)d_in[7];  bv_row = (const float*)d_in[8];
    Wq_col = (const float*)d_in[9];  bq_col = (const float*)d_in[10];
    Wo     = (const float*)d_in[11]; bo     = (const float*)d_in[12];
  }
  const float* ln1_g = (const float*)d_in[13]; const float* ln1_b = (const float*)d_in[14];
  const float* ln2_g = (const float*)d_in[15]; const float* ln2_b = (const float*)d_in[16];
  const float* W1    = (const float*)d_in[17]; const float* b1    = (const float*)d_in[18];
  const float* W2    = (const float*)d_in[19]; const float* b2    = (const float*)d_in[20];
  const float* Wk_sh = (const float*)d_in[21]; const float* bk_sh = (const float*)d_in[22];
  const float* Wv_sh = (const float*)d_in[23]; const float* bv_sh = (const float*)d_in[24];
  const float* lnf_g = (const float*)d_in[25]; const float* lnf_b = (const float*)d_in[26];
  const float* Whead = (const float*)d_in[27]; const float* bhead = (const float*)d_in[28];

  // ---- workspace carve-up
  char* p = (char*)d_ws;
  float* x      = (float*)p; p += (size_t)BS_ * D_ * 4;
  bf16*  h_bf   = (bf16*)p;  p += (size_t)BS_ * D_ * 2;
  bf16*  qkv3   = (bf16*)p;  p += (size_t)BS_ * 2304 * 2;
  bf16*  vTb    = (bf16*)p;  p += (size_t)B_ * 768 * S_ * 2;
  bf16*  memkv  = (bf16*)p;  p += (size_t)L_ * BS_ * 1536 * 2;
  bf16*  ctx_bf = (bf16*)p;  p += (size_t)BS_ * D_ * 2;
  bf16*  mlp_bf = (bf16*)p;  p += (size_t)BS_ * DFF_ * 2;
  float* pkbuf  = (float*)p; p += (size_t)2 * BS_ * D_ * 4;   // split-K partials
  float* b6cat  = (float*)p; p += (size_t)L_ * 4608 * 4;
  bf16* tW6    = (bf16*)p; p += (size_t)L_ * 3072 * D_ * 2;   // q|k|qc|v rows
  bf16* tWsh   = (bf16*)p; p += (size_t)1536 * D_ * 2;        // ksh|vsh rows
  bf16* tWo    = (bf16*)p; p += (size_t)L_ * D_ * D_ * 2;
  bf16* tW1    = (bf16*)p; p += (size_t)L_ * DFF_ * D_ * 2;
  bf16* tW2    = (bf16*)p; p += (size_t)L_ * D_ * DFF_ * 2;
  bf16* tWhead = (bf16*)p; p += (size_t)V_ * D_ * 2;

  // ---- weight conversion (transposed bf16), bias concat
  dim3 tb(32, 8);
  const size_t DD = (size_t)D_ * D_;
  const size_t W6S = (size_t)3072 * 768;
  k_w2bf_t<<<dim3(24, 24, L_), tb, 0, stream>>>(Wq_row, tW6,              768, 768, DD, W6S);
  k_w2bf_t<<<dim3(24, 24, L_), tb, 0, stream>>>(Wk_row, tW6 + 768 * 768,  768, 768, DD, W6S);
  k_w2bf_t<<<dim3(24, 24, L_), tb, 0, stream>>>(Wq_col, tW6 + 1536 * 768, 768, 768, DD, W6S);
  k_w2bf_t<<<dim3(24, 24, L_), tb, 0, stream>>>(Wv_row, tW6 + 2304 * 768, 768, 768, DD, W6S);
  k_w2bf_t<<<dim3(24, 24, 1), tb, 0, stream>>>(Wk_sh, tWsh,             768, 768, 0, 0);
  k_w2bf_t<<<dim3(24, 24, 1), tb, 0, stream>>>(Wv_sh, tWsh + 768 * 768, 768, 768, 0, 0);
  k_w2bf_t<<<dim3(24, 24, L_), tb, 0, stream>>>(Wo,     tWo, 768, 768, DD, DD);
  k_w2bf_t<<<dim3(96, 24, L_), tb, 0, stream>>>(W1, tW1, 768, 3072, (size_t)768 * 3072, (size_t)3072 * 768);
  k_w2bf_t<<<dim3(24, 96, L_), tb, 0, stream>>>(W2, tW2, 3072, 768, (size_t)768 * 3072, (size_t)768 * 3072);
  k_w2bf_t<<<dim3(1000, 24, 1), tb, 0, stream>>>(Whead, tWhead, 768, 32000, 0, 0);
  k_bcat<<<dim3(144), 256, 0, stream>>>(bq_row, bk_row, bq_col, bv_row, bk_sh, bv_sh, b6cat);

  k_embed<<<dim3((BS_ * D_) / 256), 256, 0, stream>>>(tokens, tok_emb, pos_emb, x);
  k_ln<<<dim3(BS_), 256, 0, stream>>>(x, ln1_g, ln1_b, h_bf);   // layer-0 ln1

  for (int i = 0; i < L_; i++) {
    k_bgemm<128, 6, 1><<<dim3(576), 256, 0, stream>>>(
        h_bf, tW6 + (size_t)i * W6S, tWsh, b6cat + (size_t)i * 4608,
        nullptr, nullptr, qkv3, vTb, memkv + (size_t)i * BS_ * 1536,
        16, BS_, 4608, 768);
    k_attn<<<dim3(B_ * H_, S_ / 64), 256, 0, stream>>>(qkv3, vTb, memkv, ctx_bf, i);
    k_bgemm<64, 1, 1><<<dim3(192), 256, 0, stream>>>(
        ctx_bf, tWo + (size_t)i * DD, nullptr, bo + i * D_, x, x,
        nullptr, nullptr, nullptr, 32, BS_, 768, 768);
    k_ln<<<dim3(BS_), 256, 0, stream>>>(x, ln2_g + i * D_, ln2_b + i * D_, h_bf);
    k_bgemm<128, 2, 1><<<dim3(384), 256, 0, stream>>>(
        h_bf, tW1 + (size_t)i * 3072 * 768, nullptr, b1 + (size_t)i * DFF_,
        nullptr, nullptr, mlp_bf, nullptr, nullptr, 16, BS_, 3072, 768);
    k_bgemm<64, 7, 2><<<dim3(384), 256, 0, stream>>>(
        mlp_bf, tW2 + (size_t)i * 768 * 3072, nullptr, b2 + i * D_,
        nullptr, pkbuf, nullptr, nullptr, nullptr, 32, BS_, 768, 3072);
    // fused: x += p0+p1+b2 ; h_bf = LN(x) with next layer's ln1 (or lnf)
    const float* gn = (i < L_ - 1) ? (ln1_g + (i + 1) * D_) : lnf_g;
    const float* bn = (i < L_ - 1) ? (ln1_b + (i + 1) * D_) : lnf_b;
    k_redln<<<dim3(BS_), 256, 0, stream>>>(x, pkbuf, b2 + i * D_, gn, bn, h_bf);
  }
  k_head8<<<dim3(1000), 512, 0, stream>>>(h_bf, tWhead, bhead, (float*)d_out);
}

// Round 13
// 1637.261 us; speedup vs baseline: 1.2605x; 1.0004x over previous
//
#include <hip/hip_runtime.h>
#include <hip/hip_bf16.h>
#include <math.h>

#define L_   8
#define D_   768
#define H_   12
#define V_   32000
#define B_   2
#define S_   1024
#define HD_  64
#define BS_  2048      // B_*S_
#define DFF_ 3072      // MR*D

typedef __hip_bfloat16 bf16;
typedef __attribute__((ext_vector_type(8))) short bf16x8;
typedef __attribute__((ext_vector_type(4))) float f32x4;

// Balanced LDS slot swizzle for the 128x128 k_bgemm (BK=32, 4-slot rows)
#define CFUN(r) (((r) >> 1) & 3)

__device__ __forceinline__ void cp16(void* lds, const void* g) {
  __builtin_amdgcn_global_load_lds(
      (const __attribute__((address_space(1))) void*)g,
      (__attribute__((address_space(3))) void*)lds, 16, 0, 0);
}

__device__ __forceinline__ unsigned short f2bf(float v) {
  __hip_bfloat16 h = __float2bfloat16(v);
  return *reinterpret_cast<unsigned short*>(&h);
}
__device__ __forceinline__ float bf2f(unsigned short u) {
  return __uint_as_float(((unsigned)u) << 16);
}

// ---------------------------------------------------------------- embedding
__global__ __launch_bounds__(256) void k_embed(const int* __restrict__ tokens,
    const float* __restrict__ tok_emb, const float* __restrict__ pos_emb,
    float* __restrict__ x) {
  int idx = blockIdx.x * 256 + threadIdx.x;
  int row = idx / D_;
  int d   = idx - row * D_;
  int s   = row & (S_ - 1);
  int t   = tokens[row];
  x[idx] = tok_emb[(size_t)t * D_ + d] + pos_emb[(size_t)s * D_ + d];
}

// ---------------------------------------------------------------- layernorm -> bf16
__global__ __launch_bounds__(256) void k_ln(const float* __restrict__ x,
    const float* __restrict__ g, const float* __restrict__ b,
    bf16* __restrict__ out) {
  int row = blockIdx.x;
  const float* xr = x + (size_t)row * D_;
  int t = threadIdx.x;
  float v0 = xr[t], v1 = xr[t + 256], v2 = xr[t + 512];
  float s  = v0 + v1 + v2;
  float s2 = v0 * v0 + v1 * v1 + v2 * v2;
#pragma unroll
  for (int off = 32; off; off >>= 1) {
    s  += __shfl_down(s, off);
    s2 += __shfl_down(s2, off);
  }
  __shared__ float rs[4], rs2[4];
  __shared__ float mean_s, rstd_s;
  int wid = t >> 6;
  if ((t & 63) == 0) { rs[wid] = s; rs2[wid] = s2; }
  __syncthreads();
  if (t == 0) {
    float S1 = rs[0] + rs[1] + rs[2] + rs[3];
    float S2 = rs2[0] + rs2[1] + rs2[2] + rs2[3];
    float m  = S1 / D_;
    float var = S2 / D_ - m * m;
    mean_s = m;
    rstd_s = rsqrtf(var + 1e-5f);
  }
  __syncthreads();
  float m = mean_s, r = rstd_s;
  bf16* orow = out + (size_t)row * D_;
  orow[t]       = __float2bfloat16((v0 - m) * r * g[t]       + b[t]);
  orow[t + 256] = __float2bfloat16((v1 - m) * r * g[t + 256] + b[t + 256]);
  orow[t + 512] = __float2bfloat16((v2 - m) * r * g[t + 512] + b[t + 512]);
}

// ---------------------------------- fused split-K reduce + residual + LN
// x[row] += p0 + p1 + bias ; out = LN(x[row]) * g + b   (one block per row)
__global__ __launch_bounds__(256) void k_redln(float* __restrict__ x,
    const float* __restrict__ pk, const float* __restrict__ b2,
    const float* __restrict__ g, const float* __restrict__ b,
    bf16* __restrict__ out) {
  const int row = blockIdx.x;
  const int t = threadIdx.x;
  const size_t base = (size_t)row * D_;
  const size_t MN = (size_t)BS_ * D_;
  float v0, v1, v2;
  {
    int c0 = t, c1 = t + 256, c2 = t + 512;
    v0 = x[base + c0] + pk[base + c0] + pk[MN + base + c0] + b2[c0];
    v1 = x[base + c1] + pk[base + c1] + pk[MN + base + c1] + b2[c1];
    v2 = x[base + c2] + pk[base + c2] + pk[MN + base + c2] + b2[c2];
    x[base + c0] = v0; x[base + c1] = v1; x[base + c2] = v2;
  }
  float s  = v0 + v1 + v2;
  float s2 = v0 * v0 + v1 * v1 + v2 * v2;
#pragma unroll
  for (int off = 32; off; off >>= 1) {
    s  += __shfl_down(s, off);
    s2 += __shfl_down(s2, off);
  }
  __shared__ float rs[4], rs2[4];
  __shared__ float mean_s, rstd_s;
  int wid = t >> 6;
  if ((t & 63) == 0) { rs[wid] = s; rs2[wid] = s2; }
  __syncthreads();
  if (t == 0) {
    float S1 = rs[0] + rs[1] + rs[2] + rs[3];
    float S2 = rs2[0] + rs2[1] + rs2[2] + rs2[3];
    float m  = S1 / D_;
    float var = S2 / D_ - m * m;
    mean_s = m;
    rstd_s = rsqrtf(var + 1e-5f);
  }
  __syncthreads();
  float m = mean_s, r = rstd_s;
  bf16* orow = out + base;
  orow[t]       = __float2bfloat16((v0 - m) * r * g[t]       + b[t]);
  orow[t + 256] = __float2bfloat16((v1 - m) * r * g[t + 256] + b[t + 256]);
  orow[t + 512] = __float2bfloat16((v2 - m) * r * g[t + 512] + b[t + 512]);
}

// ------------------------------------------------- weight convert + transpose
__global__ __launch_bounds__(256) void k_w2bf_t(const float* __restrict__ W,
    bf16* __restrict__ Wt, int K, int N, size_t ils, size_t ols) {
  __shared__ float t[32][33];
  const float* Wm = W + (size_t)blockIdx.z * ils;
  bf16* Wtm = Wt + (size_t)blockIdx.z * ols;
  int n0 = blockIdx.x * 32, k0 = blockIdx.y * 32;
  int tx = threadIdx.x;
  for (int i = threadIdx.y; i < 32; i += 8)
    t[i][tx] = Wm[(size_t)(k0 + i) * N + n0 + tx];
  __syncthreads();
  for (int i = threadIdx.y; i < 32; i += 8)
    Wtm[(size_t)(n0 + i) * K + k0 + tx] = __float2bfloat16(t[tx][i]);
}

// ---------------------------------------------------------------- bias concat
__global__ __launch_bounds__(256) void k_bcat(const float* __restrict__ bq,
    const float* __restrict__ bk, const float* __restrict__ bqc,
    const float* __restrict__ bv, const float* __restrict__ bksh,
    const float* __restrict__ bvsh, float* __restrict__ b6) {
  int idx = blockIdx.x * 256 + threadIdx.x;
  if (idx >= L_ * 4608) return;
  int l = idx / 4608, c = idx - l * 4608;
  float v = (c < 768)  ? bq[l * 768 + c]
          : (c < 1536) ? bk[l * 768 + c - 768]
          : (c < 2304) ? bqc[l * 768 + c - 1536]
          : (c < 3072) ? bv[l * 768 + c - 2304]
          : (c < 3840) ? bksh[c - 3072]
                       : bvsh[c - 3840];
  b6[idx] = v;
}

// ---------------------------------------------------------------- bf16 MFMA GEMM
// (per-layer GEMMs) BMx128 tile, BK=32, 3-buffer counted-vmcnt pipeline.
template <int BM, int EPI, int KSPL>
__global__ __launch_bounds__(256) void k_bgemm(
    const bf16* __restrict__ A, const bf16* __restrict__ Wt,
    const bf16* __restrict__ Wt2,
    const float* __restrict__ bias, const float* __restrict__ resid,
    float* __restrict__ Cf, bf16* __restrict__ Cb, bf16* __restrict__ Cb2,
    bf16* __restrict__ Cb3, int NM, int M, int N, int K) {
  constexpr int ASZ = BM * 64;
  constexpr int ALINES = BM / 64;
  constexpr int BSTRIDE = ASZ + 8192;
  constexpr int MF = BM / 32;
  __shared__ __align__(16) char smem[3 * BSTRIDE];
  const int tid = threadIdx.x;
  const int l = tid & 63, w = tid >> 6;
  const int wr = w >> 1, wc = w & 1;

  const int nwg = (int)gridDim.x;
  int id = (int)blockIdx.x;
  id = (id & 7) * (nwg >> 3) + (id >> 3);
  int sk = 0;
  if constexpr (KSPL == 2) {
    const int TT = nwg >> 1;
    sk = id / TT;
    id -= sk * TT;
  }
  const int m0 = (id % NM) * BM;
  const int n0 = (id / NM) * 128;
  const int kstart = sk * (K / KSPL);

  const int lane15 = l & 15, lg = l >> 4;

  const bf16* WB = Wt;
  int nb0 = n0;
  if constexpr (EPI == 6) {
    if (n0 >= 3072) { WB = Wt2; nb0 = n0 - 3072; }
  }

  const int r0 = tid >> 2, p0 = tid & 3;
  const char* aSrc[ALINES];
#pragma unroll
  for (int i = 0; i < ALINES; i++) {
    const int rr = i * 64 + r0;
    aSrc[i] = (const char*)(A + (size_t)(m0 + rr) * K + kstart) + ((p0 ^ CFUN(rr)) * 16);
  }
  const char* bSrc0 = (const char*)(WB + (size_t)(nb0 + r0) * K + kstart) + ((p0 ^ CFUN(r0)) * 16);
  const char* bSrc1 = (const char*)(WB + (size_t)(nb0 + 64 + r0) * K + kstart) + ((p0 ^ CFUN(64 + r0)) * 16);

  int aOff[MF], bOff[4];
#pragma unroll
  for (int mi = 0; mi < MF; mi++) {
    int r = wr * (BM / 2) + mi * 16 + lane15;
    aOff[mi] = r * 64 + ((lg ^ CFUN(r)) * 16);
  }
#pragma unroll
  for (int ni = 0; ni < 4; ni++) {
    int r = wc * 64 + ni * 16 + lane15;
    bOff[ni] = ASZ + r * 64 + ((lg ^ CFUN(r)) * 16);
  }

  f32x4 acc[MF][4];
#pragma unroll
  for (int mi = 0; mi < MF; mi++)
#pragma unroll
    for (int ni = 0; ni < 4; ni++) acc[mi][ni] = (f32x4){0.f, 0.f, 0.f, 0.f};

  auto stage = [&](int buf, int t) {
    const size_t kb = (size_t)t * 64;
    char* base = smem + buf * BSTRIDE;
#pragma unroll
    for (int i = 0; i < ALINES; i++)
      cp16(base + i * 4096 + w * 1024, aSrc[i] + kb);
    cp16(base + ASZ + w * 1024, bSrc0 + kb);
    cp16(base + ASZ + 4096 + w * 1024, bSrc1 + kb);
  };
  auto compute = [&](int buf) {
    const char* base = smem + buf * BSTRIDE;
    bf16x8 af[MF], bfr[4];
#pragma unroll
    for (int mi = 0; mi < MF; mi++) af[mi] = *(const bf16x8*)(base + aOff[mi]);
#pragma unroll
    for (int ni = 0; ni < 4; ni++) bfr[ni] = *(const bf16x8*)(base + bOff[ni]);
    __builtin_amdgcn_s_setprio(1);
#pragma unroll
    for (int mi = 0; mi < MF; mi++)
#pragma unroll
      for (int ni = 0; ni < 4; ni++)
        acc[mi][ni] = __builtin_amdgcn_mfma_f32_16x16x32_bf16(
            af[mi], bfr[ni], acc[mi][ni], 0, 0, 0);
    __builtin_amdgcn_s_setprio(0);
  };

  const int nk = (K / KSPL) >> 5;
  stage(0, 0);
  stage(1, 1);
  int buf = 0;
  for (int t = 0; t < nk; t++) {
    if (t + 1 < nk) {
      if constexpr (ALINES == 2) asm volatile("s_waitcnt vmcnt(4)" ::: "memory");
      else                       asm volatile("s_waitcnt vmcnt(3)" ::: "memory");
    } else {
      asm volatile("s_waitcnt vmcnt(0)" ::: "memory");
    }
    __builtin_amdgcn_s_barrier();
    if (t + 2 < nk) {
      int nb = buf + 2; if (nb >= 3) nb -= 3;
      stage(nb, t + 2);
    }
    compute(buf);
    buf = (buf == 2) ? 0 : buf + 1;
  }

#pragma unroll
  for (int ni = 0; ni < 4; ni++) {
    const int col = n0 + wc * 64 + ni * 16 + lane15;
    const float bv = bias[col];
#pragma unroll
    for (int mi = 0; mi < MF; mi++) {
      const int rowb = m0 + wr * (BM / 2) + mi * 16 + lg * 4;
      if constexpr (EPI == 6) {
        if (col < 2304) {
#pragma unroll
          for (int j = 0; j < 4; j++)
            Cb[(size_t)(rowb + j) * 2304 + col] = __float2bfloat16(acc[mi][ni][j] + bv);
        } else if (col < 3072) {
          ushort4 pk;
          pk.x = f2bf(acc[mi][ni][0] + bv);
          pk.y = f2bf(acc[mi][ni][1] + bv);
          pk.z = f2bf(acc[mi][ni][2] + bv);
          pk.w = f2bf(acc[mi][ni][3] + bv);
          const int bq = rowb >> 10, s = rowb & (S_ - 1);
          *reinterpret_cast<ushort4*>(
              (unsigned short*)Cb2 + ((size_t)(bq * 768 + (col - 2304))) * S_ + s) = pk;
        } else {
#pragma unroll
          for (int j = 0; j < 4; j++)
            Cb3[(size_t)(rowb + j) * 1536 + (col - 3072)] =
                __float2bfloat16(acc[mi][ni][j] + bv);
        }
      } else if constexpr (EPI == 7) {
#pragma unroll
        for (int j = 0; j < 4; j++)
          Cf[(size_t)sk * M * N + (size_t)(rowb + j) * N + col] = acc[mi][ni][j];
      } else {
#pragma unroll
        for (int j = 0; j < 4; j++) {
          const int row = rowb + j;
          float v = acc[mi][ni][j] + bv;
          if constexpr (EPI == 1) v += resid[(size_t)row * N + col];
          if constexpr (EPI == 2) {
            v = 0.5f * v * (1.0f + erff(v * 0.70710678118654752f));
            Cb[(size_t)row * N + col] = __float2bfloat16(v);
          } else if constexpr (EPI == 3) {
            Cb[(size_t)row * N + col] = __float2bfloat16(v);
          } else {
            Cf[(size_t)row * N + col] = v;
          }
        }
      }
    }
  }
}

// ------------------------------------------- head GEMM: 8-phase 256x256
#define HBAR() asm volatile("s_barrier" ::: "memory")
#define MFMA16(AF, BF, MB, NB)                                               \
  do {                                                                       \
    __builtin_amdgcn_s_setprio(1);                                           \
    _Pragma("unroll") for (int mi_ = 0; mi_ < 4; mi_++)                      \
      _Pragma("unroll") for (int ni_ = 0; ni_ < 2; ni_++)                    \
        _Pragma("unroll") for (int ks_ = 0; ks_ < 2; ks_++)                  \
          acc[(MB) + mi_][(NB) + ni_] =                                      \
              __builtin_amdgcn_mfma_f32_16x16x32_bf16(                       \
                  AF[mi_][ks_], BF[ni_][ks_], acc[(MB) + mi_][(NB) + ni_],   \
                  0, 0, 0);                                                  \
    __builtin_amdgcn_s_setprio(0);                                           \
  } while (0)

__global__ __launch_bounds__(512, 1) void k_head8(const bf16* __restrict__ A,
    const bf16* __restrict__ Wt, const float* __restrict__ bias,
    float* __restrict__ C) {
  __shared__ __align__(16) char smem[131072];
  const int tid = threadIdx.x;
  const int l = tid & 63, w = tid >> 6;
  const int wr = w >> 2, wc = w & 3;
  const int lane15 = l & 15, lg = l >> 4;

  int id = (int)blockIdx.x;
  id = (id & 7) * 125 + (id >> 3);
  const int m0 = (id % 8) * 256;
  const int n0 = (id / 8) * 256;

  auto issueA = [&](int tile, int hb) {
#pragma unroll
    for (int j = 0; j < 2; j++) {
      const int idx = j * 512 + tid;
      const int rl = idx >> 3, sl = idx & 7;
      const bf16* g = A + (size_t)(m0 + hb + rl) * 768 + tile * 64 +
                      ((sl ^ (rl & 7)) << 3);
      cp16(smem + (tile & 1) * 32768 + hb * 128 + (j * 512 + w * 64) * 16, g);
    }
  };
  auto issueB = [&](int tile, int hb) {
#pragma unroll
    for (int j = 0; j < 2; j++) {
      const int idx = j * 512 + tid;
      const int rl = idx >> 3, sl = idx & 7;
      const bf16* g = Wt + (size_t)(n0 + hb + rl) * 768 + tile * 64 +
                      ((sl ^ (rl & 7)) << 3);
      cp16(smem + 65536 + (tile & 1) * 32768 + hb * 128 + (j * 512 + w * 64) * 16, g);
    }
  };
  auto ldA = [&](int buf, int mi, int ks) {
    const int r = wr * 128 + mi * 16 + lane15;
    return *(const bf16x8*)(smem + buf * 32768 + r * 128 +
                            ((((ks << 2) + lg) ^ (r & 7)) << 4));
  };
  auto ldB = [&](int buf, int ni, int ks) {
    const int r = wc * 64 + ni * 16 + lane15;
    return *(const bf16x8*)(smem + 65536 + buf * 32768 + r * 128 +
                            ((((ks << 2) + lg) ^ (r & 7)) << 4));
  };

  f32x4 acc[8][4];
#pragma unroll
  for (int i = 0; i < 8; i++)
#pragma unroll
    for (int j = 0; j < 4; j++) acc[i][j] = (f32x4){0.f, 0.f, 0.f, 0.f};
  bf16x8 alo[4][2], ahi[4][2], blo[2][2], bhi[2][2];

  issueA(0, 0);  issueA(0, 128);  issueB(0, 0);  issueB(0, 128);
  issueB(1, 0);  issueA(1, 0);    issueB(1, 128);
  asm volatile("s_waitcnt vmcnt(6)" ::: "memory");
  HBAR();

  for (int it = 0; it < 5; ++it) {
    const int Tb = 2 * it + 1, Tn = 2 * it + 2;
#pragma unroll
    for (int mi = 0; mi < 4; mi++) { alo[mi][0] = ldA(0, mi, 0); alo[mi][1] = ldA(0, mi, 1); }
#pragma unroll
    for (int ni = 0; ni < 2; ni++) { blo[ni][0] = ldB(0, ni, 0); blo[ni][1] = ldB(0, ni, 1); }
    issueA(Tb, 128);
    HBAR(); MFMA16(alo, blo, 0, 0); HBAR();
#pragma unroll
    for (int ni = 0; ni < 2; ni++) { bhi[ni][0] = ldB(0, ni + 2, 0); bhi[ni][1] = ldB(0, ni + 2, 1); }
    HBAR(); MFMA16(alo, bhi, 0, 2); HBAR();
#pragma unroll
    for (int mi = 0; mi < 4; mi++) { ahi[mi][0] = ldA(0, mi + 4, 0); ahi[mi][1] = ldA(0, mi + 4, 1); }
    issueB(Tn, 0);
    HBAR(); MFMA16(ahi, bhi, 4, 2); HBAR();
    issueA(Tn, 0);
    issueB(Tn, 128);
    asm volatile("s_waitcnt vmcnt(6)" ::: "memory");
    HBAR(); MFMA16(ahi, blo, 4, 0); HBAR();
#pragma unroll
    for (int mi = 0; mi < 4; mi++) { alo[mi][0] = ldA(1, mi, 0); alo[mi][1] = ldA(1, mi, 1); }
#pragma unroll
    for (int ni = 0; ni < 2; ni++) { blo[ni][0] = ldB(1, ni, 0); blo[ni][1] = ldB(1, ni, 1); }
    issueA(Tn, 128);
    HBAR(); MFMA16(alo, blo, 0, 0); HBAR();
#pragma unroll
    for (int ni = 0; ni < 2; ni++) { bhi[ni][0] = ldB(1, ni + 2, 0); bhi[ni][1] = ldB(1, ni + 2, 1); }
    HBAR(); MFMA16(alo, bhi, 0, 2); HBAR();
#pragma unroll
    for (int mi = 0; mi < 4; mi++) { ahi[mi][0] = ldA(1, mi + 4, 0); ahi[mi][1] = ldA(1, mi + 4, 1); }
    issueB(Tn + 1, 0);
    HBAR(); MFMA16(ahi, bhi, 4, 2); HBAR();
    issueA(Tn + 1, 0);
    issueB(Tn + 1, 128);
    asm volatile("s_waitcnt vmcnt(6)" ::: "memory");
    HBAR(); MFMA16(ahi, blo, 4, 0); HBAR();
  }

  {
#pragma unroll
    for (int mi = 0; mi < 4; mi++) { alo[mi][0] = ldA(0, mi, 0); alo[mi][1] = ldA(0, mi, 1); }
#pragma unroll
    for (int ni = 0; ni < 2; ni++) { blo[ni][0] = ldB(0, ni, 0); blo[ni][1] = ldB(0, ni, 1); }
    issueA(11, 128);
    HBAR(); MFMA16(alo, blo, 0, 0); HBAR();
#pragma unroll
    for (int ni = 0; ni < 2; ni++) { bhi[ni][0] = ldB(0, ni + 2, 0); bhi[ni][1] = ldB(0, ni + 2, 1); }
    HBAR(); MFMA16(alo, bhi, 0, 2); HBAR();
#pragma unroll
    for (int mi = 0; mi < 4; mi++) { ahi[mi][0] = ldA(0, mi + 4, 0); ahi[mi][1] = ldA(0, mi + 4, 1); }
    HBAR(); MFMA16(ahi, bhi, 4, 2); HBAR();
    asm volatile("s_waitcnt vmcnt(0)" ::: "memory");
    HBAR(); MFMA16(ahi, blo, 4, 0); HBAR();
#pragma unroll
    for (int mi = 0; mi < 4; mi++) { alo[mi][0] = ldA(1, mi, 0); alo[mi][1] = ldA(1, mi, 1); }
#pragma unroll
    for (int ni = 0; ni < 2; ni++) { blo[ni][0] = ldB(1, ni, 0); blo[ni][1] = ldB(1, ni, 1); }
    MFMA16(alo, blo, 0, 0);
#pragma unroll
    for (int ni = 0; ni < 2; ni++) { bhi[ni][0] = ldB(1, ni + 2, 0); bhi[ni][1] = ldB(1, ni + 2, 1); }
    MFMA16(alo, bhi, 0, 2);
#pragma unroll
    for (int mi = 0; mi < 4; mi++) { ahi[mi][0] = ldA(1, mi + 4, 0); ahi[mi][1] = ldA(1, mi + 4, 1); }
    MFMA16(ahi, bhi, 4, 2);
    MFMA16(ahi, blo, 4, 0);
  }

#pragma unroll
  for (int ni = 0; ni < 4; ni++) {
    const int col = n0 + wc * 64 + ni * 16 + lane15;
    const float bv = bias[col];
#pragma unroll
    for (int mi = 0; mi < 8; mi++) {
      const int rowb = m0 + wr * 128 + mi * 16 + lg * 4;
#pragma unroll
      for (int j = 0; j < 4; j++)
        C[(size_t)(rowb + j) * 32000 + col] = acc[mi][ni][j] + bv;
    }
  }
}

// ---------------------------------------------------------------- flash attention
__global__ __launch_bounds__(256) void k_attn(
    const bf16* __restrict__ qkv, const bf16* __restrict__ vT,
    const bf16* __restrict__ memkv, bf16* __restrict__ ctx, int layer) {
  const int bh = blockIdx.x;
  const int b = bh / H_, h = bh % H_;
  const int qt = (int)gridDim.y - 1 - (int)blockIdx.y;   // big q first
  const int tid = threadIdx.x;
  const int w = tid >> 6, l = tid & 63;
  const int lane15 = l & 15, lg = l >> 4;
  const float inv = 0.125f;

  __shared__ char plds[4][2048];
  __shared__ float wlp[4][16][16];
  char* pl = plds[w];

  const int qrow0 = qt * 64 + w * 16;
  const size_t rowA = (size_t)(b * S_ + qrow0 + lane15);
  const bf16* qp = qkv + rowA * 2304 + h * 64 + lg * 8;
  auto scale8 = [](bf16x8 v) {
    bf16x8 r;
#pragma unroll
    for (int e = 0; e < 8; e++)
      r[e] = (short)f2bf(bf2f((unsigned short)v[e]) * 0.125f);
    return r;
  };
  const bf16x8 qf0 = scale8(*(const bf16x8*)(qp));
  const bf16x8 qf1 = scale8(*(const bf16x8*)(qp + 32));

  const bf16* kbase = qkv + (size_t)(b * S_) * 2304 + 768 + h * 64 + lg * 8;
  const bf16* vbase = vT + ((size_t)(b * 768 + h * 64 + lane15)) * S_;

  float mrow[4], dsum[4];
  f32x4 acc[4];
#pragma unroll
  for (int j = 0; j < 4; j++) { mrow[j] = -INFINITY; dsum[j] = 0.f; }
#pragma unroll
  for (int ni = 0; ni < 4; ni++) acc[ni] = (f32x4){0.f, 0.f, 0.f, 0.f};

  const int ntile = ((qrow0 + 15) >> 6) + 1;
  for (int kt64 = 0; kt64 < ntile; kt64++) {
    const int k0 = kt64 * 64;
    f32x4 sc[4];
#pragma unroll
    for (int kt = 0; kt < 4; kt++) {
      const bf16* kp = kbase + (size_t)(k0 + kt * 16 + lane15) * 2304;
      bf16x8 kf0 = *(const bf16x8*)(kp);
      bf16x8 kf1 = *(const bf16x8*)(kp + 32);
      f32x4 z = (f32x4){0.f, 0.f, 0.f, 0.f};
      z = __builtin_amdgcn_mfma_f32_16x16x32_bf16(qf0, kf0, z, 0, 0, 0);
      sc[kt] = __builtin_amdgcn_mfma_f32_16x16x32_bf16(qf1, kf1, z, 0, 0, 0);
    }
    float tmax[4];
#pragma unroll
    for (int j = 0; j < 4; j++) tmax[j] = -INFINITY;
    const bool needMask = (k0 + 63 > qrow0);
    if (needMask) {
#pragma unroll
      for (int kt = 0; kt < 4; kt++) {
        const int kabs = k0 + kt * 16 + lane15;
#pragma unroll
        for (int j = 0; j < 4; j++) {
          const int qabs = qrow0 + lg * 4 + j;
          float v = (kabs <= qabs) ? sc[kt][j] : -INFINITY;
          sc[kt][j] = v;
          tmax[j] = fmaxf(tmax[j], v);
        }
      }
    } else {
#pragma unroll
      for (int kt = 0; kt < 4; kt++)
#pragma unroll
        for (int j = 0; j < 4; j++) tmax[j] = fmaxf(tmax[j], sc[kt][j]);
    }
#pragma unroll
    for (int off = 1; off < 16; off <<= 1)
#pragma unroll
      for (int j = 0; j < 4; j++) tmax[j] = fmaxf(tmax[j], __shfl_xor(tmax[j], off, 16));

    bool grow = false;
#pragma unroll
    for (int j = 0; j < 4; j++) grow |= (tmax[j] > mrow[j]);
    if (__ballot(grow) != 0ull) {
#pragma unroll
      for (int j = 0; j < 4; j++) {
        const float mnew = fmaxf(mrow[j], tmax[j]);
        const float alpha = __expf(mrow[j] - mnew);
        mrow[j] = mnew;
        dsum[j] *= alpha;
#pragma unroll
        for (int ni = 0; ni < 4; ni++) acc[ni][j] *= alpha;
      }
    }
    float psum[4] = {0.f, 0.f, 0.f, 0.f};
#pragma unroll
    for (int kt = 0; kt < 4; kt++) {
      const int gsl = kt * 2 + (lane15 >> 3);
      const int ebyte = (lane15 & 7) * 2;
#pragma unroll
      for (int j = 0; j < 4; j++) {
        const float p = __expf(sc[kt][j] - mrow[j]);
        psum[j] += p;
        const int r = lg * 4 + j;
        *(unsigned short*)(pl + r * 128 + ((gsl ^ (r & 7)) << 4) + ebyte) = f2bf(p);
      }
    }
#pragma unroll
    for (int off = 1; off < 16; off <<= 1)
#pragma unroll
      for (int j = 0; j < 4; j++) psum[j] += __shfl_xor(psum[j], off, 16);
#pragma unroll
    for (int j = 0; j < 4; j++) dsum[j] += psum[j];

#pragma unroll
    for (int ks = 0; ks < 2; ks++) {
      bf16x8 pa = *(const bf16x8*)(pl + lane15 * 128 +
                                   ((((ks << 2) + lg) ^ (lane15 & 7)) << 4));
      const bf16* vp = vbase + k0 + ks * 32 + lg * 8;
#pragma unroll
      for (int ni = 0; ni < 4; ni++) {
        bf16x8 vf = *(const bf16x8*)(vp + (size_t)ni * 16 * S_);
        acc[ni] = __builtin_amdgcn_mfma_f32_16x16x32_bf16(pa, vf, acc[ni], 0, 0, 0);
      }
    }
  }

  const int r4 = lg * 4;
  if (lane15 < layer) {
    const int ml = lane15;
#pragma unroll
    for (int j = 0; j < 4; j++) {
      const size_t rowB = (size_t)(b * S_) + qrow0 + r4 + j;
      const bf16* qc = qkv + rowB * 2304 + 1536 + h * 64;
      const bf16* mk = memkv + ((size_t)ml * BS_ + rowB) * 1536 + h * 64;
      float d_ = 0.f;
#pragma unroll
      for (int t = 0; t < 8; t++) {
        bf16x8 qv = *(const bf16x8*)(qc + t * 8);
        bf16x8 kv = *(const bf16x8*)(mk + t * 8);
#pragma unroll
        for (int e = 0; e < 8; e++)
          d_ += bf2f((unsigned short)qv[e]) * bf2f((unsigned short)kv[e]);
      }
      wlp[w][r4 + j][ml] = d_ * inv;
    }
  }
  if (layer > 0) {
#pragma unroll
    for (int j = 0; j < 4; j++) {
      const int r = r4 + j;
      float mm = -INFINITY;
      for (int ml = 0; ml < layer; ml++) mm = fmaxf(mm, wlp[w][r][ml]);
      const float mnew = fmaxf(mrow[j], mm);
      const float alpha = __expf(mrow[j] - mnew);
      mrow[j] = mnew;
      dsum[j] *= alpha;
#pragma unroll
      for (int ni = 0; ni < 4; ni++) acc[ni][j] *= alpha;
      const size_t rowB = (size_t)(b * S_) + qrow0 + r;
      for (int ml = 0; ml < layer; ml++) {
        const float p = __expf(wlp[w][r][ml] - mnew);
        dsum[j] += p;
        const unsigned short* mv = (const unsigned short*)(memkv +
            ((size_t)ml * BS_ + rowB) * 1536 + 768 + h * 64 + lane15);
#pragma unroll
        for (int ni = 0; ni < 4; ni++)
          acc[ni][j] += p * bf2f(mv[ni * 16]);
      }
    }
  }

#pragma unroll
  for (int j = 0; j < 4; j++) {
    const float rd = 1.f / dsum[j];
    const size_t rowB = (size_t)(b * S_) + qrow0 + r4 + j;
    bf16* cp = ctx + rowB * 768 + h * 64 + lane15;
#pragma unroll
    for (int ni = 0; ni < 4; ni++)
      cp[ni * 16] = __float2bfloat16(acc[ni][j] * rd);
  }
}

// ---------------------------------------------------------------- launch
extern "C" void kernel_launch(void* const* d_in, const int* in_sizes, int n_in,
                              void* d_out, int out_size, void* d_ws, size_t ws_size,
                              hipStream_t stream) {
  const int*   tokens  = (const int*)d_in[0];
  const float* tok_emb = (const float*)d_in[1];
  const float* pos_emb = (const float*)d_in[2];
  const float *Wq_row, *Wk_row, *Wv_row, *Wq_col, *Wo;
  const float *bq_row, *bk_row, *bv_row, *bq_col, *bo;
  if (in_sizes[4] == L_ * D_ * D_) {  // dict order
    Wq_row = (const float*)d_in[3];  Wk_row = (const float*)d_in[4];
    Wv_row = (const float*)d_in[5];  Wq_col = (const float*)d_in[6];
    Wo     = (const float*)d_in[7];
    bq_row = (const float*)d_in[8];  bk_row = (const float*)d_in[9];
    bv_row = (const float*)d_in[10]; bq_col = (const float*)d_in[11];
    bo     = (const float*)d_in[12];
  } else {  // signature order fallback
    Wq_row = (const float*)d_in[3];  bq_row = (const float*)d_in[4];
    Wk_row = (const float*)d_in[5];  bk_row = (const float*)d_in[6];
    Wv_row = (const float*)d_in[7];  bv_row = (const float*)d_in[8];
    Wq_col = (const float*)d_in[9];  bq_col = (const float*)d_in[10];
    Wo     = (const float*)d_in[11]; bo     = (const float*)d_in[12];
  }
  const float* ln1_g = (const float*)d_in[13]; const float* ln1_b = (const float*)d_in[14];
  const float* ln2_g = (const float*)d_in[15]; const float* ln2_b = (const float*)d_in[16];
  const float* W1    = (const float*)d_in[17]; const float* b1    = (const float*)d_in[18];
  const float* W2    = (const float*)d_in[19]; const float* b2    = (const float*)d_in[20];
  const float* Wk_sh = (const float*)d_in[21]; const float* bk_sh = (const float*)d_in[22];
  const float* Wv_sh = (const float*)d_in[23]; const float* bv_sh = (const float*)d_in[24];
  const float* lnf_g = (const float*)d_in[25]; const float* lnf_b = (const float*)d_in[26];
  const float* Whead = (const float*)d_in[27]; const float* bhead = (const float*)d_in[28];

  // ---- workspace carve-up
  char* p = (char*)d_ws;
  float* x      = (float*)p; p += (size_t)BS_ * D_ * 4;
  bf16*  h_bf   = (bf16*)p;  p += (size_t)BS_ * D_ * 2;
  bf16*  qkv3   = (bf16*)p;  p += (size_t)BS_ * 2304 * 2;
  bf16*  vTb    = (bf16*)p;  p += (size_t)B_ * 768 * S_ * 2;
  bf16*  memkv  = (bf16*)p;  p += (size_t)L_ * BS_ * 1536 * 2;
  bf16*  ctx_bf = (bf16*)p;  p += (size_t)BS_ * D_ * 2;
  bf16*  mlp_bf = (bf16*)p;  p += (size_t)BS_ * DFF_ * 2;
  float* pkbuf  = (float*)p; p += (size_t)2 * BS_ * D_ * 4;   // split-K partials
  float* b6cat  = (float*)p; p += (size_t)L_ * 4608 * 4;
  bf16* tW6    = (bf16*)p; p += (size_t)L_ * 3072 * D_ * 2;   // q|k|qc|v rows
  bf16* tWsh   = (bf16*)p; p += (size_t)1536 * D_ * 2;        // ksh|vsh rows
  bf16* tWo    = (bf16*)p; p += (size_t)L_ * D_ * D_ * 2;
  bf16* tW1    = (bf16*)p; p += (size_t)L_ * DFF_ * D_ * 2;
  bf16* tW2    = (bf16*)p; p += (size_t)L_ * D_ * DFF_ * 2;
  bf16* tWhead = (bf16*)p; p += (size_t)V_ * D_ * 2;

  // ---- weight conversion (transposed bf16), bias concat
  dim3 tb(32, 8);
  const size_t DD = (size_t)D_ * D_;
  const size_t W6S = (size_t)3072 * 768;
  k_w2bf_t<<<dim3(24, 24, L_), tb, 0, stream>>>(Wq_row, tW6,              768, 768, DD, W6S);
  k_w2bf_t<<<dim3(24, 24, L_), tb, 0, stream>>>(Wk_row, tW6 + 768 * 768,  768, 768, DD, W6S);
  k_w2bf_t<<<dim3(24, 24, L_), tb, 0, stream>>>(Wq_col, tW6 + 1536 * 768, 768, 768, DD, W6S);
  k_w2bf_t<<<dim3(24, 24, L_), tb, 0, stream>>>(Wv_row, tW6 + 2304 * 768, 768, 768, DD, W6S);
  k_w2bf_t<<<dim3(24, 24, 1), tb, 0, stream>>>(Wk_sh, tWsh,             768, 768, 0, 0);
  k_w2bf_t<<<dim3(24, 24, 1), tb, 0, stream>>>(Wv_sh, tWsh + 768 * 768, 768, 768, 0, 0);
  k_w2bf_t<<<dim3(24, 24, L_), tb, 0, stream>>>(Wo,     tWo, 768, 768, DD, DD);
  k_w2bf_t<<<dim3(96, 24, L_), tb, 0, stream>>>(W1, tW1, 768, 3072, (size_t)768 * 3072, (size_t)3072 * 768);
  k_w2bf_t<<<dim3(24, 96, L_), tb, 0, stream>>>(W2, tW2, 3072, 768, (size_t)768 * 3072, (size_t)768 * 3072);
  k_w2bf_t<<<dim3(1000, 24, 1), tb, 0, stream>>>(Whead, tWhead, 768, 32000, 0, 0);
  k_bcat<<<dim3(144), 256, 0, stream>>>(bq_row, bk_row, bq_col, bv_row, bk_sh, bv_sh, b6cat);

  k_embed<<<dim3((BS_ * D_) / 256), 256, 0, stream>>>(tokens, tok_emb, pos_emb, x);
  k_ln<<<dim3(BS_), 256, 0, stream>>>(x, ln1_g, ln1_b, h_bf);   // layer-0 ln1

  for (int i = 0; i < L_; i++) {
    k_bgemm<128, 6, 1><<<dim3(576), 256, 0, stream>>>(
        h_bf, tW6 + (size_t)i * W6S, tWsh, b6cat + (size_t)i * 4608,
        nullptr, nullptr, qkv3, vTb, memkv + (size_t)i * BS_ * 1536,
        16, BS_, 4608, 768);
    k_attn<<<dim3(B_ * H_, S_ / 64), 256, 0, stream>>>(qkv3, vTb, memkv, ctx_bf, i);
    // Wo with split-K=2 -> partials; fused reduce+residual+ln2
    k_bgemm<64, 7, 2><<<dim3(384), 256, 0, stream>>>(
        ctx_bf, tWo + (size_t)i * DD, nullptr, bo + i * D_,
        nullptr, pkbuf, nullptr, nullptr, nullptr, 32, BS_, 768, 768);
    k_redln<<<dim3(BS_), 256, 0, stream>>>(x, pkbuf, bo + i * D_,
                                           ln2_g + i * D_, ln2_b + i * D_, h_bf);
    k_bgemm<128, 2, 1><<<dim3(384), 256, 0, stream>>>(
        h_bf, tW1 + (size_t)i * 3072 * 768, nullptr, b1 + (size_t)i * DFF_,
        nullptr, nullptr, mlp_bf, nullptr, nullptr, 16, BS_, 3072, 768);
    k_bgemm<64, 7, 2><<<dim3(384), 256, 0, stream>>>(
        mlp_bf, tW2 + (size_t)i * 768 * 3072, nullptr, b2 + i * D_,
        nullptr, pkbuf, nullptr, nullptr, nullptr, 32, BS_, 768, 3072);
    const float* gn = (i < L_ - 1) ? (ln1_g + (i + 1) * D_) : lnf_g;
    const float* bn = (i < L_ - 1) ? (ln1_b + (i + 1) * D_) : lnf_b;
    k_redln<<<dim3(BS_), 256, 0, stream>>>(x, pkbuf, b2 + i * D_, gn, bn, h_bf);
  }
  k_head8<<<dim3(1000), 512, 0, stream>>>(h_bf, tWhead, bhead, (float*)d_out);
}

// Round 14
// 1630.125 us; speedup vs baseline: 1.2660x; 1.0044x over previous
//
#include <hip/hip_runtime.h>
#include <hip/hip_bf16.h>
#include <math.h>

#define L_   8
#define D_   768
#define H_   12
#define V_   32000
#define B_   2
#define S_   1024
#define HD_  64
#define BS_  2048      // B_*S_
#define DFF_ 3072      // MR*D

typedef __hip_bfloat16 bf16;
typedef __attribute__((ext_vector_type(8))) short bf16x8;
typedef __attribute__((ext_vector_type(4))) float f32x4;

// Balanced LDS slot swizzle for the 128x128 k_bgemm (BK=32, 4-slot rows)
#define CFUN(r) (((r) >> 1) & 3)

__device__ __forceinline__ void cp16(void* lds, const void* g) {
  __builtin_amdgcn_global_load_lds(
      (const __attribute__((address_space(1))) void*)g,
      (__attribute__((address_space(3))) void*)lds, 16, 0, 0);
}

__device__ __forceinline__ unsigned short f2bf(float v) {
  __hip_bfloat16 h = __float2bfloat16(v);
  return *reinterpret_cast<unsigned short*>(&h);
}
__device__ __forceinline__ float bf2f(unsigned short u) {
  return __uint_as_float(((unsigned)u) << 16);
}

// ---------------------------------------------------------------- embedding
__global__ __launch_bounds__(256) void k_embed(const int* __restrict__ tokens,
    const float* __restrict__ tok_emb, const float* __restrict__ pos_emb,
    float* __restrict__ x) {
  int idx = blockIdx.x * 256 + threadIdx.x;
  int row = idx / D_;
  int d   = idx - row * D_;
  int s   = row & (S_ - 1);
  int t   = tokens[row];
  x[idx] = tok_emb[(size_t)t * D_ + d] + pos_emb[(size_t)s * D_ + d];
}

// ---------------------------------------------------------------- layernorm -> bf16
__global__ __launch_bounds__(256) void k_ln(const float* __restrict__ x,
    const float* __restrict__ g, const float* __restrict__ b,
    bf16* __restrict__ out) {
  int row = blockIdx.x;
  const float* xr = x + (size_t)row * D_;
  int t = threadIdx.x;
  float v0 = xr[t], v1 = xr[t + 256], v2 = xr[t + 512];
  float s  = v0 + v1 + v2;
  float s2 = v0 * v0 + v1 * v1 + v2 * v2;
#pragma unroll
  for (int off = 32; off; off >>= 1) {
    s  += __shfl_down(s, off);
    s2 += __shfl_down(s2, off);
  }
  __shared__ float rs[4], rs2[4];
  __shared__ float mean_s, rstd_s;
  int wid = t >> 6;
  if ((t & 63) == 0) { rs[wid] = s; rs2[wid] = s2; }
  __syncthreads();
  if (t == 0) {
    float S1 = rs[0] + rs[1] + rs[2] + rs[3];
    float S2 = rs2[0] + rs2[1] + rs2[2] + rs2[3];
    float m  = S1 / D_;
    float var = S2 / D_ - m * m;
    mean_s = m;
    rstd_s = rsqrtf(var + 1e-5f);
  }
  __syncthreads();
  float m = mean_s, r = rstd_s;
  bf16* orow = out + (size_t)row * D_;
  orow[t]       = __float2bfloat16((v0 - m) * r * g[t]       + b[t]);
  orow[t + 256] = __float2bfloat16((v1 - m) * r * g[t + 256] + b[t + 256]);
  orow[t + 512] = __float2bfloat16((v2 - m) * r * g[t + 512] + b[t + 512]);
}

// ---------------------------------- fused split-K reduce + residual + LN
__global__ __launch_bounds__(256) void k_redln(float* __restrict__ x,
    const float* __restrict__ pk, const float* __restrict__ b2,
    const float* __restrict__ g, const float* __restrict__ b,
    bf16* __restrict__ out) {
  const int row = blockIdx.x;
  const int t = threadIdx.x;
  const size_t base = (size_t)row * D_;
  const size_t MN = (size_t)BS_ * D_;
  float v0, v1, v2;
  {
    int c0 = t, c1 = t + 256, c2 = t + 512;
    v0 = x[base + c0] + pk[base + c0] + pk[MN + base + c0] + b2[c0];
    v1 = x[base + c1] + pk[base + c1] + pk[MN + base + c1] + b2[c1];
    v2 = x[base + c2] + pk[base + c2] + pk[MN + base + c2] + b2[c2];
    x[base + c0] = v0; x[base + c1] = v1; x[base + c2] = v2;
  }
  float s  = v0 + v1 + v2;
  float s2 = v0 * v0 + v1 * v1 + v2 * v2;
#pragma unroll
  for (int off = 32; off; off >>= 1) {
    s  += __shfl_down(s, off);
    s2 += __shfl_down(s2, off);
  }
  __shared__ float rs[4], rs2[4];
  __shared__ float mean_s, rstd_s;
  int wid = t >> 6;
  if ((t & 63) == 0) { rs[wid] = s; rs2[wid] = s2; }
  __syncthreads();
  if (t == 0) {
    float S1 = rs[0] + rs[1] + rs[2] + rs[3];
    float S2 = rs2[0] + rs2[1] + rs2[2] + rs2[3];
    float m  = S1 / D_;
    float var = S2 / D_ - m * m;
    mean_s = m;
    rstd_s = rsqrtf(var + 1e-5f);
  }
  __syncthreads();
  float m = mean_s, r = rstd_s;
  bf16* orow = out + base;
  orow[t]       = __float2bfloat16((v0 - m) * r * g[t]       + b[t]);
  orow[t + 256] = __float2bfloat16((v1 - m) * r * g[t + 256] + b[t + 256]);
  orow[t + 512] = __float2bfloat16((v2 - m) * r * g[t + 512] + b[t + 512]);
}

// ------------------------------------------------- weight convert + transpose
// W[K][N] f32 -> Wt[N][K] bf16; vectorized ushort4 stores (4 k per thread).
__global__ __launch_bounds__(256) void k_w2bf_t(const float* __restrict__ W,
    bf16* __restrict__ Wt, int K, int N, size_t ils, size_t ols) {
  __shared__ float t[32][33];
  const float* Wm = W + (size_t)blockIdx.z * ils;
  bf16* Wtm = Wt + (size_t)blockIdx.z * ols;
  int n0 = blockIdx.x * 32, k0 = blockIdx.y * 32;
  int tx = threadIdx.x, ty = threadIdx.y;
  for (int i = ty; i < 32; i += 8)
    t[i][tx] = Wm[(size_t)(k0 + i) * N + n0 + tx];
  __syncthreads();
  const int tlin = ty * 32 + tx;
  const int n = tlin >> 3;
  const int kq = (tlin & 7) * 4;
  ushort4 o;
  o.x = f2bf(t[kq + 0][n]);
  o.y = f2bf(t[kq + 1][n]);
  o.z = f2bf(t[kq + 2][n]);
  o.w = f2bf(t[kq + 3][n]);
  *reinterpret_cast<ushort4*>((unsigned short*)Wtm + (size_t)(n0 + n) * K + k0 + kq) = o;
}

// ---------------------------------------------------------------- bias concat
__global__ __launch_bounds__(256) void k_bcat(const float* __restrict__ bq,
    const float* __restrict__ bk, const float* __restrict__ bqc,
    const float* __restrict__ bv, const float* __restrict__ bksh,
    const float* __restrict__ bvsh, float* __restrict__ b6) {
  int idx = blockIdx.x * 256 + threadIdx.x;
  if (idx >= L_ * 4608) return;
  int l = idx / 4608, c = idx - l * 4608;
  float v = (c < 768)  ? bq[l * 768 + c]
          : (c < 1536) ? bk[l * 768 + c - 768]
          : (c < 2304) ? bqc[l * 768 + c - 1536]
          : (c < 3072) ? bv[l * 768 + c - 2304]
          : (c < 3840) ? bksh[c - 3072]
                       : bvsh[c - 3840];
  b6[idx] = v;
}

// ---------------------------------------------------------------- bf16 MFMA GEMM
// (per-layer GEMMs) BMx128 tile, BK=32, 3-buffer counted-vmcnt pipeline.
template <int BM, int EPI, int KSPL>
__global__ __launch_bounds__(256) void k_bgemm(
    const bf16* __restrict__ A, const bf16* __restrict__ Wt,
    const float* __restrict__ bias, const float* __restrict__ resid,
    float* __restrict__ Cf, bf16* __restrict__ Cb,
    int NM, int M, int N, int K) {
  constexpr int ASZ = BM * 64;
  constexpr int ALINES = BM / 64;
  constexpr int BSTRIDE = ASZ + 8192;
  constexpr int MF = BM / 32;
  __shared__ __align__(16) char smem[3 * BSTRIDE];
  const int tid = threadIdx.x;
  const int l = tid & 63, w = tid >> 6;
  const int wr = w >> 1, wc = w & 1;

  const int nwg = (int)gridDim.x;
  int id = (int)blockIdx.x;
  id = (id & 7) * (nwg >> 3) + (id >> 3);
  int sk = 0;
  if constexpr (KSPL == 2) {
    const int TT = nwg >> 1;
    sk = id / TT;
    id -= sk * TT;
  }
  const int m0 = (id % NM) * BM;
  const int n0 = (id / NM) * 128;
  const int kstart = sk * (K / KSPL);

  const int lane15 = l & 15, lg = l >> 4;

  const int r0 = tid >> 2, p0 = tid & 3;
  const char* aSrc[ALINES];
#pragma unroll
  for (int i = 0; i < ALINES; i++) {
    const int rr = i * 64 + r0;
    aSrc[i] = (const char*)(A + (size_t)(m0 + rr) * K + kstart) + ((p0 ^ CFUN(rr)) * 16);
  }
  const char* bSrc0 = (const char*)(Wt + (size_t)(n0 + r0) * K + kstart) + ((p0 ^ CFUN(r0)) * 16);
  const char* bSrc1 = (const char*)(Wt + (size_t)(n0 + 64 + r0) * K + kstart) + ((p0 ^ CFUN(64 + r0)) * 16);

  int aOff[MF], bOff[4];
#pragma unroll
  for (int mi = 0; mi < MF; mi++) {
    int r = wr * (BM / 2) + mi * 16 + lane15;
    aOff[mi] = r * 64 + ((lg ^ CFUN(r)) * 16);
  }
#pragma unroll
  for (int ni = 0; ni < 4; ni++) {
    int r = wc * 64 + ni * 16 + lane15;
    bOff[ni] = ASZ + r * 64 + ((lg ^ CFUN(r)) * 16);
  }

  f32x4 acc[MF][4];
#pragma unroll
  for (int mi = 0; mi < MF; mi++)
#pragma unroll
    for (int ni = 0; ni < 4; ni++) acc[mi][ni] = (f32x4){0.f, 0.f, 0.f, 0.f};

  auto stage = [&](int buf, int t) {
    const size_t kb = (size_t)t * 64;
    char* base = smem + buf * BSTRIDE;
#pragma unroll
    for (int i = 0; i < ALINES; i++)
      cp16(base + i * 4096 + w * 1024, aSrc[i] + kb);
    cp16(base + ASZ + w * 1024, bSrc0 + kb);
    cp16(base + ASZ + 4096 + w * 1024, bSrc1 + kb);
  };
  auto compute = [&](int buf) {
    const char* base = smem + buf * BSTRIDE;
    bf16x8 af[MF], bfr[4];
#pragma unroll
    for (int mi = 0; mi < MF; mi++) af[mi] = *(const bf16x8*)(base + aOff[mi]);
#pragma unroll
    for (int ni = 0; ni < 4; ni++) bfr[ni] = *(const bf16x8*)(base + bOff[ni]);
    __builtin_amdgcn_s_setprio(1);
#pragma unroll
    for (int mi = 0; mi < MF; mi++)
#pragma unroll
      for (int ni = 0; ni < 4; ni++)
        acc[mi][ni] = __builtin_amdgcn_mfma_f32_16x16x32_bf16(
            af[mi], bfr[ni], acc[mi][ni], 0, 0, 0);
    __builtin_amdgcn_s_setprio(0);
  };

  const int nk = (K / KSPL) >> 5;
  stage(0, 0);
  stage(1, 1);
  int buf = 0;
  for (int t = 0; t < nk; t++) {
    if (t + 1 < nk) {
      if constexpr (ALINES == 2) asm volatile("s_waitcnt vmcnt(4)" ::: "memory");
      else                       asm volatile("s_waitcnt vmcnt(3)" ::: "memory");
    } else {
      asm volatile("s_waitcnt vmcnt(0)" ::: "memory");
    }
    __builtin_amdgcn_s_barrier();
    if (t + 2 < nk) {
      int nb = buf + 2; if (nb >= 3) nb -= 3;
      stage(nb, t + 2);
    }
    compute(buf);
    buf = (buf == 2) ? 0 : buf + 1;
  }

#pragma unroll
  for (int ni = 0; ni < 4; ni++) {
    const int col = n0 + wc * 64 + ni * 16 + lane15;
    const float bv = bias[col];
#pragma unroll
    for (int mi = 0; mi < MF; mi++) {
      const int rowb = m0 + wr * (BM / 2) + mi * 16 + lg * 4;
      if constexpr (EPI == 7) {
#pragma unroll
        for (int j = 0; j < 4; j++)
          Cf[(size_t)sk * M * N + (size_t)(rowb + j) * N + col] = acc[mi][ni][j];
      } else {
#pragma unroll
        for (int j = 0; j < 4; j++) {
          const int row = rowb + j;
          float v = acc[mi][ni][j] + bv;
          if constexpr (EPI == 1) v += resid[(size_t)row * N + col];
          if constexpr (EPI == 2) {
            v = 0.5f * v * (1.0f + erff(v * 0.70710678118654752f));
            Cb[(size_t)row * N + col] = __float2bfloat16(v);
          } else if constexpr (EPI == 3) {
            Cb[(size_t)row * N + col] = __float2bfloat16(v);
          } else {
            Cf[(size_t)row * N + col] = v;
          }
        }
      }
    }
  }
}

// ------------------------------------------- 8-phase 256x256 GEMM (K=768)
// Validated race-safe schedule (rounds 10-12). EPI 0: head f32+bias out
// (ldc=32000). EPI 6: fused qkv routing (col<2304 qkv | <3072 vT | memkv),
// B from Wt (n0<3072) or Wt2 (shared k/v).
#define HBAR() asm volatile("s_barrier" ::: "memory")
#define MFMA16(AF, BF, MB, NB)                                               \
  do {                                                                       \
    __builtin_amdgcn_s_setprio(1);                                           \
    _Pragma("unroll") for (int mi_ = 0; mi_ < 4; mi_++)                      \
      _Pragma("unroll") for (int ni_ = 0; ni_ < 2; ni_++)                    \
        _Pragma("unroll") for (int ks_ = 0; ks_ < 2; ks_++)                  \
          acc[(MB) + mi_][(NB) + ni_] =                                      \
              __builtin_amdgcn_mfma_f32_16x16x32_bf16(                       \
                  AF[mi_][ks_], BF[ni_][ks_], acc[(MB) + mi_][(NB) + ni_],   \
                  0, 0, 0);                                                  \
    __builtin_amdgcn_s_setprio(0);                                           \
  } while (0)

template <int EPI>
__global__ __launch_bounds__(512, 1) void k_g8(const bf16* __restrict__ A,
    const bf16* __restrict__ Wt, const bf16* __restrict__ Wt2,
    const float* __restrict__ bias, float* __restrict__ Cf,
    bf16* __restrict__ Cb, bf16* __restrict__ Cb2, bf16* __restrict__ Cb3) {
  __shared__ __align__(16) char smem[131072];
  const int tid = threadIdx.x;
  const int l = tid & 63, w = tid >> 6;
  const int wr = w >> 2, wc = w & 3;
  const int lane15 = l & 15, lg = l >> 4;

  const int nwg = (int)gridDim.x;
  int id = (int)blockIdx.x;
  id = (id & 7) * (nwg >> 3) + (id >> 3);
  const int m0 = (id % 8) * 256;
  const int n0 = (id / 8) * 256;

  const bf16* WB = Wt;
  int nb0 = n0;
  if constexpr (EPI == 6) {
    if (n0 >= 3072) { WB = Wt2; nb0 = n0 - 3072; }
  }

  auto issueA = [&](int tile, int hb) {
#pragma unroll
    for (int j = 0; j < 2; j++) {
      const int idx = j * 512 + tid;
      const int rl = idx >> 3, sl = idx & 7;
      const bf16* g = A + (size_t)(m0 + hb + rl) * 768 + tile * 64 +
                      ((sl ^ (rl & 7)) << 3);
      cp16(smem + (tile & 1) * 32768 + hb * 128 + (j * 512 + w * 64) * 16, g);
    }
  };
  auto issueB = [&](int tile, int hb) {
#pragma unroll
    for (int j = 0; j < 2; j++) {
      const int idx = j * 512 + tid;
      const int rl = idx >> 3, sl = idx & 7;
      const bf16* g = WB + (size_t)(nb0 + hb + rl) * 768 + tile * 64 +
                      ((sl ^ (rl & 7)) << 3);
      cp16(smem + 65536 + (tile & 1) * 32768 + hb * 128 + (j * 512 + w * 64) * 16, g);
    }
  };
  auto ldA = [&](int buf, int mi, int ks) {
    const int r = wr * 128 + mi * 16 + lane15;
    return *(const bf16x8*)(smem + buf * 32768 + r * 128 +
                            ((((ks << 2) + lg) ^ (r & 7)) << 4));
  };
  auto ldB = [&](int buf, int ni, int ks) {
    const int r = wc * 64 + ni * 16 + lane15;
    return *(const bf16x8*)(smem + 65536 + buf * 32768 + r * 128 +
                            ((((ks << 2) + lg) ^ (r & 7)) << 4));
  };

  f32x4 acc[8][4];
#pragma unroll
  for (int i = 0; i < 8; i++)
#pragma unroll
    for (int j = 0; j < 4; j++) acc[i][j] = (f32x4){0.f, 0.f, 0.f, 0.f};
  bf16x8 alo[4][2], ahi[4][2], blo[2][2], bhi[2][2];

  issueA(0, 0);  issueA(0, 128);  issueB(0, 0);  issueB(0, 128);
  issueB(1, 0);  issueA(1, 0);    issueB(1, 128);
  asm volatile("s_waitcnt vmcnt(6)" ::: "memory");
  HBAR();

  for (int it = 0; it < 5; ++it) {
    const int Tb = 2 * it + 1, Tn = 2 * it + 2;
#pragma unroll
    for (int mi = 0; mi < 4; mi++) { alo[mi][0] = ldA(0, mi, 0); alo[mi][1] = ldA(0, mi, 1); }
#pragma unroll
    for (int ni = 0; ni < 2; ni++) { blo[ni][0] = ldB(0, ni, 0); blo[ni][1] = ldB(0, ni, 1); }
    issueA(Tb, 128);
    HBAR(); MFMA16(alo, blo, 0, 0); HBAR();
#pragma unroll
    for (int ni = 0; ni < 2; ni++) { bhi[ni][0] = ldB(0, ni + 2, 0); bhi[ni][1] = ldB(0, ni + 2, 1); }
    HBAR(); MFMA16(alo, bhi, 0, 2); HBAR();
#pragma unroll
    for (int mi = 0; mi < 4; mi++) { ahi[mi][0] = ldA(0, mi + 4, 0); ahi[mi][1] = ldA(0, mi + 4, 1); }
    issueB(Tn, 0);
    HBAR(); MFMA16(ahi, bhi, 4, 2); HBAR();
    issueA(Tn, 0);
    issueB(Tn, 128);
    asm volatile("s_waitcnt vmcnt(6)" ::: "memory");
    HBAR(); MFMA16(ahi, blo, 4, 0); HBAR();
#pragma unroll
    for (int mi = 0; mi < 4; mi++) { alo[mi][0] = ldA(1, mi, 0); alo[mi][1] = ldA(1, mi, 1); }
#pragma unroll
    for (int ni = 0; ni < 2; ni++) { blo[ni][0] = ldB(1, ni, 0); blo[ni][1] = ldB(1, ni, 1); }
    issueA(Tn, 128);
    HBAR(); MFMA16(alo, blo, 0, 0); HBAR();
#pragma unroll
    for (int ni = 0; ni < 2; ni++) { bhi[ni][0] = ldB(1, ni + 2, 0); bhi[ni][1] = ldB(1, ni + 2, 1); }
    HBAR(); MFMA16(alo, bhi, 0, 2); HBAR();
#pragma unroll
    for (int mi = 0; mi < 4; mi++) { ahi[mi][0] = ldA(1, mi + 4, 0); ahi[mi][1] = ldA(1, mi + 4, 1); }
    issueB(Tn + 1, 0);
    HBAR(); MFMA16(ahi, bhi, 4, 2); HBAR();
    issueA(Tn + 1, 0);
    issueB(Tn + 1, 128);
    asm volatile("s_waitcnt vmcnt(6)" ::: "memory");
    HBAR(); MFMA16(ahi, blo, 4, 0); HBAR();
  }

  {
#pragma unroll
    for (int mi = 0; mi < 4; mi++) { alo[mi][0] = ldA(0, mi, 0); alo[mi][1] = ldA(0, mi, 1); }
#pragma unroll
    for (int ni = 0; ni < 2; ni++) { blo[ni][0] = ldB(0, ni, 0); blo[ni][1] = ldB(0, ni, 1); }
    issueA(11, 128);
    HBAR(); MFMA16(alo, blo, 0, 0); HBAR();
#pragma unroll
    for (int ni = 0; ni < 2; ni++) { bhi[ni][0] = ldB(0, ni + 2, 0); bhi[ni][1] = ldB(0, ni + 2, 1); }
    HBAR(); MFMA16(alo, bhi, 0, 2); HBAR();
#pragma unroll
    for (int mi = 0; mi < 4; mi++) { ahi[mi][0] = ldA(0, mi + 4, 0); ahi[mi][1] = ldA(0, mi + 4, 1); }
    HBAR(); MFMA16(ahi, bhi, 4, 2); HBAR();
    asm volatile("s_waitcnt vmcnt(0)" ::: "memory");
    HBAR(); MFMA16(ahi, blo, 4, 0); HBAR();
#pragma unroll
    for (int mi = 0; mi < 4; mi++) { alo[mi][0] = ldA(1, mi, 0); alo[mi][1] = ldA(1, mi, 1); }
#pragma unroll
    for (int ni = 0; ni < 2; ni++) { blo[ni][0] = ldB(1, ni, 0); blo[ni][1] = ldB(1, ni, 1); }
    MFMA16(alo, blo, 0, 0);
#pragma unroll
    for (int ni = 0; ni < 2; ni++) { bhi[ni][0] = ldB(1, ni + 2, 0); bhi[ni][1] = ldB(1, ni + 2, 1); }
    MFMA16(alo, bhi, 0, 2);
#pragma unroll
    for (int mi = 0; mi < 4; mi++) { ahi[mi][0] = ldA(1, mi + 4, 0); ahi[mi][1] = ldA(1, mi + 4, 1); }
    MFMA16(ahi, bhi, 4, 2);
    MFMA16(ahi, blo, 4, 0);
  }

  // epilogue
#pragma unroll
  for (int ni = 0; ni < 4; ni++) {
    const int col = n0 + wc * 64 + ni * 16 + lane15;
    const float bv = bias[col];
#pragma unroll
    for (int mi = 0; mi < 8; mi++) {
      const int rowb = m0 + wr * 128 + mi * 16 + lg * 4;
      if constexpr (EPI == 0) {
#pragma unroll
        for (int j = 0; j < 4; j++)
          Cf[(size_t)(rowb + j) * 32000 + col] = acc[mi][ni][j] + bv;
      } else {  // EPI == 6
        if (col < 2304) {
#pragma unroll
          for (int j = 0; j < 4; j++)
            Cb[(size_t)(rowb + j) * 2304 + col] = __float2bfloat16(acc[mi][ni][j] + bv);
        } else if (col < 3072) {
          ushort4 pk;
          pk.x = f2bf(acc[mi][ni][0] + bv);
          pk.y = f2bf(acc[mi][ni][1] + bv);
          pk.z = f2bf(acc[mi][ni][2] + bv);
          pk.w = f2bf(acc[mi][ni][3] + bv);
          const int bq = rowb >> 10, s = rowb & (S_ - 1);
          *reinterpret_cast<ushort4*>(
              (unsigned short*)Cb2 + ((size_t)(bq * 768 + (col - 2304))) * S_ + s) = pk;
        } else {
#pragma unroll
          for (int j = 0; j < 4; j++)
            Cb3[(size_t)(rowb + j) * 1536 + (col - 3072)] =
                __float2bfloat16(acc[mi][ni][j] + bv);
        }
      }
    }
  }
}

// ---------------------------------------------------------------- flash attention
__global__ __launch_bounds__(256) void k_attn(
    const bf16* __restrict__ qkv, const bf16* __restrict__ vT,
    const bf16* __restrict__ memkv, bf16* __restrict__ ctx, int layer) {
  const int bh = blockIdx.x;
  const int b = bh / H_, h = bh % H_;
  const int qt = (int)gridDim.y - 1 - (int)blockIdx.y;   // big q first
  const int tid = threadIdx.x;
  const int w = tid >> 6, l = tid & 63;
  const int lane15 = l & 15, lg = l >> 4;
  const float inv = 0.125f;

  __shared__ char plds[4][2048];
  __shared__ float wlp[4][16][16];
  char* pl = plds[w];

  const int qrow0 = qt * 64 + w * 16;
  const size_t rowA = (size_t)(b * S_ + qrow0 + lane15);
  const bf16* qp = qkv + rowA * 2304 + h * 64 + lg * 8;
  auto scale8 = [](bf16x8 v) {
    bf16x8 r;
#pragma unroll
    for (int e = 0; e < 8; e++)
      r[e] = (short)f2bf(bf2f((unsigned short)v[e]) * 0.125f);
    return r;
  };
  const bf16x8 qf0 = scale8(*(const bf16x8*)(qp));
  const bf16x8 qf1 = scale8(*(const bf16x8*)(qp + 32));

  const bf16* kbase = qkv + (size_t)(b * S_) * 2304 + 768 + h * 64 + lg * 8;
  const bf16* vbase = vT + ((size_t)(b * 768 + h * 64 + lane15)) * S_;

  float mrow[4], dsum[4];
  f32x4 acc[4];
#pragma unroll
  for (int j = 0; j < 4; j++) { mrow[j] = -INFINITY; dsum[j] = 0.f; }
#pragma unroll
  for (int ni = 0; ni < 4; ni++) acc[ni] = (f32x4){0.f, 0.f, 0.f, 0.f};

  const int ntile = ((qrow0 + 15) >> 6) + 1;
  for (int kt64 = 0; kt64 < ntile; kt64++) {
    const int k0 = kt64 * 64;
    f32x4 sc[4];
#pragma unroll
    for (int kt = 0; kt < 4; kt++) {
      const bf16* kp = kbase + (size_t)(k0 + kt * 16 + lane15) * 2304;
      bf16x8 kf0 = *(const bf16x8*)(kp);
      bf16x8 kf1 = *(const bf16x8*)(kp + 32);
      f32x4 z = (f32x4){0.f, 0.f, 0.f, 0.f};
      z = __builtin_amdgcn_mfma_f32_16x16x32_bf16(qf0, kf0, z, 0, 0, 0);
      sc[kt] = __builtin_amdgcn_mfma_f32_16x16x32_bf16(qf1, kf1, z, 0, 0, 0);
    }
    float tmax[4];
#pragma unroll
    for (int j = 0; j < 4; j++) tmax[j] = -INFINITY;
    const bool needMask = (k0 + 63 > qrow0);
    if (needMask) {
#pragma unroll
      for (int kt = 0; kt < 4; kt++) {
        const int kabs = k0 + kt * 16 + lane15;
#pragma unroll
        for (int j = 0; j < 4; j++) {
          const int qabs = qrow0 + lg * 4 + j;
          float v = (kabs <= qabs) ? sc[kt][j] : -INFINITY;
          sc[kt][j] = v;
          tmax[j] = fmaxf(tmax[j], v);
        }
      }
    } else {
#pragma unroll
      for (int kt = 0; kt < 4; kt++)
#pragma unroll
        for (int j = 0; j < 4; j++) tmax[j] = fmaxf(tmax[j], sc[kt][j]);
    }
#pragma unroll
    for (int off = 1; off < 16; off <<= 1)
#pragma unroll
      for (int j = 0; j < 4; j++) tmax[j] = fmaxf(tmax[j], __shfl_xor(tmax[j], off, 16));

    bool grow = false;
#pragma unroll
    for (int j = 0; j < 4; j++) grow |= (tmax[j] > mrow[j]);
    if (__ballot(grow) != 0ull) {
#pragma unroll
      for (int j = 0; j < 4; j++) {
        const float mnew = fmaxf(mrow[j], tmax[j]);
        const float alpha = __expf(mrow[j] - mnew);
        mrow[j] = mnew;
        dsum[j] *= alpha;
#pragma unroll
        for (int ni = 0; ni < 4; ni++) acc[ni][j] *= alpha;
      }
    }
    float psum[4] = {0.f, 0.f, 0.f, 0.f};
#pragma unroll
    for (int kt = 0; kt < 4; kt++) {
      const int gsl = kt * 2 + (lane15 >> 3);
      const int ebyte = (lane15 & 7) * 2;
#pragma unroll
      for (int j = 0; j < 4; j++) {
        const float p = __expf(sc[kt][j] - mrow[j]);
        psum[j] += p;
        const int r = lg * 4 + j;
        *(unsigned short*)(pl + r * 128 + ((gsl ^ (r & 7)) << 4) + ebyte) = f2bf(p);
      }
    }
#pragma unroll
    for (int off = 1; off < 16; off <<= 1)
#pragma unroll
      for (int j = 0; j < 4; j++) psum[j] += __shfl_xor(psum[j], off, 16);
#pragma unroll
    for (int j = 0; j < 4; j++) dsum[j] += psum[j];

#pragma unroll
    for (int ks = 0; ks < 2; ks++) {
      bf16x8 pa = *(const bf16x8*)(pl + lane15 * 128 +
                                   ((((ks << 2) + lg) ^ (lane15 & 7)) << 4));
      const bf16* vp = vbase + k0 + ks * 32 + lg * 8;
#pragma unroll
      for (int ni = 0; ni < 4; ni++) {
        bf16x8 vf = *(const bf16x8*)(vp + (size_t)ni * 16 * S_);
        acc[ni] = __builtin_amdgcn_mfma_f32_16x16x32_bf16(pa, vf, acc[ni], 0, 0, 0);
      }
    }
  }

  const int r4 = lg * 4;
  if (lane15 < layer) {
    const int ml = lane15;
#pragma unroll
    for (int j = 0; j < 4; j++) {
      const size_t rowB = (size_t)(b * S_) + qrow0 + r4 + j;
      const bf16* qc = qkv + rowB * 2304 + 1536 + h * 64;
      const bf16* mk = memkv + ((size_t)ml * BS_ + rowB) * 1536 + h * 64;
      float d_ = 0.f;
#pragma unroll
      for (int t = 0; t < 8; t++) {
        bf16x8 qv = *(const bf16x8*)(qc + t * 8);
        bf16x8 kv = *(const bf16x8*)(mk + t * 8);
#pragma unroll
        for (int e = 0; e < 8; e++)
          d_ += bf2f((unsigned short)qv[e]) * bf2f((unsigned short)kv[e]);
      }
      wlp[w][r4 + j][ml] = d_ * inv;
    }
  }
  if (layer > 0) {
#pragma unroll
    for (int j = 0; j < 4; j++) {
      const int r = r4 + j;
      float mm = -INFINITY;
      for (int ml = 0; ml < layer; ml++) mm = fmaxf(mm, wlp[w][r][ml]);
      const float mnew = fmaxf(mrow[j], mm);
      const float alpha = __expf(mrow[j] - mnew);
      mrow[j] = mnew;
      dsum[j] *= alpha;
#pragma unroll
      for (int ni = 0; ni < 4; ni++) acc[ni][j] *= alpha;
      const size_t rowB = (size_t)(b * S_) + qrow0 + r;
      for (int ml = 0; ml < layer; ml++) {
        const float p = __expf(wlp[w][r][ml] - mnew);
        dsum[j] += p;
        const unsigned short* mv = (const unsigned short*)(memkv +
            ((size_t)ml * BS_ + rowB) * 1536 + 768 + h * 64 + lane15);
#pragma unroll
        for (int ni = 0; ni < 4; ni++)
          acc[ni][j] += p * bf2f(mv[ni * 16]);
      }
    }
  }

#pragma unroll
  for (int j = 0; j < 4; j++) {
    const float rd = 1.f / dsum[j];
    const size_t rowB = (size_t)(b * S_) + qrow0 + r4 + j;
    bf16* cp = ctx + rowB * 768 + h * 64 + lane15;
#pragma unroll
    for (int ni = 0; ni < 4; ni++)
      cp[ni * 16] = __float2bfloat16(acc[ni][j] * rd);
  }
}

// ---------------------------------------------------------------- launch
extern "C" void kernel_launch(void* const* d_in, const int* in_sizes, int n_in,
                              void* d_out, int out_size, void* d_ws, size_t ws_size,
                              hipStream_t stream) {
  const int*   tokens  = (const int*)d_in[0];
  const float* tok_emb = (const float*)d_in[1];
  const float* pos_emb = (const float*)d_in[2];
  const float *Wq_row, *Wk_row, *Wv_row, *Wq_col, *Wo;
  const float *bq_row, *bk_row, *bv_row, *bq_col, *bo;
  if (in_sizes[4] == L_ * D_ * D_) {  // dict order
    Wq_row = (const float*)d_in[3];  Wk_row = (const float*)d_in[4];
    Wv_row = (const float*)d_in[5];  Wq_col = (const float*)d_in[6];
    Wo     = (const float*)d_in[7];
    bq_row = (const float*)d_in[8];  bk_row = (const float*)d_in[9];
    bv_row = (const float*)d_in[10]; bq_col = (const float*)d_in[11];
    bo     = (const float*)d_in[12];
  } else {  // signature order fallback
    Wq_row = (const float*)d_in[3];  bq_row = (const float*)d_in[4];
    Wk_row = (const float*)d_in[5];  bk_row = (const float*)d_in[6];
    Wv_row = (const float*)d_in[7];  bv_row = (const float*)d_in[8];
    Wq_col = (const float*)d_in[9];  bq_col = (const float*)d_in[10];
    Wo     = (const float*)d_in[11]; bo     = (const float*)d_in[12];
  }
  const float* ln1_g = (const float*)d_in[13]; const float* ln1_b = (const float*)d_in[14];
  const float* ln2_g = (const float*)d_in[15]; const float* ln2_b = (const float*)d_in[16];
  const float* W1    = (const float*)d_in[17]; const float* b1    = (const float*)d_in[18];
  const float* W2    = (const float*)d_in[19]; const float* b2    = (const float*)d_in[20];
  const float* Wk_sh = (const float*)d_in[21]; const float* bk_sh = (const float*)d_in[22];
  const float* Wv_sh = (const float*)d_in[23]; const float* bv_sh = (const float*)d_in[24];
  const float* lnf_g = (const float*)d_in[25]; const float* lnf_b = (const float*)d_in[26];
  const float* Whead = (const float*)d_in[27]; const float* bhead = (const float*)d_in[28];

  // ---- workspace carve-up
  char* p = (char*)d_ws;
  float* x      = (float*)p; p += (size_t)BS_ * D_ * 4;
  bf16*  h_bf   = (bf16*)p;  p += (size_t)BS_ * D_ * 2;
  bf16*  qkv3   = (bf16*)p;  p += (size_t)BS_ * 2304 * 2;
  bf16*  vTb    = (bf16*)p;  p += (size_t)B_ * 768 * S_ * 2;
  bf16*  memkv  = (bf16*)p;  p += (size_t)L_ * BS_ * 1536 * 2;
  bf16*  ctx_bf = (bf16*)p;  p += (size_t)BS_ * D_ * 2;
  bf16*  mlp_bf = (bf16*)p;  p += (size_t)BS_ * DFF_ * 2;
  float* pkbuf  = (float*)p; p += (size_t)2 * BS_ * D_ * 4;   // split-K partials
  float* b6cat  = (float*)p; p += (size_t)L_ * 4608 * 4;
  bf16* tW6    = (bf16*)p; p += (size_t)L_ * 3072 * D_ * 2;   // q|k|qc|v rows
  bf16* tWsh   = (bf16*)p; p += (size_t)1536 * D_ * 2;        // ksh|vsh rows
  bf16* tWo    = (bf16*)p; p += (size_t)L_ * D_ * D_ * 2;
  bf16* tW1    = (bf16*)p; p += (size_t)L_ * DFF_ * D_ * 2;
  bf16* tW2    = (bf16*)p; p += (size_t)L_ * D_ * DFF_ * 2;
  bf16* tWhead = (bf16*)p; p += (size_t)V_ * D_ * 2;

  // ---- weight conversion (transposed bf16), bias concat
  dim3 tb(32, 8);
  const size_t DD = (size_t)D_ * D_;
  const size_t W6S = (size_t)3072 * 768;
  k_w2bf_t<<<dim3(24, 24, L_), tb, 0, stream>>>(Wq_row, tW6,              768, 768, DD, W6S);
  k_w2bf_t<<<dim3(24, 24, L_), tb, 0, stream>>>(Wk_row, tW6 + 768 * 768,  768, 768, DD, W6S);
  k_w2bf_t<<<dim3(24, 24, L_), tb, 0, stream>>>(Wq_col, tW6 + 1536 * 768, 768, 768, DD, W6S);
  k_w2bf_t<<<dim3(24, 24, L_), tb, 0, stream>>>(Wv_row, tW6 + 2304 * 768, 768, 768, DD, W6S);
  k_w2bf_t<<<dim3(24, 24, 1), tb, 0, stream>>>(Wk_sh, tWsh,             768, 768, 0, 0);
  k_w2bf_t<<<dim3(24, 24, 1), tb, 0, stream>>>(Wv_sh, tWsh + 768 * 768, 768, 768, 0, 0);
  k_w2bf_t<<<dim3(24, 24, L_), tb, 0, stream>>>(Wo,     tWo, 768, 768, DD, DD);
  k_w2bf_t<<<dim3(96, 24, L_), tb, 0, stream>>>(W1, tW1, 768, 3072, (size_t)768 * 3072, (size_t)3072 * 768);
  k_w2bf_t<<<dim3(24, 96, L_), tb, 0, stream>>>(W2, tW2, 3072, 768, (size_t)768 * 3072, (size_t)768 * 3072);
  k_w2bf_t<<<dim3(1000, 24, 1), tb, 0, stream>>>(Whead, tWhead, 768, 32000, 0, 0);
  k_bcat<<<dim3(144), 256, 0, stream>>>(bq_row, bk_row, bq_col, bv_row, bk_sh, bv_sh, b6cat);

  k_embed<<<dim3((BS_ * D_) / 256), 256, 0, stream>>>(tokens, tok_emb, pos_emb, x);
  k_ln<<<dim3(BS_), 256, 0, stream>>>(x, ln1_g, ln1_b, h_bf);   // layer-0 ln1

  for (int i = 0; i < L_; i++) {
    k_g8<6><<<dim3(144), 512, 0, stream>>>(
        h_bf, tW6 + (size_t)i * W6S, tWsh, b6cat + (size_t)i * 4608,
        nullptr, qkv3, vTb, memkv + (size_t)i * BS_ * 1536);
    k_attn<<<dim3(B_ * H_, S_ / 64), 256, 0, stream>>>(qkv3, vTb, memkv, ctx_bf, i);
    k_bgemm<64, 7, 2><<<dim3(384), 256, 0, stream>>>(
        ctx_bf, tWo + (size_t)i * DD, bo + i * D_,
        nullptr, pkbuf, nullptr, 32, BS_, 768, 768);
    k_redln<<<dim3(BS_), 256, 0, stream>>>(x, pkbuf, bo + i * D_,
                                           ln2_g + i * D_, ln2_b + i * D_, h_bf);
    k_bgemm<128, 2, 1><<<dim3(384), 256, 0, stream>>>(
        h_bf, tW1 + (size_t)i * 3072 * 768, b1 + (size_t)i * DFF_,
        nullptr, nullptr, mlp_bf, 16, BS_, 3072, 768);
    k_bgemm<64, 7, 2><<<dim3(384), 256, 0, stream>>>(
        mlp_bf, tW2 + (size_t)i * 768 * 3072, b2 + i * D_,
        nullptr, pkbuf, nullptr, 32, BS_, 768, 3072);
    const float* gn = (i < L_ - 1) ? (ln1_g + (i + 1) * D_) : lnf_g;
    const float* bn = (i < L_ - 1) ? (ln1_b + (i + 1) * D_) : lnf_b;
    k_redln<<<dim3(BS_), 256, 0, stream>>>(x, pkbuf, b2 + i * D_, gn, bn, h_bf);
  }
  k_g8<0><<<dim3(1000), 512, 0, stream>>>(h_bf, tWhead, nullptr, bhead,
                                          (float*)d_out, nullptr, nullptr, nullptr);
}

// Round 15
// 1588.631 us; speedup vs baseline: 1.2991x; 1.0261x over previous
//
#include <hip/hip_runtime.h>
#include <hip/hip_bf16.h>
#include <math.h>

#define L_   8
#define D_   768
#define H_   12
#define V_   32000
#define B_   2
#define S_   1024
#define HD_  64
#define BS_  2048      // B_*S_
#define DFF_ 3072      // MR*D

typedef __hip_bfloat16 bf16;
typedef __attribute__((ext_vector_type(8))) short bf16x8;
typedef __attribute__((ext_vector_type(4))) float f32x4;

// Balanced LDS slot swizzle for the 128x128 k_bgemm (BK=32, 4-slot rows)
#define CFUN(r) (((r) >> 1) & 3)

__device__ __forceinline__ void cp16(void* lds, const void* g) {
  __builtin_amdgcn_global_load_lds(
      (const __attribute__((address_space(1))) void*)g,
      (__attribute__((address_space(3))) void*)lds, 16, 0, 0);
}

__device__ __forceinline__ unsigned short f2bf(float v) {
  __hip_bfloat16 h = __float2bfloat16(v);
  return *reinterpret_cast<unsigned short*>(&h);
}
__device__ __forceinline__ float bf2f(unsigned short u) {
  return __uint_as_float(((unsigned)u) << 16);
}

// ------------------------------------------- fused embed + layer-0 LN
__global__ __launch_bounds__(256) void k_embedln(const int* __restrict__ tokens,
    const float* __restrict__ tok_emb, const float* __restrict__ pos_emb,
    const float* __restrict__ g, const float* __restrict__ b,
    float* __restrict__ x, bf16* __restrict__ out) {
  const int row = blockIdx.x;
  const int t = threadIdx.x;
  const int s = row & (S_ - 1);
  const int tok = tokens[row];
  const size_t base = (size_t)row * D_;
  const float* te = tok_emb + (size_t)tok * D_;
  const float* pe = pos_emb + (size_t)s * D_;
  float v0 = te[t] + pe[t];
  float v1 = te[t + 256] + pe[t + 256];
  float v2 = te[t + 512] + pe[t + 512];
  x[base + t] = v0; x[base + t + 256] = v1; x[base + t + 512] = v2;
  float sum  = v0 + v1 + v2;
  float s2 = v0 * v0 + v1 * v1 + v2 * v2;
#pragma unroll
  for (int off = 32; off; off >>= 1) {
    sum += __shfl_down(sum, off);
    s2  += __shfl_down(s2, off);
  }
  __shared__ float rs[4], rs2[4];
  __shared__ float mean_s, rstd_s;
  int wid = t >> 6;
  if ((t & 63) == 0) { rs[wid] = sum; rs2[wid] = s2; }
  __syncthreads();
  if (t == 0) {
    float S1 = rs[0] + rs[1] + rs[2] + rs[3];
    float S2 = rs2[0] + rs2[1] + rs2[2] + rs2[3];
    float m  = S1 / D_;
    float var = S2 / D_ - m * m;
    mean_s = m;
    rstd_s = rsqrtf(var + 1e-5f);
  }
  __syncthreads();
  float m = mean_s, r = rstd_s;
  bf16* orow = out + base;
  orow[t]       = __float2bfloat16((v0 - m) * r * g[t]       + b[t]);
  orow[t + 256] = __float2bfloat16((v1 - m) * r * g[t + 256] + b[t + 256]);
  orow[t + 512] = __float2bfloat16((v2 - m) * r * g[t + 512] + b[t + 512]);
}

// ---------------------------------- fused split-K reduce + residual + LN
__global__ __launch_bounds__(256) void k_redln(float* __restrict__ x,
    const float* __restrict__ pk, const float* __restrict__ b2,
    const float* __restrict__ g, const float* __restrict__ b,
    bf16* __restrict__ out) {
  const int row = blockIdx.x;
  const int t = threadIdx.x;
  const size_t base = (size_t)row * D_;
  const size_t MN = (size_t)BS_ * D_;
  float v0, v1, v2;
  {
    int c0 = t, c1 = t + 256, c2 = t + 512;
    v0 = x[base + c0] + pk[base + c0] + pk[MN + base + c0] + b2[c0];
    v1 = x[base + c1] + pk[base + c1] + pk[MN + base + c1] + b2[c1];
    v2 = x[base + c2] + pk[base + c2] + pk[MN + base + c2] + b2[c2];
    x[base + c0] = v0; x[base + c1] = v1; x[base + c2] = v2;
  }
  float s  = v0 + v1 + v2;
  float s2 = v0 * v0 + v1 * v1 + v2 * v2;
#pragma unroll
  for (int off = 32; off; off >>= 1) {
    s  += __shfl_down(s, off);
    s2 += __shfl_down(s2, off);
  }
  __shared__ float rs[4], rs2[4];
  __shared__ float mean_s, rstd_s;
  int wid = t >> 6;
  if ((t & 63) == 0) { rs[wid] = s; rs2[wid] = s2; }
  __syncthreads();
  if (t == 0) {
    float S1 = rs[0] + rs[1] + rs[2] + rs[3];
    float S2 = rs2[0] + rs2[1] + rs2[2] + rs2[3];
    float m  = S1 / D_;
    float var = S2 / D_ - m * m;
    mean_s = m;
    rstd_s = rsqrtf(var + 1e-5f);
  }
  __syncthreads();
  float m = mean_s, r = rstd_s;
  bf16* orow = out + base;
  orow[t]       = __float2bfloat16((v0 - m) * r * g[t]       + b[t]);
  orow[t + 256] = __float2bfloat16((v1 - m) * r * g[t + 256] + b[t + 256]);
  orow[t + 512] = __float2bfloat16((v2 - m) * r * g[t + 512] + b[t + 512]);
}

// --------------------------------------- mega-fused weight convert + bias
// All weight transposes (f32 [K][N] -> bf16 [N][K]) + bias concat in ONE
// launch. Region boundaries are compile-time constants.
__device__ __forceinline__ void conv_tile(const float* __restrict__ Wsrc,
    int N, int K, bf16* __restrict__ Wdst, int n0, int k0,
    float (*t)[33], int tx, int ty) {
  for (int i = ty; i < 32; i += 8)
    t[i][tx] = Wsrc[(size_t)(k0 + i) * N + n0 + tx];
  __syncthreads();
  const int tlin = ty * 32 + tx;
  const int n = tlin >> 3;
  const int kq = (tlin & 7) * 4;
  ushort4 o;
  o.x = f2bf(t[kq + 0][n]);
  o.y = f2bf(t[kq + 1][n]);
  o.z = f2bf(t[kq + 2][n]);
  o.w = f2bf(t[kq + 3][n]);
  *reinterpret_cast<ushort4*>((unsigned short*)Wdst + (size_t)(n0 + n) * K + k0 + kq) = o;
}

#define TILE_DD   576        // 24x24 tiles for a 768x768 matrix
#define C_WQ      4608       // 8*576
#define C_WK      9216
#define C_WQC     13824
#define C_WV      18432
#define C_WKSH    19008
#define C_WVSH    19584
#define C_WO      24192
#define C_W1      42624      // + 8*2304
#define C_W2      61056      // + 8*2304
#define C_WHEAD   85056      // + 24000
#define C_BIAS    85200      // + 144
#define W6S_      ((size_t)3072 * 768)
#define DD_       ((size_t)768 * 768)
#define DF_       ((size_t)768 * 3072)

__global__ __launch_bounds__(256) void k_wconv(
    const float* __restrict__ Wq, const float* __restrict__ Wk,
    const float* __restrict__ Wqc, const float* __restrict__ Wv,
    const float* __restrict__ Wksh, const float* __restrict__ Wvsh,
    const float* __restrict__ Wo, const float* __restrict__ W1,
    const float* __restrict__ W2, const float* __restrict__ Whead,
    bf16* __restrict__ tW6, bf16* __restrict__ tWsh, bf16* __restrict__ tWo,
    bf16* __restrict__ tW1, bf16* __restrict__ tW2, bf16* __restrict__ tWhead,
    const float* __restrict__ bq, const float* __restrict__ bk,
    const float* __restrict__ bqc, const float* __restrict__ bv,
    const float* __restrict__ bksh, const float* __restrict__ bvsh,
    float* __restrict__ b6) {
  __shared__ float t[32][33];
  const int idx = blockIdx.x;
  const int tx = threadIdx.x & 31, ty = threadIdx.x >> 5;

  if (idx < C_WV) {                 // four D x D families -> tW6 sections
    int sect, tt;
    const float* src;
    if (idx < C_WQ)       { sect = 0; tt = idx;          src = Wq;  }
    else if (idx < C_WK)  { sect = 1; tt = idx - C_WQ;   src = Wk;  }
    else if (idx < C_WQC) { sect = 2; tt = idx - C_WK;   src = Wqc; }
    else                  { sect = 3; tt = idx - C_WQC;  src = Wv;  }
    const int z = tt / TILE_DD, rem = tt - z * TILE_DD;
    const int n0 = (rem % 24) * 32, k0 = (rem / 24) * 32;
    conv_tile(src + (size_t)z * DD_, 768, 768,
              tW6 + (size_t)z * W6S_ + (size_t)sect * DD_, n0, k0, t, tx, ty);
  } else if (idx < C_WVSH) {        // shared k/v
    const float* src = (idx < C_WKSH) ? Wksh : Wvsh;
    bf16* dst = (idx < C_WKSH) ? tWsh : (tWsh + DD_);
    const int rem = (idx < C_WKSH) ? (idx - C_WV) : (idx - C_WKSH);
    conv_tile(src, 768, 768, dst, (rem % 24) * 32, (rem / 24) * 32, t, tx, ty);
  } else if (idx < C_WO) {
    const int tt = idx - C_WVSH;
    const int z = tt / TILE_DD, rem = tt - z * TILE_DD;
    conv_tile(Wo + (size_t)z * DD_, 768, 768, tWo + (size_t)z * DD_,
              (rem % 24) * 32, (rem / 24) * 32, t, tx, ty);
  } else if (idx < C_W1) {          // W1: [768][3072] -> [3072][768]
    const int tt = idx - C_WO;
    const int z = tt / 2304, rem = tt - z * 2304;
    conv_tile(W1 + (size_t)z * DF_, 3072, 768, tW1 + (size_t)z * DF_,
              (rem % 96) * 32, (rem / 96) * 32, t, tx, ty);
  } else if (idx < C_W2) {          // W2: [3072][768] -> [768][3072]
    const int tt = idx - C_W1;
    const int z = tt / 2304, rem = tt - z * 2304;
    conv_tile(W2 + (size_t)z * DF_, 768, 3072, tW2 + (size_t)z * DF_,
              (rem % 24) * 32, (rem / 24) * 32, t, tx, ty);
  } else if (idx < C_WHEAD) {       // Whead: [768][32000] -> [32000][768]
    const int tt = idx - C_W2;
    conv_tile(Whead, 32000, 768, tWhead, (tt % 1000) * 32, (tt / 1000) * 32,
              t, tx, ty);
  } else {                          // bias concat
    const int i2 = (idx - C_WHEAD) * 256 + threadIdx.x;
    if (i2 < L_ * 4608) {
      const int l = i2 / 4608, c = i2 - l * 4608;
      float v = (c < 768)  ? bq[l * 768 + c]
              : (c < 1536) ? bk[l * 768 + c - 768]
              : (c < 2304) ? bqc[l * 768 + c - 1536]
              : (c < 3072) ? bv[l * 768 + c - 2304]
              : (c < 3840) ? bksh[c - 3072]
                           : bvsh[c - 3840];
      b6[i2] = v;
    }
  }
}

// ---------------------------------------------------------------- bf16 MFMA GEMM
// (per-layer GEMMs) BMx128 tile, BK=32, 3-buffer counted-vmcnt pipeline.
template <int BM, int EPI, int KSPL>
__global__ __launch_bounds__(256) void k_bgemm(
    const bf16* __restrict__ A, const bf16* __restrict__ Wt,
    const float* __restrict__ bias, const float* __restrict__ resid,
    float* __restrict__ Cf, bf16* __restrict__ Cb,
    int NM, int M, int N, int K) {
  constexpr int ASZ = BM * 64;
  constexpr int ALINES = BM / 64;
  constexpr int BSTRIDE = ASZ + 8192;
  constexpr int MF = BM / 32;
  __shared__ __align__(16) char smem[3 * BSTRIDE];
  const int tid = threadIdx.x;
  const int l = tid & 63, w = tid >> 6;
  const int wr = w >> 1, wc = w & 1;

  const int nwg = (int)gridDim.x;
  int id = (int)blockIdx.x;
  id = (id & 7) * (nwg >> 3) + (id >> 3);
  int sk = 0;
  if constexpr (KSPL == 2) {
    const int TT = nwg >> 1;
    sk = id / TT;
    id -= sk * TT;
  }
  const int m0 = (id % NM) * BM;
  const int n0 = (id / NM) * 128;
  const int kstart = sk * (K / KSPL);

  const int lane15 = l & 15, lg = l >> 4;

  const int r0 = tid >> 2, p0 = tid & 3;
  const char* aSrc[ALINES];
#pragma unroll
  for (int i = 0; i < ALINES; i++) {
    const int rr = i * 64 + r0;
    aSrc[i] = (const char*)(A + (size_t)(m0 + rr) * K + kstart) + ((p0 ^ CFUN(rr)) * 16);
  }
  const char* bSrc0 = (const char*)(Wt + (size_t)(n0 + r0) * K + kstart) + ((p0 ^ CFUN(r0)) * 16);
  const char* bSrc1 = (const char*)(Wt + (size_t)(n0 + 64 + r0) * K + kstart) + ((p0 ^ CFUN(64 + r0)) * 16);

  int aOff[MF], bOff[4];
#pragma unroll
  for (int mi = 0; mi < MF; mi++) {
    int r = wr * (BM / 2) + mi * 16 + lane15;
    aOff[mi] = r * 64 + ((lg ^ CFUN(r)) * 16);
  }
#pragma unroll
  for (int ni = 0; ni < 4; ni++) {
    int r = wc * 64 + ni * 16 + lane15;
    bOff[ni] = ASZ + r * 64 + ((lg ^ CFUN(r)) * 16);
  }

  f32x4 acc[MF][4];
#pragma unroll
  for (int mi = 0; mi < MF; mi++)
#pragma unroll
    for (int ni = 0; ni < 4; ni++) acc[mi][ni] = (f32x4){0.f, 0.f, 0.f, 0.f};

  auto stage = [&](int buf, int t) {
    const size_t kb = (size_t)t * 64;
    char* base = smem + buf * BSTRIDE;
#pragma unroll
    for (int i = 0; i < ALINES; i++)
      cp16(base + i * 4096 + w * 1024, aSrc[i] + kb);
    cp16(base + ASZ + w * 1024, bSrc0 + kb);
    cp16(base + ASZ + 4096 + w * 1024, bSrc1 + kb);
  };
  auto compute = [&](int buf) {
    const char* base = smem + buf * BSTRIDE;
    bf16x8 af[MF], bfr[4];
#pragma unroll
    for (int mi = 0; mi < MF; mi++) af[mi] = *(const bf16x8*)(base + aOff[mi]);
#pragma unroll
    for (int ni = 0; ni < 4; ni++) bfr[ni] = *(const bf16x8*)(base + bOff[ni]);
    __builtin_amdgcn_s_setprio(1);
#pragma unroll
    for (int mi = 0; mi < MF; mi++)
#pragma unroll
      for (int ni = 0; ni < 4; ni++)
        acc[mi][ni] = __builtin_amdgcn_mfma_f32_16x16x32_bf16(
            af[mi], bfr[ni], acc[mi][ni], 0, 0, 0);
    __builtin_amdgcn_s_setprio(0);
  };

  const int nk = (K / KSPL) >> 5;
  stage(0, 0);
  stage(1, 1);
  int buf = 0;
  for (int t = 0; t < nk; t++) {
    if (t + 1 < nk) {
      if constexpr (ALINES == 2) asm volatile("s_waitcnt vmcnt(4)" ::: "memory");
      else                       asm volatile("s_waitcnt vmcnt(3)" ::: "memory");
    } else {
      asm volatile("s_waitcnt vmcnt(0)" ::: "memory");
    }
    __builtin_amdgcn_s_barrier();
    if (t + 2 < nk) {
      int nb = buf + 2; if (nb >= 3) nb -= 3;
      stage(nb, t + 2);
    }
    compute(buf);
    buf = (buf == 2) ? 0 : buf + 1;
  }

#pragma unroll
  for (int ni = 0; ni < 4; ni++) {
    const int col = n0 + wc * 64 + ni * 16 + lane15;
    const float bv = bias[col];
#pragma unroll
    for (int mi = 0; mi < MF; mi++) {
      const int rowb = m0 + wr * (BM / 2) + mi * 16 + lg * 4;
      if constexpr (EPI == 7) {
#pragma unroll
        for (int j = 0; j < 4; j++)
          Cf[(size_t)sk * M * N + (size_t)(rowb + j) * N + col] = acc[mi][ni][j];
      } else {
#pragma unroll
        for (int j = 0; j < 4; j++) {
          const int row = rowb + j;
          float v = acc[mi][ni][j] + bv;
          if constexpr (EPI == 1) v += resid[(size_t)row * N + col];
          if constexpr (EPI == 2) {
            v = 0.5f * v * (1.0f + erff(v * 0.70710678118654752f));
            Cb[(size_t)row * N + col] = __float2bfloat16(v);
          } else if constexpr (EPI == 3) {
            Cb[(size_t)row * N + col] = __float2bfloat16(v);
          } else {
            Cf[(size_t)row * N + col] = v;
          }
        }
      }
    }
  }
}

// ------------------------------------------- 8-phase 256x256 GEMM (K=768)
#define HBAR() asm volatile("s_barrier" ::: "memory")
#define MFMA16(AF, BF, MB, NB)                                               \
  do {                                                                       \
    __builtin_amdgcn_s_setprio(1);                                           \
    _Pragma("unroll") for (int mi_ = 0; mi_ < 4; mi_++)                      \
      _Pragma("unroll") for (int ni_ = 0; ni_ < 2; ni_++)                    \
        _Pragma("unroll") for (int ks_ = 0; ks_ < 2; ks_++)                  \
          acc[(MB) + mi_][(NB) + ni_] =                                      \
              __builtin_amdgcn_mfma_f32_16x16x32_bf16(                       \
                  AF[mi_][ks_], BF[ni_][ks_], acc[(MB) + mi_][(NB) + ni_],   \
                  0, 0, 0);                                                  \
    __builtin_amdgcn_s_setprio(0);                                           \
  } while (0)

template <int EPI>
__global__ __launch_bounds__(512, 1) void k_g8(const bf16* __restrict__ A,
    const bf16* __restrict__ Wt, const bf16* __restrict__ Wt2,
    const float* __restrict__ bias, float* __restrict__ Cf,
    bf16* __restrict__ Cb, bf16* __restrict__ Cb2, bf16* __restrict__ Cb3) {
  __shared__ __align__(16) char smem[131072];
  const int tid = threadIdx.x;
  const int l = tid & 63, w = tid >> 6;
  const int wr = w >> 2, wc = w & 3;
  const int lane15 = l & 15, lg = l >> 4;

  const int nwg = (int)gridDim.x;
  int id = (int)blockIdx.x;
  id = (id & 7) * (nwg >> 3) + (id >> 3);
  const int m0 = (id % 8) * 256;
  const int n0 = (id / 8) * 256;

  const bf16* WB = Wt;
  int nb0 = n0;
  if constexpr (EPI == 6) {
    if (n0 >= 3072) { WB = Wt2; nb0 = n0 - 3072; }
  }

  auto issueA = [&](int tile, int hb) {
#pragma unroll
    for (int j = 0; j < 2; j++) {
      const int idx = j * 512 + tid;
      const int rl = idx >> 3, sl = idx & 7;
      const bf16* g = A + (size_t)(m0 + hb + rl) * 768 + tile * 64 +
                      ((sl ^ (rl & 7)) << 3);
      cp16(smem + (tile & 1) * 32768 + hb * 128 + (j * 512 + w * 64) * 16, g);
    }
  };
  auto issueB = [&](int tile, int hb) {
#pragma unroll
    for (int j = 0; j < 2; j++) {
      const int idx = j * 512 + tid;
      const int rl = idx >> 3, sl = idx & 7;
      const bf16* g = WB + (size_t)(nb0 + hb + rl) * 768 + tile * 64 +
                      ((sl ^ (rl & 7)) << 3);
      cp16(smem + 65536 + (tile & 1) * 32768 + hb * 128 + (j * 512 + w * 64) * 16, g);
    }
  };
  auto ldA = [&](int buf, int mi, int ks) {
    const int r = wr * 128 + mi * 16 + lane15;
    return *(const bf16x8*)(smem + buf * 32768 + r * 128 +
                            ((((ks << 2) + lg) ^ (r & 7)) << 4));
  };
  auto ldB = [&](int buf, int ni, int ks) {
    const int r = wc * 64 + ni * 16 + lane15;
    return *(const bf16x8*)(smem + 65536 + buf * 32768 + r * 128 +
                            ((((ks << 2) + lg) ^ (r & 7)) << 4));
  };

  f32x4 acc[8][4];
#pragma unroll
  for (int i = 0; i < 8; i++)
#pragma unroll
    for (int j = 0; j < 4; j++) acc[i][j] = (f32x4){0.f, 0.f, 0.f, 0.f};
  bf16x8 alo[4][2], ahi[4][2], blo[2][2], bhi[2][2];

  issueA(0, 0);  issueA(0, 128);  issueB(0, 0);  issueB(0, 128);
  issueB(1, 0);  issueA(1, 0);    issueB(1, 128);
  asm volatile("s_waitcnt vmcnt(6)" ::: "memory");
  HBAR();

  for (int it = 0; it < 5; ++it) {
    const int Tb = 2 * it + 1, Tn = 2 * it + 2;
#pragma unroll
    for (int mi = 0; mi < 4; mi++) { alo[mi][0] = ldA(0, mi, 0); alo[mi][1] = ldA(0, mi, 1); }
#pragma unroll
    for (int ni = 0; ni < 2; ni++) { blo[ni][0] = ldB(0, ni, 0); blo[ni][1] = ldB(0, ni, 1); }
    issueA(Tb, 128);
    HBAR(); MFMA16(alo, blo, 0, 0); HBAR();
#pragma unroll
    for (int ni = 0; ni < 2; ni++) { bhi[ni][0] = ldB(0, ni + 2, 0); bhi[ni][1] = ldB(0, ni + 2, 1); }
    HBAR(); MFMA16(alo, bhi, 0, 2); HBAR();
#pragma unroll
    for (int mi = 0; mi < 4; mi++) { ahi[mi][0] = ldA(0, mi + 4, 0); ahi[mi][1] = ldA(0, mi + 4, 1); }
    issueB(Tn, 0);
    HBAR(); MFMA16(ahi, bhi, 4, 2); HBAR();
    issueA(Tn, 0);
    issueB(Tn, 128);
    asm volatile("s_waitcnt vmcnt(6)" ::: "memory");
    HBAR(); MFMA16(ahi, blo, 4, 0); HBAR();
#pragma unroll
    for (int mi = 0; mi < 4; mi++) { alo[mi][0] = ldA(1, mi, 0); alo[mi][1] = ldA(1, mi, 1); }
#pragma unroll
    for (int ni = 0; ni < 2; ni++) { blo[ni][0] = ldB(1, ni, 0); blo[ni][1] = ldB(1, ni, 1); }
    issueA(Tn, 128);
    HBAR(); MFMA16(alo, blo, 0, 0); HBAR();
#pragma unroll
    for (int ni = 0; ni < 2; ni++) { bhi[ni][0] = ldB(1, ni + 2, 0); bhi[ni][1] = ldB(1, ni + 2, 1); }
    HBAR(); MFMA16(alo, bhi, 0, 2); HBAR();
#pragma unroll
    for (int mi = 0; mi < 4; mi++) { ahi[mi][0] = ldA(1, mi + 4, 0); ahi[mi][1] = ldA(1, mi + 4, 1); }
    issueB(Tn + 1, 0);
    HBAR(); MFMA16(ahi, bhi, 4, 2); HBAR();
    issueA(Tn + 1, 0);
    issueB(Tn + 1, 128);
    asm volatile("s_waitcnt vmcnt(6)" ::: "memory");
    HBAR(); MFMA16(ahi, blo, 4, 0); HBAR();
  }

  {
#pragma unroll
    for (int mi = 0; mi < 4; mi++) { alo[mi][0] = ldA(0, mi, 0); alo[mi][1] = ldA(0, mi, 1); }
#pragma unroll
    for (int ni = 0; ni < 2; ni++) { blo[ni][0] = ldB(0, ni, 0); blo[ni][1] = ldB(0, ni, 1); }
    issueA(11, 128);
    HBAR(); MFMA16(alo, blo, 0, 0); HBAR();
#pragma unroll
    for (int ni = 0; ni < 2; ni++) { bhi[ni][0] = ldB(0, ni + 2, 0); bhi[ni][1] = ldB(0, ni + 2, 1); }
    HBAR(); MFMA16(alo, bhi, 0, 2); HBAR();
#pragma unroll
    for (int mi = 0; mi < 4; mi++) { ahi[mi][0] = ldA(0, mi + 4, 0); ahi[mi][1] = ldA(0, mi + 4, 1); }
    HBAR(); MFMA16(ahi, bhi, 4, 2); HBAR();
    asm volatile("s_waitcnt vmcnt(0)" ::: "memory");
    HBAR(); MFMA16(ahi, blo, 4, 0); HBAR();
#pragma unroll
    for (int mi = 0; mi < 4; mi++) { alo[mi][0] = ldA(1, mi, 0); alo[mi][1] = ldA(1, mi, 1); }
#pragma unroll
    for (int ni = 0; ni < 2; ni++) { blo[ni][0] = ldB(1, ni, 0); blo[ni][1] = ldB(1, ni, 1); }
    MFMA16(alo, blo, 0, 0);
#pragma unroll
    for (int ni = 0; ni < 2; ni++) { bhi[ni][0] = ldB(1, ni + 2, 0); bhi[ni][1] = ldB(1, ni + 2, 1); }
    MFMA16(alo, bhi, 0, 2);
#pragma unroll
    for (int mi = 0; mi < 4; mi++) { ahi[mi][0] = ldA(1, mi + 4, 0); ahi[mi][1] = ldA(1, mi + 4, 1); }
    MFMA16(ahi, bhi, 4, 2);
    MFMA16(ahi, blo, 4, 0);
  }

  // epilogue
#pragma unroll
  for (int ni = 0; ni < 4; ni++) {
    const int col = n0 + wc * 64 + ni * 16 + lane15;
    const float bv = bias[col];
#pragma unroll
    for (int mi = 0; mi < 8; mi++) {
      const int rowb = m0 + wr * 128 + mi * 16 + lg * 4;
      if constexpr (EPI == 0) {
#pragma unroll
        for (int j = 0; j < 4; j++)
          Cf[(size_t)(rowb + j) * 32000 + col] = acc[mi][ni][j] + bv;
      } else {  // EPI == 6
        if (col < 2304) {
#pragma unroll
          for (int j = 0; j < 4; j++)
            Cb[(size_t)(rowb + j) * 2304 + col] = __float2bfloat16(acc[mi][ni][j] + bv);
        } else if (col < 3072) {
          ushort4 pk;
          pk.x = f2bf(acc[mi][ni][0] + bv);
          pk.y = f2bf(acc[mi][ni][1] + bv);
          pk.z = f2bf(acc[mi][ni][2] + bv);
          pk.w = f2bf(acc[mi][ni][3] + bv);
          const int bq = rowb >> 10, s = rowb & (S_ - 1);
          *reinterpret_cast<ushort4*>(
              (unsigned short*)Cb2 + ((size_t)(bq * 768 + (col - 2304))) * S_ + s) = pk;
        } else {
#pragma unroll
          for (int j = 0; j < 4; j++)
            Cb3[(size_t)(rowb + j) * 1536 + (col - 3072)] =
                __float2bfloat16(acc[mi][ni][j] + bv);
        }
      }
    }
  }
}

// ---------------------------------------------------------------- flash attention
__global__ __launch_bounds__(256) void k_attn(
    const bf16* __restrict__ qkv, const bf16* __restrict__ vT,
    const bf16* __restrict__ memkv, bf16* __restrict__ ctx, int layer) {
  const int bh = blockIdx.x;
  const int b = bh / H_, h = bh % H_;
  const int qt = (int)gridDim.y - 1 - (int)blockIdx.y;   // big q first
  const int tid = threadIdx.x;
  const int w = tid >> 6, l = tid & 63;
  const int lane15 = l & 15, lg = l >> 4;
  const float inv = 0.125f;

  __shared__ char plds[4][2048];
  __shared__ float wlp[4][16][16];
  char* pl = plds[w];

  const int qrow0 = qt * 64 + w * 16;
  const size_t rowA = (size_t)(b * S_ + qrow0 + lane15);
  const bf16* qp = qkv + rowA * 2304 + h * 64 + lg * 8;
  auto scale8 = [](bf16x8 v) {
    bf16x8 r;
#pragma unroll
    for (int e = 0; e < 8; e++)
      r[e] = (short)f2bf(bf2f((unsigned short)v[e]) * 0.125f);
    return r;
  };
  const bf16x8 qf0 = scale8(*(const bf16x8*)(qp));
  const bf16x8 qf1 = scale8(*(const bf16x8*)(qp + 32));

  const bf16* kbase = qkv + (size_t)(b * S_) * 2304 + 768 + h * 64 + lg * 8;
  const bf16* vbase = vT + ((size_t)(b * 768 + h * 64 + lane15)) * S_;

  float mrow[4], dsum[4];
  f32x4 acc[4];
#pragma unroll
  for (int j = 0; j < 4; j++) { mrow[j] = -INFINITY; dsum[j] = 0.f; }
#pragma unroll
  for (int ni = 0; ni < 4; ni++) acc[ni] = (f32x4){0.f, 0.f, 0.f, 0.f};

  const int ntile = ((qrow0 + 15) >> 6) + 1;
  for (int kt64 = 0; kt64 < ntile; kt64++) {
    const int k0 = kt64 * 64;
    f32x4 sc[4];
#pragma unroll
    for (int kt = 0; kt < 4; kt++) {
      const bf16* kp = kbase + (size_t)(k0 + kt * 16 + lane15) * 2304;
      bf16x8 kf0 = *(const bf16x8*)(kp);
      bf16x8 kf1 = *(const bf16x8*)(kp + 32);
      f32x4 z = (f32x4){0.f, 0.f, 0.f, 0.f};
      z = __builtin_amdgcn_mfma_f32_16x16x32_bf16(qf0, kf0, z, 0, 0, 0);
      sc[kt] = __builtin_amdgcn_mfma_f32_16x16x32_bf16(qf1, kf1, z, 0, 0, 0);
    }
    float tmax[4];
#pragma unroll
    for (int j = 0; j < 4; j++) tmax[j] = -INFINITY;
    const bool needMask = (k0 + 63 > qrow0);
    if (needMask) {
#pragma unroll
      for (int kt = 0; kt < 4; kt++) {
        const int kabs = k0 + kt * 16 + lane15;
#pragma unroll
        for (int j = 0; j < 4; j++) {
          const int qabs = qrow0 + lg * 4 + j;
          float v = (kabs <= qabs) ? sc[kt][j] : -INFINITY;
          sc[kt][j] = v;
          tmax[j] = fmaxf(tmax[j], v);
        }
      }
    } else {
#pragma unroll
      for (int kt = 0; kt < 4; kt++)
#pragma unroll
        for (int j = 0; j < 4; j++) tmax[j] = fmaxf(tmax[j], sc[kt][j]);
    }
#pragma unroll
    for (int off = 1; off < 16; off <<= 1)
#pragma unroll
      for (int j = 0; j < 4; j++) tmax[j] = fmaxf(tmax[j], __shfl_xor(tmax[j], off, 16));

    bool grow = false;
#pragma unroll
    for (int j = 0; j < 4; j++) grow |= (tmax[j] > mrow[j]);
    if (__ballot(grow) != 0ull) {
#pragma unroll
      for (int j = 0; j < 4; j++) {
        const float mnew = fmaxf(mrow[j], tmax[j]);
        const float alpha = __expf(mrow[j] - mnew);
        mrow[j] = mnew;
        dsum[j] *= alpha;
#pragma unroll
        for (int ni = 0; ni < 4; ni++) acc[ni][j] *= alpha;
      }
    }
    float psum[4] = {0.f, 0.f, 0.f, 0.f};
#pragma unroll
    for (int kt = 0; kt < 4; kt++) {
      const int gsl = kt * 2 + (lane15 >> 3);
      const int ebyte = (lane15 & 7) * 2;
#pragma unroll
      for (int j = 0; j < 4; j++) {
        const float p = __expf(sc[kt][j] - mrow[j]);
        psum[j] += p;
        const int r = lg * 4 + j;
        *(unsigned short*)(pl + r * 128 + ((gsl ^ (r & 7)) << 4) + ebyte) = f2bf(p);
      }
    }
#pragma unroll
    for (int off = 1; off < 16; off <<= 1)
#pragma unroll
      for (int j = 0; j < 4; j++) psum[j] += __shfl_xor(psum[j], off, 16);
#pragma unroll
    for (int j = 0; j < 4; j++) dsum[j] += psum[j];

#pragma unroll
    for (int ks = 0; ks < 2; ks++) {
      bf16x8 pa = *(const bf16x8*)(pl + lane15 * 128 +
                                   ((((ks << 2) + lg) ^ (lane15 & 7)) << 4));
      const bf16* vp = vbase + k0 + ks * 32 + lg * 8;
#pragma unroll
      for (int ni = 0; ni < 4; ni++) {
        bf16x8 vf = *(const bf16x8*)(vp + (size_t)ni * 16 * S_);
        acc[ni] = __builtin_amdgcn_mfma_f32_16x16x32_bf16(pa, vf, acc[ni], 0, 0, 0);
      }
    }
  }

  const int r4 = lg * 4;
  if (lane15 < layer) {
    const int ml = lane15;
#pragma unroll
    for (int j = 0; j < 4; j++) {
      const size_t rowB = (size_t)(b * S_) + qrow0 + r4 + j;
      const bf16* qc = qkv + rowB * 2304 + 1536 + h * 64;
      const bf16* mk = memkv + ((size_t)ml * BS_ + rowB) * 1536 + h * 64;
      float d_ = 0.f;
#pragma unroll
      for (int t = 0; t < 8; t++) {
        bf16x8 qv = *(const bf16x8*)(qc + t * 8);
        bf16x8 kv = *(const bf16x8*)(mk + t * 8);
#pragma unroll
        for (int e = 0; e < 8; e++)
          d_ += bf2f((unsigned short)qv[e]) * bf2f((unsigned short)kv[e]);
      }
      wlp[w][r4 + j][ml] = d_ * inv;
    }
  }
  if (layer > 0) {
#pragma unroll
    for (int j = 0; j < 4; j++) {
      const int r = r4 + j;
      float mm = -INFINITY;
      for (int ml = 0; ml < layer; ml++) mm = fmaxf(mm, wlp[w][r][ml]);
      const float mnew = fmaxf(mrow[j], mm);
      const float alpha = __expf(mrow[j] - mnew);
      mrow[j] = mnew;
      dsum[j] *= alpha;
#pragma unroll
      for (int ni = 0; ni < 4; ni++) acc[ni][j] *= alpha;
      const size_t rowB = (size_t)(b * S_) + qrow0 + r;
      for (int ml = 0; ml < layer; ml++) {
        const float p = __expf(wlp[w][r][ml] - mnew);
        dsum[j] += p;
        const unsigned short* mv = (const unsigned short*)(memkv +
            ((size_t)ml * BS_ + rowB) * 1536 + 768 + h * 64 + lane15);
#pragma unroll
        for (int ni = 0; ni < 4; ni++)
          acc[ni][j] += p * bf2f(mv[ni * 16]);
      }
    }
  }

#pragma unroll
  for (int j = 0; j < 4; j++) {
    const float rd = 1.f / dsum[j];
    const size_t rowB = (size_t)(b * S_) + qrow0 + r4 + j;
    bf16* cp = ctx + rowB * 768 + h * 64 + lane15;
#pragma unroll
    for (int ni = 0; ni < 4; ni++)
      cp[ni * 16] = __float2bfloat16(acc[ni][j] * rd);
  }
}

// ---------------------------------------------------------------- launch
extern "C" void kernel_launch(void* const* d_in, const int* in_sizes, int n_in,
                              void* d_out, int out_size, void* d_ws, size_t ws_size,
                              hipStream_t stream) {
  const int*   tokens  = (const int*)d_in[0];
  const float* tok_emb = (const float*)d_in[1];
  const float* pos_emb = (const float*)d_in[2];
  const float *Wq_row, *Wk_row, *Wv_row, *Wq_col, *Wo;
  const float *bq_row, *bk_row, *bv_row, *bq_col, *bo;
  if (in_sizes[4] == L_ * D_ * D_) {  // dict order
    Wq_row = (const float*)d_in[3];  Wk_row = (const float*)d_in[4];
    Wv_row = (const float*)d_in[5];  Wq_col = (const float*)d_in[6];
    Wo     = (const float*)d_in[7];
    bq_row = (const float*)d_in[8];  bk_row = (const float*)d_in[9];
    bv_row = (const float*)d_in[10]; bq_col = (const float*)d_in[11];
    bo     = (const float*)d_in[12];
  } else {  // signature order fallback
    Wq_row = (const float*)d_in[3];  bq_row = (const float*)d_in[4];
    Wk_row = (const float*)d_in[5];  bk_row = (const float*)d_in[6];
    Wv_row = (const float*)d_in[7];  bv_row = (const float*)d_in[8];
    Wq_col = (const float*)d_in[9];  bq_col = (const float*)d_in[10];
    Wo     = (const float*)d_in[11]; bo     = (const float*)d_in[12];
  }
  const float* ln1_g = (const float*)d_in[13]; const float* ln1_b = (const float*)d_in[14];
  const float* ln2_g = (const float*)d_in[15]; const float* ln2_b = (const float*)d_in[16];
  const float* W1    = (const float*)d_in[17]; const float* b1    = (const float*)d_in[18];
  const float* W2    = (const float*)d_in[19]; const float* b2    = (const float*)d_in[20];
  const float* Wk_sh = (const float*)d_in[21]; const float* bk_sh = (const float*)d_in[22];
  const float* Wv_sh = (const float*)d_in[23]; const float* bv_sh = (const float*)d_in[24];
  const float* lnf_g = (const float*)d_in[25]; const float* lnf_b = (const float*)d_in[26];
  const float* Whead = (const float*)d_in[27]; const float* bhead = (const float*)d_in[28];

  // ---- workspace carve-up
  char* p = (char*)d_ws;
  float* x      = (float*)p; p += (size_t)BS_ * D_ * 4;
  bf16*  h_bf   = (bf16*)p;  p += (size_t)BS_ * D_ * 2;
  bf16*  qkv3   = (bf16*)p;  p += (size_t)BS_ * 2304 * 2;
  bf16*  vTb    = (bf16*)p;  p += (size_t)B_ * 768 * S_ * 2;
  bf16*  memkv  = (bf16*)p;  p += (size_t)L_ * BS_ * 1536 * 2;
  bf16*  ctx_bf = (bf16*)p;  p += (size_t)BS_ * D_ * 2;
  bf16*  mlp_bf = (bf16*)p;  p += (size_t)BS_ * DFF_ * 2;
  float* pkbuf  = (float*)p; p += (size_t)2 * BS_ * D_ * 4;   // split-K partials
  float* b6cat  = (float*)p; p += (size_t)L_ * 4608 * 4;
  bf16* tW6    = (bf16*)p; p += (size_t)L_ * 3072 * D_ * 2;   // q|k|qc|v rows
  bf16* tWsh   = (bf16*)p; p += (size_t)1536 * D_ * 2;        // ksh|vsh rows
  bf16* tWo    = (bf16*)p; p += (size_t)L_ * D_ * D_ * 2;
  bf16* tW1    = (bf16*)p; p += (size_t)L_ * DFF_ * D_ * 2;
  bf16* tW2    = (bf16*)p; p += (size_t)L_ * D_ * DFF_ * 2;
  bf16* tWhead = (bf16*)p; p += (size_t)V_ * D_ * 2;

  // ---- single-launch weight conversion + bias concat
  k_wconv<<<dim3(C_BIAS), 256, 0, stream>>>(
      Wq_row, Wk_row, Wq_col, Wv_row, Wk_sh, Wv_sh, Wo, W1, W2, Whead,
      tW6, tWsh, tWo, tW1, tW2, tWhead,
      bq_row, bk_row, bq_col, bv_row, bk_sh, bv_sh, b6cat);

  // fused embed + layer-0 ln1
  k_embedln<<<dim3(BS_), 256, 0, stream>>>(tokens, tok_emb, pos_emb,
                                           ln1_g, ln1_b, x, h_bf);

  const size_t DD = (size_t)D_ * D_;
  const size_t W6S = (size_t)3072 * 768;
  for (int i = 0; i < L_; i++) {
    k_g8<6><<<dim3(144), 512, 0, stream>>>(
        h_bf, tW6 + (size_t)i * W6S, tWsh, b6cat + (size_t)i * 4608,
        nullptr, qkv3, vTb, memkv + (size_t)i * BS_ * 1536);
    k_attn<<<dim3(B_ * H_, S_ / 64), 256, 0, stream>>>(qkv3, vTb, memkv, ctx_bf, i);
    k_bgemm<64, 7, 2><<<dim3(384), 256, 0, stream>>>(
        ctx_bf, tWo + (size_t)i * DD, bo + i * D_,
        nullptr, pkbuf, nullptr, 32, BS_, 768, 768);
    k_redln<<<dim3(BS_), 256, 0, stream>>>(x, pkbuf, bo + i * D_,
                                           ln2_g + i * D_, ln2_b + i * D_, h_bf);
    k_bgemm<128, 2, 1><<<dim3(384), 256, 0, stream>>>(
        h_bf, tW1 + (size_t)i * 3072 * 768, b1 + (size_t)i * DFF_,
        nullptr, nullptr, mlp_bf, 16, BS_, 3072, 768);
    k_bgemm<64, 7, 2><<<dim3(384), 256, 0, stream>>>(
        mlp_bf, tW2 + (size_t)i * 768 * 3072, b2 + i * D_,
        nullptr, pkbuf, nullptr, 32, BS_, 768, 3072);
    const float* gn = (i < L_ - 1) ? (ln1_g + (i + 1) * D_) : lnf_g;
    const float* bn = (i < L_ - 1) ? (ln1_b + (i + 1) * D_) : lnf_b;
    k_redln<<<dim3(BS_), 256, 0, stream>>>(x, pkbuf, b2 + i * D_, gn, bn, h_bf);
  }
  k_g8<0><<<dim3(1000), 512, 0, stream>>>(h_bf, tWhead, nullptr, bhead,
                                          (float*)d_out, nullptr, nullptr, nullptr);
}

// Round 16
// 1563.571 us; speedup vs baseline: 1.3199x; 1.0160x over previous
//
#include <hip/hip_runtime.h>
#include <hip/hip_bf16.h>
#include <math.h>

#define L_   8
#define D_   768
#define H_   12
#define V_   32000
#define B_   2
#define S_   1024
#define HD_  64
#define BS_  2048      // B_*S_
#define DFF_ 3072      // MR*D

typedef __hip_bfloat16 bf16;
typedef __attribute__((ext_vector_type(8))) short bf16x8;
typedef __attribute__((ext_vector_type(4))) float f32x4;

// Balanced LDS slot swizzle for the 128x128 k_bgemm (BK=32, 4-slot rows)
#define CFUN(r) (((r) >> 1) & 3)

__device__ __forceinline__ void cp16(void* lds, const void* g) {
  __builtin_amdgcn_global_load_lds(
      (const __attribute__((address_space(1))) void*)g,
      (__attribute__((address_space(3))) void*)lds, 16, 0, 0);
}

__device__ __forceinline__ unsigned short f2bf(float v) {
  __hip_bfloat16 h = __float2bfloat16(v);
  return *reinterpret_cast<unsigned short*>(&h);
}
__device__ __forceinline__ float bf2f(unsigned short u) {
  return __uint_as_float(((unsigned)u) << 16);
}

// ------------------------------------------- fused embed + layer-0 LN
__global__ __launch_bounds__(256) void k_embedln(const int* __restrict__ tokens,
    const float* __restrict__ tok_emb, const float* __restrict__ pos_emb,
    const float* __restrict__ g, const float* __restrict__ b,
    float* __restrict__ x, bf16* __restrict__ out) {
  const int row = blockIdx.x;
  const int t = threadIdx.x;
  const int s = row & (S_ - 1);
  const int tok = tokens[row];
  const size_t base = (size_t)row * D_;
  const float* te = tok_emb + (size_t)tok * D_;
  const float* pe = pos_emb + (size_t)s * D_;
  float v0 = te[t] + pe[t];
  float v1 = te[t + 256] + pe[t + 256];
  float v2 = te[t + 512] + pe[t + 512];
  x[base + t] = v0; x[base + t + 256] = v1; x[base + t + 512] = v2;
  float sum  = v0 + v1 + v2;
  float s2 = v0 * v0 + v1 * v1 + v2 * v2;
#pragma unroll
  for (int off = 32; off; off >>= 1) {
    sum += __shfl_down(sum, off);
    s2  += __shfl_down(s2, off);
  }
  __shared__ float rs[4], rs2[4];
  __shared__ float mean_s, rstd_s;
  int wid = t >> 6;
  if ((t & 63) == 0) { rs[wid] = sum; rs2[wid] = s2; }
  __syncthreads();
  if (t == 0) {
    float S1 = rs[0] + rs[1] + rs[2] + rs[3];
    float S2 = rs2[0] + rs2[1] + rs2[2] + rs2[3];
    float m  = S1 / D_;
    float var = S2 / D_ - m * m;
    mean_s = m;
    rstd_s = rsqrtf(var + 1e-5f);
  }
  __syncthreads();
  float m = mean_s, r = rstd_s;
  bf16* orow = out + base;
  orow[t]       = __float2bfloat16((v0 - m) * r * g[t]       + b[t]);
  orow[t + 256] = __float2bfloat16((v1 - m) * r * g[t + 256] + b[t + 256]);
  orow[t + 512] = __float2bfloat16((v2 - m) * r * g[t + 512] + b[t + 512]);
}

// ---------------------------------- fused split-K reduce + residual + LN
__global__ __launch_bounds__(256) void k_redln(float* __restrict__ x,
    const float* __restrict__ pk, const float* __restrict__ b2,
    const float* __restrict__ g, const float* __restrict__ b,
    bf16* __restrict__ out) {
  const int row = blockIdx.x;
  const int t = threadIdx.x;
  const size_t base = (size_t)row * D_;
  const size_t MN = (size_t)BS_ * D_;
  float v0, v1, v2;
  {
    int c0 = t, c1 = t + 256, c2 = t + 512;
    v0 = x[base + c0] + pk[base + c0] + pk[MN + base + c0] + b2[c0];
    v1 = x[base + c1] + pk[base + c1] + pk[MN + base + c1] + b2[c1];
    v2 = x[base + c2] + pk[base + c2] + pk[MN + base + c2] + b2[c2];
    x[base + c0] = v0; x[base + c1] = v1; x[base + c2] = v2;
  }
  float s  = v0 + v1 + v2;
  float s2 = v0 * v0 + v1 * v1 + v2 * v2;
#pragma unroll
  for (int off = 32; off; off >>= 1) {
    s  += __shfl_down(s, off);
    s2 += __shfl_down(s2, off);
  }
  __shared__ float rs[4], rs2[4];
  __shared__ float mean_s, rstd_s;
  int wid = t >> 6;
  if ((t & 63) == 0) { rs[wid] = s; rs2[wid] = s2; }
  __syncthreads();
  if (t == 0) {
    float S1 = rs[0] + rs[1] + rs[2] + rs[3];
    float S2 = rs2[0] + rs2[1] + rs2[2] + rs2[3];
    float m  = S1 / D_;
    float var = S2 / D_ - m * m;
    mean_s = m;
    rstd_s = rsqrtf(var + 1e-5f);
  }
  __syncthreads();
  float m = mean_s, r = rstd_s;
  bf16* orow = out + base;
  orow[t]       = __float2bfloat16((v0 - m) * r * g[t]       + b[t]);
  orow[t + 256] = __float2bfloat16((v1 - m) * r * g[t + 256] + b[t + 256]);
  orow[t + 512] = __float2bfloat16((v2 - m) * r * g[t + 512] + b[t + 512]);
}

// --------------------------------------- mega-fused weight convert + bias
// 64x64 tiles, float4 coalesced loads (64 B/thread), LDS transpose,
// ushort4 stores. All weights + bias concat in ONE launch.
__device__ __forceinline__ void conv_tile64(const float* __restrict__ Wsrc,
    int N, int K, bf16* __restrict__ Wdst, int n0, int k0,
    float (*t)[65], int tid) {
  const int ro = tid >> 4;            // 0..15
  const int cq = (tid & 15) * 4;      // 0..60 step 4
#pragma unroll
  for (int i = 0; i < 4; i++) {
    const int row = i * 16 + ro;
    float4 v = *reinterpret_cast<const float4*>(
        Wsrc + (size_t)(k0 + row) * N + n0 + cq);
    t[row][cq] = v.x; t[row][cq + 1] = v.y;
    t[row][cq + 2] = v.z; t[row][cq + 3] = v.w;
  }
  __syncthreads();
  const int n = tid >> 2;             // 0..63
  const int kq0 = (tid & 3) * 16;     // 0,16,32,48
  unsigned short* dst = (unsigned short*)Wdst + (size_t)(n0 + n) * K + k0;
#pragma unroll
  for (int kk = 0; kk < 4; kk++) {
    const int kq = kq0 + kk * 4;
    ushort4 o;
    o.x = f2bf(t[kq][n]);     o.y = f2bf(t[kq + 1][n]);
    o.z = f2bf(t[kq + 2][n]); o.w = f2bf(t[kq + 3][n]);
    *reinterpret_cast<ushort4*>(dst + kq) = o;
  }
}

#define TILE_DD   144        // 12x12 64-tiles for a 768x768 matrix
#define C_WQ      1152       // 8*144
#define C_WK      2304
#define C_WQC     3456
#define C_WV      4608
#define C_WKSH    4752
#define C_WVSH    4896
#define C_WO      6048
#define C_W1      10656      // + 8*576
#define C_W2      15264      // + 8*576
#define C_WHEAD   21264      // + 6000 (500x12)
#define C_BIAS    21408      // + 144
#define W6S_      ((size_t)3072 * 768)
#define DD_       ((size_t)768 * 768)
#define DF_       ((size_t)768 * 3072)

__global__ __launch_bounds__(256) void k_wconv(
    const float* __restrict__ Wq, const float* __restrict__ Wk,
    const float* __restrict__ Wqc, const float* __restrict__ Wv,
    const float* __restrict__ Wksh, const float* __restrict__ Wvsh,
    const float* __restrict__ Wo, const float* __restrict__ W1,
    const float* __restrict__ W2, const float* __restrict__ Whead,
    bf16* __restrict__ tW6, bf16* __restrict__ tWsh, bf16* __restrict__ tWo,
    bf16* __restrict__ tW1, bf16* __restrict__ tW2, bf16* __restrict__ tWhead,
    const float* __restrict__ bq, const float* __restrict__ bk,
    const float* __restrict__ bqc, const float* __restrict__ bv,
    const float* __restrict__ bksh, const float* __restrict__ bvsh,
    float* __restrict__ b6) {
  __shared__ float t[64][65];
  const int idx = blockIdx.x;
  const int tid = threadIdx.x;

  if (idx < C_WV) {                 // four D x D families -> tW6 sections
    int sect, tt;
    const float* src;
    if (idx < C_WQ)       { sect = 0; tt = idx;          src = Wq;  }
    else if (idx < C_WK)  { sect = 1; tt = idx - C_WQ;   src = Wk;  }
    else if (idx < C_WQC) { sect = 2; tt = idx - C_WK;   src = Wqc; }
    else                  { sect = 3; tt = idx - C_WQC;  src = Wv;  }
    const int z = tt / TILE_DD, rem = tt - z * TILE_DD;
    conv_tile64(src + (size_t)z * DD_, 768, 768,
                tW6 + (size_t)z * W6S_ + (size_t)sect * DD_,
                (rem % 12) * 64, (rem / 12) * 64, t, tid);
  } else if (idx < C_WVSH) {        // shared k/v
    const float* src = (idx < C_WKSH) ? Wksh : Wvsh;
    bf16* dst = (idx < C_WKSH) ? tWsh : (tWsh + DD_);
    const int rem = (idx < C_WKSH) ? (idx - C_WV) : (idx - C_WKSH);
    conv_tile64(src, 768, 768, dst, (rem % 12) * 64, (rem / 12) * 64, t, tid);
  } else if (idx < C_WO) {
    const int tt = idx - C_WVSH;
    const int z = tt / TILE_DD, rem = tt - z * TILE_DD;
    conv_tile64(Wo + (size_t)z * DD_, 768, 768, tWo + (size_t)z * DD_,
                (rem % 12) * 64, (rem / 12) * 64, t, tid);
  } else if (idx < C_W1) {          // W1: [768][3072] -> [3072][768]
    const int tt = idx - C_WO;
    const int z = tt / 576, rem = tt - z * 576;
    conv_tile64(W1 + (size_t)z * DF_, 3072, 768, tW1 + (size_t)z * DF_,
                (rem % 48) * 64, (rem / 48) * 64, t, tid);
  } else if (idx < C_W2) {          // W2: [3072][768] -> [768][3072]
    const int tt = idx - C_W1;
    const int z = tt / 576, rem = tt - z * 576;
    conv_tile64(W2 + (size_t)z * DF_, 768, 3072, tW2 + (size_t)z * DF_,
                (rem % 12) * 64, (rem / 12) * 64, t, tid);
  } else if (idx < C_WHEAD) {       // Whead: [768][32000] -> [32000][768]
    const int tt = idx - C_W2;
    conv_tile64(Whead, 32000, 768, tWhead, (tt % 500) * 64, (tt / 500) * 64,
                t, tid);
  } else {                          // bias concat
    const int i2 = (idx - C_WHEAD) * 256 + tid;
    if (i2 < L_ * 4608) {
      const int l = i2 / 4608, c = i2 - l * 4608;
      float v = (c < 768)  ? bq[l * 768 + c]
              : (c < 1536) ? bk[l * 768 + c - 768]
              : (c < 2304) ? bqc[l * 768 + c - 1536]
              : (c < 3072) ? bv[l * 768 + c - 2304]
              : (c < 3840) ? bksh[c - 3072]
                           : bvsh[c - 3840];
      b6[i2] = v;
    }
  }
}

// ---------------------------------------------------------------- bf16 MFMA GEMM
// (per-layer GEMMs) BMx128 tile, BK=32, 3-buffer counted-vmcnt pipeline.
template <int BM, int EPI, int KSPL>
__global__ __launch_bounds__(256) void k_bgemm(
    const bf16* __restrict__ A, const bf16* __restrict__ Wt,
    const float* __restrict__ bias, const float* __restrict__ resid,
    float* __restrict__ Cf, bf16* __restrict__ Cb,
    int NM, int M, int N, int K) {
  constexpr int ASZ = BM * 64;
  constexpr int ALINES = BM / 64;
  constexpr int BSTRIDE = ASZ + 8192;
  constexpr int MF = BM / 32;
  __shared__ __align__(16) char smem[3 * BSTRIDE];
  const int tid = threadIdx.x;
  const int l = tid & 63, w = tid >> 6;
  const int wr = w >> 1, wc = w & 1;

  const int nwg = (int)gridDim.x;
  int id = (int)blockIdx.x;
  id = (id & 7) * (nwg >> 3) + (id >> 3);
  int sk = 0;
  if constexpr (KSPL == 2) {
    const int TT = nwg >> 1;
    sk = id / TT;
    id -= sk * TT;
  }
  const int m0 = (id % NM) * BM;
  const int n0 = (id / NM) * 128;
  const int kstart = sk * (K / KSPL);

  const int lane15 = l & 15, lg = l >> 4;

  const int r0 = tid >> 2, p0 = tid & 3;
  const char* aSrc[ALINES];
#pragma unroll
  for (int i = 0; i < ALINES; i++) {
    const int rr = i * 64 + r0;
    aSrc[i] = (const char*)(A + (size_t)(m0 + rr) * K + kstart) + ((p0 ^ CFUN(rr)) * 16);
  }
  const char* bSrc0 = (const char*)(Wt + (size_t)(n0 + r0) * K + kstart) + ((p0 ^ CFUN(r0)) * 16);
  const char* bSrc1 = (const char*)(Wt + (size_t)(n0 + 64 + r0) * K + kstart) + ((p0 ^ CFUN(64 + r0)) * 16);

  int aOff[MF], bOff[4];
#pragma unroll
  for (int mi = 0; mi < MF; mi++) {
    int r = wr * (BM / 2) + mi * 16 + lane15;
    aOff[mi] = r * 64 + ((lg ^ CFUN(r)) * 16);
  }
#pragma unroll
  for (int ni = 0; ni < 4; ni++) {
    int r = wc * 64 + ni * 16 + lane15;
    bOff[ni] = ASZ + r * 64 + ((lg ^ CFUN(r)) * 16);
  }

  f32x4 acc[MF][4];
#pragma unroll
  for (int mi = 0; mi < MF; mi++)
#pragma unroll
    for (int ni = 0; ni < 4; ni++) acc[mi][ni] = (f32x4){0.f, 0.f, 0.f, 0.f};

  auto stage = [&](int buf, int t) {
    const size_t kb = (size_t)t * 64;
    char* base = smem + buf * BSTRIDE;
#pragma unroll
    for (int i = 0; i < ALINES; i++)
      cp16(base + i * 4096 + w * 1024, aSrc[i] + kb);
    cp16(base + ASZ + w * 1024, bSrc0 + kb);
    cp16(base + ASZ + 4096 + w * 1024, bSrc1 + kb);
  };
  auto compute = [&](int buf) {
    const char* base = smem + buf * BSTRIDE;
    bf16x8 af[MF], bfr[4];
#pragma unroll
    for (int mi = 0; mi < MF; mi++) af[mi] = *(const bf16x8*)(base + aOff[mi]);
#pragma unroll
    for (int ni = 0; ni < 4; ni++) bfr[ni] = *(const bf16x8*)(base + bOff[ni]);
    __builtin_amdgcn_s_setprio(1);
#pragma unroll
    for (int mi = 0; mi < MF; mi++)
#pragma unroll
      for (int ni = 0; ni < 4; ni++)
        acc[mi][ni] = __builtin_amdgcn_mfma_f32_16x16x32_bf16(
            af[mi], bfr[ni], acc[mi][ni], 0, 0, 0);
    __builtin_amdgcn_s_setprio(0);
  };

  const int nk = (K / KSPL) >> 5;
  stage(0, 0);
  stage(1, 1);
  int buf = 0;
  for (int t = 0; t < nk; t++) {
    if (t + 1 < nk) {
      if constexpr (ALINES == 2) asm volatile("s_waitcnt vmcnt(4)" ::: "memory");
      else                       asm volatile("s_waitcnt vmcnt(3)" ::: "memory");
    } else {
      asm volatile("s_waitcnt vmcnt(0)" ::: "memory");
    }
    __builtin_amdgcn_s_barrier();
    if (t + 2 < nk) {
      int nb = buf + 2; if (nb >= 3) nb -= 3;
      stage(nb, t + 2);
    }
    compute(buf);
    buf = (buf == 2) ? 0 : buf + 1;
  }

#pragma unroll
  for (int ni = 0; ni < 4; ni++) {
    const int col = n0 + wc * 64 + ni * 16 + lane15;
    const float bv = bias[col];
#pragma unroll
    for (int mi = 0; mi < MF; mi++) {
      const int rowb = m0 + wr * (BM / 2) + mi * 16 + lg * 4;
      if constexpr (EPI == 7) {
#pragma unroll
        for (int j = 0; j < 4; j++)
          Cf[(size_t)sk * M * N + (size_t)(rowb + j) * N + col] = acc[mi][ni][j];
      } else {
#pragma unroll
        for (int j = 0; j < 4; j++) {
          const int row = rowb + j;
          float v = acc[mi][ni][j] + bv;
          if constexpr (EPI == 1) v += resid[(size_t)row * N + col];
          if constexpr (EPI == 2) {
            v = 0.5f * v * (1.0f + erff(v * 0.70710678118654752f));
            Cb[(size_t)row * N + col] = __float2bfloat16(v);
          } else if constexpr (EPI == 3) {
            Cb[(size_t)row * N + col] = __float2bfloat16(v);
          } else {
            Cf[(size_t)row * N + col] = v;
          }
        }
      }
    }
  }
}

// ------------------------------------------- 8-phase 256x256 GEMM (K=768)
#define HBAR() asm volatile("s_barrier" ::: "memory")
#define MFMA16(AF, BF, MB, NB)                                               \
  do {                                                                       \
    __builtin_amdgcn_s_setprio(1);                                           \
    _Pragma("unroll") for (int mi_ = 0; mi_ < 4; mi_++)                      \
      _Pragma("unroll") for (int ni_ = 0; ni_ < 2; ni_++)                    \
        _Pragma("unroll") for (int ks_ = 0; ks_ < 2; ks_++)                  \
          acc[(MB) + mi_][(NB) + ni_] =                                      \
              __builtin_amdgcn_mfma_f32_16x16x32_bf16(                       \
                  AF[mi_][ks_], BF[ni_][ks_], acc[(MB) + mi_][(NB) + ni_],   \
                  0, 0, 0);                                                  \
    __builtin_amdgcn_s_setprio(0);                                           \
  } while (0)

template <int EPI>
__global__ __launch_bounds__(512, 1) void k_g8(const bf16* __restrict__ A,
    const bf16* __restrict__ Wt, const bf16* __restrict__ Wt2,
    const float* __restrict__ bias, float* __restrict__ Cf,
    bf16* __restrict__ Cb, bf16* __restrict__ Cb2, bf16* __restrict__ Cb3) {
  __shared__ __align__(16) char smem[131072];
  const int tid = threadIdx.x;
  const int l = tid & 63, w = tid >> 6;
  const int wr = w >> 2, wc = w & 3;
  const int lane15 = l & 15, lg = l >> 4;

  const int nwg = (int)gridDim.x;
  int id = (int)blockIdx.x;
  id = (id & 7) * (nwg >> 3) + (id >> 3);
  const int m0 = (id % 8) * 256;
  const int n0 = (id / 8) * 256;

  const bf16* WB = Wt;
  int nb0 = n0;
  if constexpr (EPI == 6) {
    if (n0 >= 3072) { WB = Wt2; nb0 = n0 - 3072; }
  }

  auto issueA = [&](int tile, int hb) {
#pragma unroll
    for (int j = 0; j < 2; j++) {
      const int idx = j * 512 + tid;
      const int rl = idx >> 3, sl = idx & 7;
      const bf16* g = A + (size_t)(m0 + hb + rl) * 768 + tile * 64 +
                      ((sl ^ (rl & 7)) << 3);
      cp16(smem + (tile & 1) * 32768 + hb * 128 + (j * 512 + w * 64) * 16, g);
    }
  };
  auto issueB = [&](int tile, int hb) {
#pragma unroll
    for (int j = 0; j < 2; j++) {
      const int idx = j * 512 + tid;
      const int rl = idx >> 3, sl = idx & 7;
      const bf16* g = WB + (size_t)(nb0 + hb + rl) * 768 + tile * 64 +
                      ((sl ^ (rl & 7)) << 3);
      cp16(smem + 65536 + (tile & 1) * 32768 + hb * 128 + (j * 512 + w * 64) * 16, g);
    }
  };
  auto ldA = [&](int buf, int mi, int ks) {
    const int r = wr * 128 + mi * 16 + lane15;
    return *(const bf16x8*)(smem + buf * 32768 + r * 128 +
                            ((((ks << 2) + lg) ^ (r & 7)) << 4));
  };
  auto ldB = [&](int buf, int ni, int ks) {
    const int r = wc * 64 + ni * 16 + lane15;
    return *(const bf16x8*)(smem + 65536 + buf * 32768 + r * 128 +
                            ((((ks << 2) + lg) ^ (r & 7)) << 4));
  };

  f32x4 acc[8][4];
#pragma unroll
  for (int i = 0; i < 8; i++)
#pragma unroll
    for (int j = 0; j < 4; j++) acc[i][j] = (f32x4){0.f, 0.f, 0.f, 0.f};
  bf16x8 alo[4][2], ahi[4][2], blo[2][2], bhi[2][2];

  issueA(0, 0);  issueA(0, 128);  issueB(0, 0);  issueB(0, 128);
  issueB(1, 0);  issueA(1, 0);    issueB(1, 128);
  asm volatile("s_waitcnt vmcnt(6)" ::: "memory");
  HBAR();

  for (int it = 0; it < 5; ++it) {
    const int Tb = 2 * it + 1, Tn = 2 * it + 2;
#pragma unroll
    for (int mi = 0; mi < 4; mi++) { alo[mi][0] = ldA(0, mi, 0); alo[mi][1] = ldA(0, mi, 1); }
#pragma unroll
    for (int ni = 0; ni < 2; ni++) { blo[ni][0] = ldB(0, ni, 0); blo[ni][1] = ldB(0, ni, 1); }
    issueA(Tb, 128);
    HBAR(); MFMA16(alo, blo, 0, 0); HBAR();
#pragma unroll
    for (int ni = 0; ni < 2; ni++) { bhi[ni][0] = ldB(0, ni + 2, 0); bhi[ni][1] = ldB(0, ni + 2, 1); }
    HBAR(); MFMA16(alo, bhi, 0, 2); HBAR();
#pragma unroll
    for (int mi = 0; mi < 4; mi++) { ahi[mi][0] = ldA(0, mi + 4, 0); ahi[mi][1] = ldA(0, mi + 4, 1); }
    issueB(Tn, 0);
    HBAR(); MFMA16(ahi, bhi, 4, 2); HBAR();
    issueA(Tn, 0);
    issueB(Tn, 128);
    asm volatile("s_waitcnt vmcnt(6)" ::: "memory");
    HBAR(); MFMA16(ahi, blo, 4, 0); HBAR();
#pragma unroll
    for (int mi = 0; mi < 4; mi++) { alo[mi][0] = ldA(1, mi, 0); alo[mi][1] = ldA(1, mi, 1); }
#pragma unroll
    for (int ni = 0; ni < 2; ni++) { blo[ni][0] = ldB(1, ni, 0); blo[ni][1] = ldB(1, ni, 1); }
    issueA(Tn, 128);
    HBAR(); MFMA16(alo, blo, 0, 0); HBAR();
#pragma unroll
    for (int ni = 0; ni < 2; ni++) { bhi[ni][0] = ldB(1, ni + 2, 0); bhi[ni][1] = ldB(1, ni + 2, 1); }
    HBAR(); MFMA16(alo, bhi, 0, 2); HBAR();
#pragma unroll
    for (int mi = 0; mi < 4; mi++) { ahi[mi][0] = ldA(1, mi + 4, 0); ahi[mi][1] = ldA(1, mi + 4, 1); }
    issueB(Tn + 1, 0);
    HBAR(); MFMA16(ahi, bhi, 4, 2); HBAR();
    issueA(Tn + 1, 0);
    issueB(Tn + 1, 128);
    asm volatile("s_waitcnt vmcnt(6)" ::: "memory");
    HBAR(); MFMA16(ahi, blo, 4, 0); HBAR();
  }

  {
#pragma unroll
    for (int mi = 0; mi < 4; mi++) { alo[mi][0] = ldA(0, mi, 0); alo[mi][1] = ldA(0, mi, 1); }
#pragma unroll
    for (int ni = 0; ni < 2; ni++) { blo[ni][0] = ldB(0, ni, 0); blo[ni][1] = ldB(0, ni, 1); }
    issueA(11, 128);
    HBAR(); MFMA16(alo, blo, 0, 0); HBAR();
#pragma unroll
    for (int ni = 0; ni < 2; ni++) { bhi[ni][0] = ldB(0, ni + 2, 0); bhi[ni][1] = ldB(0, ni + 2, 1); }
    HBAR(); MFMA16(alo, bhi, 0, 2); HBAR();
#pragma unroll
    for (int mi = 0; mi < 4; mi++) { ahi[mi][0] = ldA(0, mi + 4, 0); ahi[mi][1] = ldA(0, mi + 4, 1); }
    HBAR(); MFMA16(ahi, bhi, 4, 2); HBAR();
    asm volatile("s_waitcnt vmcnt(0)" ::: "memory");
    HBAR(); MFMA16(ahi, blo, 4, 0); HBAR();
#pragma unroll
    for (int mi = 0; mi < 4; mi++) { alo[mi][0] = ldA(1, mi, 0); alo[mi][1] = ldA(1, mi, 1); }
#pragma unroll
    for (int ni = 0; ni < 2; ni++) { blo[ni][0] = ldB(1, ni, 0); blo[ni][1] = ldB(1, ni, 1); }
    MFMA16(alo, blo, 0, 0);
#pragma unroll
    for (int ni = 0; ni < 2; ni++) { bhi[ni][0] = ldB(1, ni + 2, 0); bhi[ni][1] = ldB(1, ni + 2, 1); }
    MFMA16(alo, bhi, 0, 2);
#pragma unroll
    for (int mi = 0; mi < 4; mi++) { ahi[mi][0] = ldA(1, mi + 4, 0); ahi[mi][1] = ldA(1, mi + 4, 1); }
    MFMA16(ahi, bhi, 4, 2);
    MFMA16(ahi, blo, 4, 0);
  }

  // epilogue
#pragma unroll
  for (int ni = 0; ni < 4; ni++) {
    const int col = n0 + wc * 64 + ni * 16 + lane15;
    const float bv = bias[col];
#pragma unroll
    for (int mi = 0; mi < 8; mi++) {
      const int rowb = m0 + wr * 128 + mi * 16 + lg * 4;
      if constexpr (EPI == 0) {
#pragma unroll
        for (int j = 0; j < 4; j++)
          Cf[(size_t)(rowb + j) * 32000 + col] = acc[mi][ni][j] + bv;
      } else {  // EPI == 6
        if (col < 2304) {
#pragma unroll
          for (int j = 0; j < 4; j++)
            Cb[(size_t)(rowb + j) * 2304 + col] = __float2bfloat16(acc[mi][ni][j] + bv);
        } else if (col < 3072) {
          ushort4 pk;
          pk.x = f2bf(acc[mi][ni][0] + bv);
          pk.y = f2bf(acc[mi][ni][1] + bv);
          pk.z = f2bf(acc[mi][ni][2] + bv);
          pk.w = f2bf(acc[mi][ni][3] + bv);
          const int bq = rowb >> 10, s = rowb & (S_ - 1);
          *reinterpret_cast<ushort4*>(
              (unsigned short*)Cb2 + ((size_t)(bq * 768 + (col - 2304))) * S_ + s) = pk;
        } else {
#pragma unroll
          for (int j = 0; j < 4; j++)
            Cb3[(size_t)(rowb + j) * 1536 + (col - 3072)] =
                __float2bfloat16(acc[mi][ni][j] + bv);
        }
      }
    }
  }
}

// ---------------------------------------------------------------- flash attention
__global__ __launch_bounds__(256) void k_attn(
    const bf16* __restrict__ qkv, const bf16* __restrict__ vT,
    const bf16* __restrict__ memkv, bf16* __restrict__ ctx, int layer) {
  const int bh = blockIdx.x;
  const int b = bh / H_, h = bh % H_;
  const int qt = (int)gridDim.y - 1 - (int)blockIdx.y;   // big q first
  const int tid = threadIdx.x;
  const int w = tid >> 6, l = tid & 63;
  const int lane15 = l & 15, lg = l >> 4;
  const float inv = 0.125f;

  __shared__ char plds[4][2048];
  __shared__ float wlp[4][16][16];
  char* pl = plds[w];

  const int qrow0 = qt * 64 + w * 16;
  const size_t rowA = (size_t)(b * S_ + qrow0 + lane15);
  const bf16* qp = qkv + rowA * 2304 + h * 64 + lg * 8;
  auto scale8 = [](bf16x8 v) {
    bf16x8 r;
#pragma unroll
    for (int e = 0; e < 8; e++)
      r[e] = (short)f2bf(bf2f((unsigned short)v[e]) * 0.125f);
    return r;
  };
  const bf16x8 qf0 = scale8(*(const bf16x8*)(qp));
  const bf16x8 qf1 = scale8(*(const bf16x8*)(qp + 32));

  const bf16* kbase = qkv + (size_t)(b * S_) * 2304 + 768 + h * 64 + lg * 8;
  const bf16* vbase = vT + ((size_t)(b * 768 + h * 64 + lane15)) * S_;

  float mrow[4], dsum[4];
  f32x4 acc[4];
#pragma unroll
  for (int j = 0; j < 4; j++) { mrow[j] = -INFINITY; dsum[j] = 0.f; }
#pragma unroll
  for (int ni = 0; ni < 4; ni++) acc[ni] = (f32x4){0.f, 0.f, 0.f, 0.f};

  const int ntile = ((qrow0 + 15) >> 6) + 1;
  for (int kt64 = 0; kt64 < ntile; kt64++) {
    const int k0 = kt64 * 64;
    f32x4 sc[4];
#pragma unroll
    for (int kt = 0; kt < 4; kt++) {
      const bf16* kp = kbase + (size_t)(k0 + kt * 16 + lane15) * 2304;
      bf16x8 kf0 = *(const bf16x8*)(kp);
      bf16x8 kf1 = *(const bf16x8*)(kp + 32);
      f32x4 z = (f32x4){0.f, 0.f, 0.f, 0.f};
      z = __builtin_amdgcn_mfma_f32_16x16x32_bf16(qf0, kf0, z, 0, 0, 0);
      sc[kt] = __builtin_amdgcn_mfma_f32_16x16x32_bf16(qf1, kf1, z, 0, 0, 0);
    }
    float tmax[4];
#pragma unroll
    for (int j = 0; j < 4; j++) tmax[j] = -INFINITY;
    const bool needMask = (k0 + 63 > qrow0);
    if (needMask) {
#pragma unroll
      for (int kt = 0; kt < 4; kt++) {
        const int kabs = k0 + kt * 16 + lane15;
#pragma unroll
        for (int j = 0; j < 4; j++) {
          const int qabs = qrow0 + lg * 4 + j;
          float v = (kabs <= qabs) ? sc[kt][j] : -INFINITY;
          sc[kt][j] = v;
          tmax[j] = fmaxf(tmax[j], v);
        }
      }
    } else {
#pragma unroll
      for (int kt = 0; kt < 4; kt++)
#pragma unroll
        for (int j = 0; j < 4; j++) tmax[j] = fmaxf(tmax[j], sc[kt][j]);
    }
#pragma unroll
    for (int off = 1; off < 16; off <<= 1)
#pragma unroll
      for (int j = 0; j < 4; j++) tmax[j] = fmaxf(tmax[j], __shfl_xor(tmax[j], off, 16));

    bool grow = false;
#pragma unroll
    for (int j = 0; j < 4; j++) grow |= (tmax[j] > mrow[j]);
    if (__ballot(grow) != 0ull) {
#pragma unroll
      for (int j = 0; j < 4; j++) {
        const float mnew = fmaxf(mrow[j], tmax[j]);
        const float alpha = __expf(mrow[j] - mnew);
        mrow[j] = mnew;
        dsum[j] *= alpha;
#pragma unroll
        for (int ni = 0; ni < 4; ni++) acc[ni][j] *= alpha;
      }
    }
    float psum[4] = {0.f, 0.f, 0.f, 0.f};
#pragma unroll
    for (int kt = 0; kt < 4; kt++) {
      const int gsl = kt * 2 + (lane15 >> 3);
      const int ebyte = (lane15 & 7) * 2;
#pragma unroll
      for (int j = 0; j < 4; j++) {
        const float p = __expf(sc[kt][j] - mrow[j]);
        psum[j] += p;
        const int r = lg * 4 + j;
        *(unsigned short*)(pl + r * 128 + ((gsl ^ (r & 7)) << 4) + ebyte) = f2bf(p);
      }
    }
#pragma unroll
    for (int off = 1; off < 16; off <<= 1)
#pragma unroll
      for (int j = 0; j < 4; j++) psum[j] += __shfl_xor(psum[j], off, 16);
#pragma unroll
    for (int j = 0; j < 4; j++) dsum[j] += psum[j];

#pragma unroll
    for (int ks = 0; ks < 2; ks++) {
      bf16x8 pa = *(const bf16x8*)(pl + lane15 * 128 +
                                   ((((ks << 2) + lg) ^ (lane15 & 7)) << 4));
      const bf16* vp = vbase + k0 + ks * 32 + lg * 8;
#pragma unroll
      for (int ni = 0; ni < 4; ni++) {
        bf16x8 vf = *(const bf16x8*)(vp + (size_t)ni * 16 * S_);
        acc[ni] = __builtin_amdgcn_mfma_f32_16x16x32_bf16(pa, vf, acc[ni], 0, 0, 0);
      }
    }
  }

  const int r4 = lg * 4;
  if (lane15 < layer) {
    const int ml = lane15;
#pragma unroll
    for (int j = 0; j < 4; j++) {
      const size_t rowB = (size_t)(b * S_) + qrow0 + r4 + j;
      const bf16* qc = qkv + rowB * 2304 + 1536 + h * 64;
      const bf16* mk = memkv + ((size_t)ml * BS_ + rowB) * 1536 + h * 64;
      float d_ = 0.f;
#pragma unroll
      for (int t = 0; t < 8; t++) {
        bf16x8 qv = *(const bf16x8*)(qc + t * 8);
        bf16x8 kv = *(const bf16x8*)(mk + t * 8);
#pragma unroll
        for (int e = 0; e < 8; e++)
          d_ += bf2f((unsigned short)qv[e]) * bf2f((unsigned short)kv[e]);
      }
      wlp[w][r4 + j][ml] = d_ * inv;
    }
  }
  if (layer > 0) {
#pragma unroll
    for (int j = 0; j < 4; j++) {
      const int r = r4 + j;
      float mm = -INFINITY;
      for (int ml = 0; ml < layer; ml++) mm = fmaxf(mm, wlp[w][r][ml]);
      const float mnew = fmaxf(mrow[j], mm);
      const float alpha = __expf(mrow[j] - mnew);
      mrow[j] = mnew;
      dsum[j] *= alpha;
#pragma unroll
      for (int ni = 0; ni < 4; ni++) acc[ni][j] *= alpha;
      const size_t rowB = (size_t)(b * S_) + qrow0 + r;
      for (int ml = 0; ml < layer; ml++) {
        const float p = __expf(wlp[w][r][ml] - mnew);
        dsum[j] += p;
        const unsigned short* mv = (const unsigned short*)(memkv +
            ((size_t)ml * BS_ + rowB) * 1536 + 768 + h * 64 + lane15);
#pragma unroll
        for (int ni = 0; ni < 4; ni++)
          acc[ni][j] += p * bf2f(mv[ni * 16]);
      }
    }
  }

#pragma unroll
  for (int j = 0; j < 4; j++) {
    const float rd = 1.f / dsum[j];
    const size_t rowB = (size_t)(b * S_) + qrow0 + r4 + j;
    bf16* cp = ctx + rowB * 768 + h * 64 + lane15;
#pragma unroll
    for (int ni = 0; ni < 4; ni++)
      cp[ni * 16] = __float2bfloat16(acc[ni][j] * rd);
  }
}

// ---------------------------------------------------------------- launch
extern "C" void kernel_launch(void* const* d_in, const int* in_sizes, int n_in,
                              void* d_out, int out_size, void* d_ws, size_t ws_size,
                              hipStream_t stream) {
  const int*   tokens  = (const int*)d_in[0];
  const float* tok_emb = (const float*)d_in[1];
  const float* pos_emb = (const float*)d_in[2];
  const float *Wq_row, *Wk_row, *Wv_row, *Wq_col, *Wo;
  const float *bq_row, *bk_row, *bv_row, *bq_col, *bo;
  if (in_sizes[4] == L_ * D_ * D_) {  // dict order
    Wq_row = (const float*)d_in[3];  Wk_row = (const float*)d_in[4];
    Wv_row = (const float*)d_in[5];  Wq_col = (const float*)d_in[6];
    Wo     = (const float*)d_in[7];
    bq_row = (const float*)d_in[8];  bk_row = (const float*)d_in[9];
    bv_row = (const float*)d_in[10]; bq_col = (const float*)d_in[11];
    bo     = (const float*)d_in[12];
  } else {  // signature order fallback
    Wq_row = (const float*)d_in[3];  bq_row = (const float*)d_in[4];
    Wk_row = (const float*)d_in[5];  bk_row = (const float*)d_in[6];
    Wv_row = (const float*)d_in[7];  bv_row = (const float*)d_in[8];
    Wq_col = (const float*)d_in[9];  bq_col = (const float*)d_in[10];
    Wo     = (const float*)d_in[11]; bo     = (const float*)d_in[12];
  }
  const float* ln1_g = (const float*)d_in[13]; const float* ln1_b = (const float*)d_in[14];
  const float* ln2_g = (const float*)d_in[15]; const float* ln2_b = (const float*)d_in[16];
  const float* W1    = (const float*)d_in[17]; const float* b1    = (const float*)d_in[18];
  const float* W2    = (const float*)d_in[19]; const float* b2    = (const float*)d_in[20];
  const float* Wk_sh = (const float*)d_in[21]; const float* bk_sh = (const float*)d_in[22];
  const float* Wv_sh = (const float*)d_in[23]; const float* bv_sh = (const float*)d_in[24];
  const float* lnf_g = (const float*)d_in[25]; const float* lnf_b = (const float*)d_in[26];
  const float* Whead = (const float*)d_in[27]; const float* bhead = (const float*)d_in[28];

  // ---- workspace carve-up
  char* p = (char*)d_ws;
  float* x      = (float*)p; p += (size_t)BS_ * D_ * 4;
  bf16*  h_bf   = (bf16*)p;  p += (size_t)BS_ * D_ * 2;
  bf16*  qkv3   = (bf16*)p;  p += (size_t)BS_ * 2304 * 2;
  bf16*  vTb    = (bf16*)p;  p += (size_t)B_ * 768 * S_ * 2;
  bf16*  memkv  = (bf16*)p;  p += (size_t)L_ * BS_ * 1536 * 2;
  bf16*  ctx_bf = (bf16*)p;  p += (size_t)BS_ * D_ * 2;
  bf16*  mlp_bf = (bf16*)p;  p += (size_t)BS_ * DFF_ * 2;
  float* pkbuf  = (float*)p; p += (size_t)2 * BS_ * D_ * 4;   // split-K partials
  float* b6cat  = (float*)p; p += (size_t)L_ * 4608 * 4;
  bf16* tW6    = (bf16*)p; p += (size_t)L_ * 3072 * D_ * 2;   // q|k|qc|v rows
  bf16* tWsh   = (bf16*)p; p += (size_t)1536 * D_ * 2;        // ksh|vsh rows
  bf16* tWo    = (bf16*)p; p += (size_t)L_ * D_ * D_ * 2;
  bf16* tW1    = (bf16*)p; p += (size_t)L_ * DFF_ * D_ * 2;
  bf16* tW2    = (bf16*)p; p += (size_t)L_ * D_ * DFF_ * 2;
  bf16* tWhead = (bf16*)p; p += (size_t)V_ * D_ * 2;

  // ---- single-launch weight conversion + bias concat (64x64 tiles, f4 loads)
  k_wconv<<<dim3(C_BIAS), 256, 0, stream>>>(
      Wq_row, Wk_row, Wq_col, Wv_row, Wk_sh, Wv_sh, Wo, W1, W2, Whead,
      tW6, tWsh, tWo, tW1, tW2, tWhead,
      bq_row, bk_row, bq_col, bv_row, bk_sh, bv_sh, b6cat);

  // fused embed + layer-0 ln1
  k_embedln<<<dim3(BS_), 256, 0, stream>>>(tokens, tok_emb, pos_emb,
                                           ln1_g, ln1_b, x, h_bf);

  const size_t DD = (size_t)D_ * D_;
  const size_t W6S = (size_t)3072 * 768;
  for (int i = 0; i < L_; i++) {
    k_g8<6><<<dim3(144), 512, 0, stream>>>(
        h_bf, tW6 + (size_t)i * W6S, tWsh, b6cat + (size_t)i * 4608,
        nullptr, qkv3, vTb, memkv + (size_t)i * BS_ * 1536);
    k_attn<<<dim3(B_ * H_, S_ / 64), 256, 0, stream>>>(qkv3, vTb, memkv, ctx_bf, i);
    k_bgemm<64, 7, 2><<<dim3(384), 256, 0, stream>>>(
        ctx_bf, tWo + (size_t)i * DD, bo + i * D_,
        nullptr, pkbuf, nullptr, 32, BS_, 768, 768);
    k_redln<<<dim3(BS_), 256, 0, stream>>>(x, pkbuf, bo + i * D_,
                                           ln2_g + i * D_, ln2_b + i * D_, h_bf);
    k_bgemm<128, 2, 1><<<dim3(384), 256, 0, stream>>>(
        h_bf, tW1 + (size_t)i * 3072 * 768, b1 + (size_t)i * DFF_,
        nullptr, nullptr, mlp_bf, 16, BS_, 3072, 768);
    k_bgemm<64, 7, 2><<<dim3(384), 256, 0, stream>>>(
        mlp_bf, tW2 + (size_t)i * 768 * 3072, b2 + i * D_,
        nullptr, pkbuf, nullptr, 32, BS_, 768, 3072);
    const float* gn = (i < L_ - 1) ? (ln1_g + (i + 1) * D_) : lnf_g;
    const float* bn = (i < L_ - 1) ? (ln1_b + (i + 1) * D_) : lnf_b;
    k_redln<<<dim3(BS_), 256, 0, stream>>>(x, pkbuf, b2 + i * D_, gn, bn, h_bf);
  }
  k_g8<0><<<dim3(1000), 512, 0, stream>>>(h_bf, tWhead, nullptr, bhead,
                                          (float*)d_out, nullptr, nullptr, nullptr);
}

// Round 17
// 1559.574 us; speedup vs baseline: 1.3233x; 1.0026x over previous
//
#include <hip/hip_runtime.h>
#include <hip/hip_bf16.h>
#include <math.h>

#define L_   8
#define D_   768
#define H_   12
#define V_   32000
#define B_   2
#define S_   1024
#define HD_  64
#define BS_  2048      // B_*S_
#define DFF_ 3072      // MR*D

typedef __hip_bfloat16 bf16;
typedef __attribute__((ext_vector_type(8))) short bf16x8;
typedef __attribute__((ext_vector_type(4))) float f32x4;

// Balanced LDS slot swizzle for the 128x128 k_bgemm (BK=32, 4-slot rows)
#define CFUN(r) (((r) >> 1) & 3)

__device__ __forceinline__ void cp16(void* lds, const void* g) {
  __builtin_amdgcn_global_load_lds(
      (const __attribute__((address_space(1))) void*)g,
      (__attribute__((address_space(3))) void*)lds, 16, 0, 0);
}

__device__ __forceinline__ unsigned short f2bf(float v) {
  __hip_bfloat16 h = __float2bfloat16(v);
  return *reinterpret_cast<unsigned short*>(&h);
}
__device__ __forceinline__ float bf2f(unsigned short u) {
  return __uint_as_float(((unsigned)u) << 16);
}

// ------------------------------------------- fused embed + layer-0 LN
__global__ __launch_bounds__(256) void k_embedln(const int* __restrict__ tokens,
    const float* __restrict__ tok_emb, const float* __restrict__ pos_emb,
    const float* __restrict__ g, const float* __restrict__ b,
    float* __restrict__ x, bf16* __restrict__ out) {
  const int row = blockIdx.x;
  const int t = threadIdx.x;
  const int s = row & (S_ - 1);
  const int tok = tokens[row];
  const size_t base = (size_t)row * D_;
  const float* te = tok_emb + (size_t)tok * D_;
  const float* pe = pos_emb + (size_t)s * D_;
  float v0 = te[t] + pe[t];
  float v1 = te[t + 256] + pe[t + 256];
  float v2 = te[t + 512] + pe[t + 512];
  x[base + t] = v0; x[base + t + 256] = v1; x[base + t + 512] = v2;
  float sum  = v0 + v1 + v2;
  float s2 = v0 * v0 + v1 * v1 + v2 * v2;
#pragma unroll
  for (int off = 32; off; off >>= 1) {
    sum += __shfl_down(sum, off);
    s2  += __shfl_down(s2, off);
  }
  __shared__ float rs[4], rs2[4];
  __shared__ float mean_s, rstd_s;
  int wid = t >> 6;
  if ((t & 63) == 0) { rs[wid] = sum; rs2[wid] = s2; }
  __syncthreads();
  if (t == 0) {
    float S1 = rs[0] + rs[1] + rs[2] + rs[3];
    float S2 = rs2[0] + rs2[1] + rs2[2] + rs2[3];
    float m  = S1 / D_;
    float var = S2 / D_ - m * m;
    mean_s = m;
    rstd_s = rsqrtf(var + 1e-5f);
  }
  __syncthreads();
  float m = mean_s, r = rstd_s;
  bf16* orow = out + base;
  orow[t]       = __float2bfloat16((v0 - m) * r * g[t]       + b[t]);
  orow[t + 256] = __float2bfloat16((v1 - m) * r * g[t + 256] + b[t + 256]);
  orow[t + 512] = __float2bfloat16((v2 - m) * r * g[t + 512] + b[t + 512]);
}

// -------------------- fused split-K reduce + residual + LN (float4, 192 thr)
__global__ __launch_bounds__(192) void k_redln(float* __restrict__ x,
    const float* __restrict__ pk, const float* __restrict__ b2,
    const float* __restrict__ g, const float* __restrict__ b,
    bf16* __restrict__ out) {
  const int row = blockIdx.x;
  const int t = threadIdx.x;          // 0..191
  const int c = t * 4;
  const size_t base = (size_t)row * D_;
  const size_t MN = (size_t)BS_ * D_;
  float4 xv = *reinterpret_cast<const float4*>(x + base + c);
  float4 p0 = *reinterpret_cast<const float4*>(pk + base + c);
  float4 p1 = *reinterpret_cast<const float4*>(pk + MN + base + c);
  float4 bv = *reinterpret_cast<const float4*>(b2 + c);
  float4 v;
  v.x = xv.x + p0.x + p1.x + bv.x;
  v.y = xv.y + p0.y + p1.y + bv.y;
  v.z = xv.z + p0.z + p1.z + bv.z;
  v.w = xv.w + p0.w + p1.w + bv.w;
  *reinterpret_cast<float4*>(x + base + c) = v;
  float s  = v.x + v.y + v.z + v.w;
  float s2 = v.x * v.x + v.y * v.y + v.z * v.z + v.w * v.w;
#pragma unroll
  for (int off = 32; off; off >>= 1) {
    s  += __shfl_down(s, off);
    s2 += __shfl_down(s2, off);
  }
  __shared__ float rs[3], rs2[3];
  __shared__ float mean_s, rstd_s;
  const int wid = t >> 6;
  if ((t & 63) == 0) { rs[wid] = s; rs2[wid] = s2; }
  __syncthreads();
  if (t == 0) {
    float S1 = rs[0] + rs[1] + rs[2];
    float S2 = rs2[0] + rs2[1] + rs2[2];
    float m  = S1 / D_;
    float var = S2 / D_ - m * m;
    mean_s = m;
    rstd_s = rsqrtf(var + 1e-5f);
  }
  __syncthreads();
  const float m = mean_s, r = rstd_s;
  float4 gv = *reinterpret_cast<const float4*>(g + c);
  float4 bb = *reinterpret_cast<const float4*>(b + c);
  ushort4 o;
  o.x = f2bf((v.x - m) * r * gv.x + bb.x);
  o.y = f2bf((v.y - m) * r * gv.y + bb.y);
  o.z = f2bf((v.z - m) * r * gv.z + bb.z);
  o.w = f2bf((v.w - m) * r * gv.w + bb.w);
  *reinterpret_cast<ushort4*>((unsigned short*)out + base + c) = o;
}

// --------------------------------------- mega-fused weight convert + bias
// 64x64 tiles, float4 loads, LDS transpose, 16-B bf16x8 stores (8 lanes
// cover one full 128-B output row contiguously).
__device__ __forceinline__ void conv_tile64(const float* __restrict__ Wsrc,
    int N, int K, bf16* __restrict__ Wdst, int n0, int k0,
    float (*t)[65], int tid) {
  const int ro = tid >> 4;            // 0..15
  const int cq = (tid & 15) * 4;      // 0..60 step 4
#pragma unroll
  for (int i = 0; i < 4; i++) {
    const int row = i * 16 + ro;
    float4 v = *reinterpret_cast<const float4*>(
        Wsrc + (size_t)(k0 + row) * N + n0 + cq);
    t[row][cq] = v.x; t[row][cq + 1] = v.y;
    t[row][cq + 2] = v.z; t[row][cq + 3] = v.w;
  }
  __syncthreads();
  const int ks = (tid & 7) * 8;       // 0..56 step 8
  const int nn0 = tid >> 3;           // 0..31
#pragma unroll
  for (int pass = 0; pass < 2; pass++) {
    const int n = nn0 + pass * 32;
    bf16x8 ov;
#pragma unroll
    for (int j = 0; j < 8; j++) ov[j] = (short)f2bf(t[ks + j][n]);
    *reinterpret_cast<bf16x8*>(
        (unsigned short*)Wdst + (size_t)(n0 + n) * K + k0 + ks) = ov;
  }
}

#define TILE_DD   144        // 12x12 64-tiles for a 768x768 matrix
#define C_WQ      1152       // 8*144
#define C_WK      2304
#define C_WQC     3456
#define C_WV      4608
#define C_WKSH    4752
#define C_WVSH    4896
#define C_WO      6048
#define C_W1      10656      // + 8*576
#define C_W2      15264      // + 8*576
#define C_WHEAD   21264      // + 6000 (500x12)
#define C_BIAS    21408      // + 144
#define W6S_      ((size_t)3072 * 768)
#define DD_       ((size_t)768 * 768)
#define DF_       ((size_t)768 * 3072)

__global__ __launch_bounds__(256) void k_wconv(
    const float* __restrict__ Wq, const float* __restrict__ Wk,
    const float* __restrict__ Wqc, const float* __restrict__ Wv,
    const float* __restrict__ Wksh, const float* __restrict__ Wvsh,
    const float* __restrict__ Wo, const float* __restrict__ W1,
    const float* __restrict__ W2, const float* __restrict__ Whead,
    bf16* __restrict__ tW6, bf16* __restrict__ tWsh, bf16* __restrict__ tWo,
    bf16* __restrict__ tW1, bf16* __restrict__ tW2, bf16* __restrict__ tWhead,
    const float* __restrict__ bq, const float* __restrict__ bk,
    const float* __restrict__ bqc, const float* __restrict__ bv,
    const float* __restrict__ bksh, const float* __restrict__ bvsh,
    float* __restrict__ b6) {
  __shared__ float t[64][65];
  const int idx = blockIdx.x;
  const int tid = threadIdx.x;

  if (idx < C_WV) {                 // four D x D families -> tW6 sections
    int sect, tt;
    const float* src;
    if (idx < C_WQ)       { sect = 0; tt = idx;          src = Wq;  }
    else if (idx < C_WK)  { sect = 1; tt = idx - C_WQ;   src = Wk;  }
    else if (idx < C_WQC) { sect = 2; tt = idx - C_WK;   src = Wqc; }
    else                  { sect = 3; tt = idx - C_WQC;  src = Wv;  }
    const int z = tt / TILE_DD, rem = tt - z * TILE_DD;
    conv_tile64(src + (size_t)z * DD_, 768, 768,
                tW6 + (size_t)z * W6S_ + (size_t)sect * DD_,
                (rem % 12) * 64, (rem / 12) * 64, t, tid);
  } else if (idx < C_WVSH) {        // shared k/v
    const float* src = (idx < C_WKSH) ? Wksh : Wvsh;
    bf16* dst = (idx < C_WKSH) ? tWsh : (tWsh + DD_);
    const int rem = (idx < C_WKSH) ? (idx - C_WV) : (idx - C_WKSH);
    conv_tile64(src, 768, 768, dst, (rem % 12) * 64, (rem / 12) * 64, t, tid);
  } else if (idx < C_WO) {
    const int tt = idx - C_WVSH;
    const int z = tt / TILE_DD, rem = tt - z * TILE_DD;
    conv_tile64(Wo + (size_t)z * DD_, 768, 768, tWo + (size_t)z * DD_,
                (rem % 12) * 64, (rem / 12) * 64, t, tid);
  } else if (idx < C_W1) {          // W1: [768][3072] -> [3072][768]
    const int tt = idx - C_WO;
    const int z = tt / 576, rem = tt - z * 576;
    conv_tile64(W1 + (size_t)z * DF_, 3072, 768, tW1 + (size_t)z * DF_,
                (rem % 48) * 64, (rem / 48) * 64, t, tid);
  } else if (idx < C_W2) {          // W2: [3072][768] -> [768][3072]
    const int tt = idx - C_W1;
    const int z = tt / 576, rem = tt - z * 576;
    conv_tile64(W2 + (size_t)z * DF_, 768, 3072, tW2 + (size_t)z * DF_,
                (rem % 12) * 64, (rem / 12) * 64, t, tid);
  } else if (idx < C_WHEAD) {       // Whead: [768][32000] -> [32000][768]
    const int tt = idx - C_W2;
    conv_tile64(Whead, 32000, 768, tWhead, (tt % 500) * 64, (tt / 500) * 64,
                t, tid);
  } else {                          // bias concat
    const int i2 = (idx - C_WHEAD) * 256 + tid;
    if (i2 < L_ * 4608) {
      const int l = i2 / 4608, c = i2 - l * 4608;
      float v = (c < 768)  ? bq[l * 768 + c]
              : (c < 1536) ? bk[l * 768 + c - 768]
              : (c < 2304) ? bqc[l * 768 + c - 1536]
              : (c < 3072) ? bv[l * 768 + c - 2304]
              : (c < 3840) ? bksh[c - 3072]
                           : bvsh[c - 3840];
      b6[i2] = v;
    }
  }
}

// ---------------------------------------------------------------- bf16 MFMA GEMM
// (per-layer GEMMs) BMx128 tile, BK=32, 3-buffer counted-vmcnt pipeline.
template <int BM, int EPI, int KSPL>
__global__ __launch_bounds__(256) void k_bgemm(
    const bf16* __restrict__ A, const bf16* __restrict__ Wt,
    const float* __restrict__ bias, const float* __restrict__ resid,
    float* __restrict__ Cf, bf16* __restrict__ Cb,
    int NM, int M, int N, int K) {
  constexpr int ASZ = BM * 64;
  constexpr int ALINES = BM / 64;
  constexpr int BSTRIDE = ASZ + 8192;
  constexpr int MF = BM / 32;
  __shared__ __align__(16) char smem[3 * BSTRIDE];
  const int tid = threadIdx.x;
  const int l = tid & 63, w = tid >> 6;
  const int wr = w >> 1, wc = w & 1;

  const int nwg = (int)gridDim.x;
  int id = (int)blockIdx.x;
  id = (id & 7) * (nwg >> 3) + (id >> 3);
  int sk = 0;
  if constexpr (KSPL == 2) {
    const int TT = nwg >> 1;
    sk = id / TT;
    id -= sk * TT;
  }
  const int m0 = (id % NM) * BM;
  const int n0 = (id / NM) * 128;
  const int kstart = sk * (K / KSPL);

  const int lane15 = l & 15, lg = l >> 4;

  const int r0 = tid >> 2, p0 = tid & 3;
  const char* aSrc[ALINES];
#pragma unroll
  for (int i = 0; i < ALINES; i++) {
    const int rr = i * 64 + r0;
    aSrc[i] = (const char*)(A + (size_t)(m0 + rr) * K + kstart) + ((p0 ^ CFUN(rr)) * 16);
  }
  const char* bSrc0 = (const char*)(Wt + (size_t)(n0 + r0) * K + kstart) + ((p0 ^ CFUN(r0)) * 16);
  const char* bSrc1 = (const char*)(Wt + (size_t)(n0 + 64 + r0) * K + kstart) + ((p0 ^ CFUN(64 + r0)) * 16);

  int aOff[MF], bOff[4];
#pragma unroll
  for (int mi = 0; mi < MF; mi++) {
    int r = wr * (BM / 2) + mi * 16 + lane15;
    aOff[mi] = r * 64 + ((lg ^ CFUN(r)) * 16);
  }
#pragma unroll
  for (int ni = 0; ni < 4; ni++) {
    int r = wc * 64 + ni * 16 + lane15;
    bOff[ni] = ASZ + r * 64 + ((lg ^ CFUN(r)) * 16);
  }

  f32x4 acc[MF][4];
#pragma unroll
  for (int mi = 0; mi < MF; mi++)
#pragma unroll
    for (int ni = 0; ni < 4; ni++) acc[mi][ni] = (f32x4){0.f, 0.f, 0.f, 0.f};

  auto stage = [&](int buf, int t) {
    const size_t kb = (size_t)t * 64;
    char* base = smem + buf * BSTRIDE;
#pragma unroll
    for (int i = 0; i < ALINES; i++)
      cp16(base + i * 4096 + w * 1024, aSrc[i] + kb);
    cp16(base + ASZ + w * 1024, bSrc0 + kb);
    cp16(base + ASZ + 4096 + w * 1024, bSrc1 + kb);
  };
  auto compute = [&](int buf) {
    const char* base = smem + buf * BSTRIDE;
    bf16x8 af[MF], bfr[4];
#pragma unroll
    for (int mi = 0; mi < MF; mi++) af[mi] = *(const bf16x8*)(base + aOff[mi]);
#pragma unroll
    for (int ni = 0; ni < 4; ni++) bfr[ni] = *(const bf16x8*)(base + bOff[ni]);
    __builtin_amdgcn_s_setprio(1);
#pragma unroll
    for (int mi = 0; mi < MF; mi++)
#pragma unroll
      for (int ni = 0; ni < 4; ni++)
        acc[mi][ni] = __builtin_amdgcn_mfma_f32_16x16x32_bf16(
            af[mi], bfr[ni], acc[mi][ni], 0, 0, 0);
    __builtin_amdgcn_s_setprio(0);
  };

  const int nk = (K / KSPL) >> 5;
  stage(0, 0);
  stage(1, 1);
  int buf = 0;
  for (int t = 0; t < nk; t++) {
    if (t + 1 < nk) {
      if constexpr (ALINES == 2) asm volatile("s_waitcnt vmcnt(4)" ::: "memory");
      else                       asm volatile("s_waitcnt vmcnt(3)" ::: "memory");
    } else {
      asm volatile("s_waitcnt vmcnt(0)" ::: "memory");
    }
    __builtin_amdgcn_s_barrier();
    if (t + 2 < nk) {
      int nb = buf + 2; if (nb >= 3) nb -= 3;
      stage(nb, t + 2);
    }
    compute(buf);
    buf = (buf == 2) ? 0 : buf + 1;
  }

#pragma unroll
  for (int ni = 0; ni < 4; ni++) {
    const int col = n0 + wc * 64 + ni * 16 + lane15;
    const float bv = bias[col];
#pragma unroll
    for (int mi = 0; mi < MF; mi++) {
      const int rowb = m0 + wr * (BM / 2) + mi * 16 + lg * 4;
      if constexpr (EPI == 7) {
#pragma unroll
        for (int j = 0; j < 4; j++)
          Cf[(size_t)sk * M * N + (size_t)(rowb + j) * N + col] = acc[mi][ni][j];
      } else {
#pragma unroll
        for (int j = 0; j < 4; j++) {
          const int row = rowb + j;
          float v = acc[mi][ni][j] + bv;
          if constexpr (EPI == 1) v += resid[(size_t)row * N + col];
          if constexpr (EPI == 2) {
            v = 0.5f * v * (1.0f + erff(v * 0.70710678118654752f));
            Cb[(size_t)row * N + col] = __float2bfloat16(v);
          } else if constexpr (EPI == 3) {
            Cb[(size_t)row * N + col] = __float2bfloat16(v);
          } else {
            Cf[(size_t)row * N + col] = v;
          }
        }
      }
    }
  }
}

// ------------------------------------------- 8-phase 256x256 GEMM (K=768)
#define HBAR() asm volatile("s_barrier" ::: "memory")
#define MFMA16(AF, BF, MB, NB)                                               \
  do {                                                                       \
    __builtin_amdgcn_s_setprio(1);                                           \
    _Pragma("unroll") for (int mi_ = 0; mi_ < 4; mi_++)                      \
      _Pragma("unroll") for (int ni_ = 0; ni_ < 2; ni_++)                    \
        _Pragma("unroll") for (int ks_ = 0; ks_ < 2; ks_++)                  \
          acc[(MB) + mi_][(NB) + ni_] =                                      \
              __builtin_amdgcn_mfma_f32_16x16x32_bf16(                       \
                  AF[mi_][ks_], BF[ni_][ks_], acc[(MB) + mi_][(NB) + ni_],   \
                  0, 0, 0);                                                  \
    __builtin_amdgcn_s_setprio(0);                                           \
  } while (0)

template <int EPI>
__global__ __launch_bounds__(512, 1) void k_g8(const bf16* __restrict__ A,
    const bf16* __restrict__ Wt, const bf16* __restrict__ Wt2,
    const float* __restrict__ bias, float* __restrict__ Cf,
    bf16* __restrict__ Cb, bf16* __restrict__ Cb2, bf16* __restrict__ Cb3) {
  __shared__ __align__(16) char smem[131072];
  const int tid = threadIdx.x;
  const int l = tid & 63, w = tid >> 6;
  const int wr = w >> 2, wc = w & 3;
  const int lane15 = l & 15, lg = l >> 4;

  const int nwg = (int)gridDim.x;
  int id = (int)blockIdx.x;
  id = (id & 7) * (nwg >> 3) + (id >> 3);
  const int m0 = (id % 8) * 256;
  const int n0 = (id / 8) * 256;

  const bf16* WB = Wt;
  int nb0 = n0;
  if constexpr (EPI == 6) {
    if (n0 >= 3072) { WB = Wt2; nb0 = n0 - 3072; }
  }

  auto issueA = [&](int tile, int hb) {
#pragma unroll
    for (int j = 0; j < 2; j++) {
      const int idx = j * 512 + tid;
      const int rl = idx >> 3, sl = idx & 7;
      const bf16* g = A + (size_t)(m0 + hb + rl) * 768 + tile * 64 +
                      ((sl ^ (rl & 7)) << 3);
      cp16(smem + (tile & 1) * 32768 + hb * 128 + (j * 512 + w * 64) * 16, g);
    }
  };
  auto issueB = [&](int tile, int hb) {
#pragma unroll
    for (int j = 0; j < 2; j++) {
      const int idx = j * 512 + tid;
      const int rl = idx >> 3, sl = idx & 7;
      const bf16* g = WB + (size_t)(nb0 + hb + rl) * 768 + tile * 64 +
                      ((sl ^ (rl & 7)) << 3);
      cp16(smem + 65536 + (tile & 1) * 32768 + hb * 128 + (j * 512 + w * 64) * 16, g);
    }
  };
  auto ldA = [&](int buf, int mi, int ks) {
    const int r = wr * 128 + mi * 16 + lane15;
    return *(const bf16x8*)(smem + buf * 32768 + r * 128 +
                            ((((ks << 2) + lg) ^ (r & 7)) << 4));
  };
  auto ldB = [&](int buf, int ni, int ks) {
    const int r = wc * 64 + ni * 16 + lane15;
    return *(const bf16x8*)(smem + 65536 + buf * 32768 + r * 128 +
                            ((((ks << 2) + lg) ^ (r & 7)) << 4));
  };

  f32x4 acc[8][4];
#pragma unroll
  for (int i = 0; i < 8; i++)
#pragma unroll
    for (int j = 0; j < 4; j++) acc[i][j] = (f32x4){0.f, 0.f, 0.f, 0.f};
  bf16x8 alo[4][2], ahi[4][2], blo[2][2], bhi[2][2];

  issueA(0, 0);  issueA(0, 128);  issueB(0, 0);  issueB(0, 128);
  issueB(1, 0);  issueA(1, 0);    issueB(1, 128);
  asm volatile("s_waitcnt vmcnt(6)" ::: "memory");
  HBAR();

  for (int it = 0; it < 5; ++it) {
    const int Tb = 2 * it + 1, Tn = 2 * it + 2;
#pragma unroll
    for (int mi = 0; mi < 4; mi++) { alo[mi][0] = ldA(0, mi, 0); alo[mi][1] = ldA(0, mi, 1); }
#pragma unroll
    for (int ni = 0; ni < 2; ni++) { blo[ni][0] = ldB(0, ni, 0); blo[ni][1] = ldB(0, ni, 1); }
    issueA(Tb, 128);
    HBAR(); MFMA16(alo, blo, 0, 0); HBAR();
#pragma unroll
    for (int ni = 0; ni < 2; ni++) { bhi[ni][0] = ldB(0, ni + 2, 0); bhi[ni][1] = ldB(0, ni + 2, 1); }
    HBAR(); MFMA16(alo, bhi, 0, 2); HBAR();
#pragma unroll
    for (int mi = 0; mi < 4; mi++) { ahi[mi][0] = ldA(0, mi + 4, 0); ahi[mi][1] = ldA(0, mi + 4, 1); }
    issueB(Tn, 0);
    HBAR(); MFMA16(ahi, bhi, 4, 2); HBAR();
    issueA(Tn, 0);
    issueB(Tn, 128);
    asm volatile("s_waitcnt vmcnt(6)" ::: "memory");
    HBAR(); MFMA16(ahi, blo, 4, 0); HBAR();
#pragma unroll
    for (int mi = 0; mi < 4; mi++) { alo[mi][0] = ldA(1, mi, 0); alo[mi][1] = ldA(1, mi, 1); }
#pragma unroll
    for (int ni = 0; ni < 2; ni++) { blo[ni][0] = ldB(1, ni, 0); blo[ni][1] = ldB(1, ni, 1); }
    issueA(Tn, 128);
    HBAR(); MFMA16(alo, blo, 0, 0); HBAR();
#pragma unroll
    for (int ni = 0; ni < 2; ni++) { bhi[ni][0] = ldB(1, ni + 2, 0); bhi[ni][1] = ldB(1, ni + 2, 1); }
    HBAR(); MFMA16(alo, bhi, 0, 2); HBAR();
#pragma unroll
    for (int mi = 0; mi < 4; mi++) { ahi[mi][0] = ldA(1, mi + 4, 0); ahi[mi][1] = ldA(1, mi + 4, 1); }
    issueB(Tn + 1, 0);
    HBAR(); MFMA16(ahi, bhi, 4, 2); HBAR();
    issueA(Tn + 1, 0);
    issueB(Tn + 1, 128);
    asm volatile("s_waitcnt vmcnt(6)" ::: "memory");
    HBAR(); MFMA16(ahi, blo, 4, 0); HBAR();
  }

  {
#pragma unroll
    for (int mi = 0; mi < 4; mi++) { alo[mi][0] = ldA(0, mi, 0); alo[mi][1] = ldA(0, mi, 1); }
#pragma unroll
    for (int ni = 0; ni < 2; ni++) { blo[ni][0] = ldB(0, ni, 0); blo[ni][1] = ldB(0, ni, 1); }
    issueA(11, 128);
    HBAR(); MFMA16(alo, blo, 0, 0); HBAR();
#pragma unroll
    for (int ni = 0; ni < 2; ni++) { bhi[ni][0] = ldB(0, ni + 2, 0); bhi[ni][1] = ldB(0, ni + 2, 1); }
    HBAR(); MFMA16(alo, bhi, 0, 2); HBAR();
#pragma unroll
    for (int mi = 0; mi < 4; mi++) { ahi[mi][0] = ldA(0, mi + 4, 0); ahi[mi][1] = ldA(0, mi + 4, 1); }
    HBAR(); MFMA16(ahi, bhi, 4, 2); HBAR();
    asm volatile("s_waitcnt vmcnt(0)" ::: "memory");
    HBAR(); MFMA16(ahi, blo, 4, 0); HBAR();
#pragma unroll
    for (int mi = 0; mi < 4; mi++) { alo[mi][0] = ldA(1, mi, 0); alo[mi][1] = ldA(1, mi, 1); }
#pragma unroll
    for (int ni = 0; ni < 2; ni++) { blo[ni][0] = ldB(1, ni, 0); blo[ni][1] = ldB(1, ni, 1); }
    MFMA16(alo, blo, 0, 0);
#pragma unroll
    for (int ni = 0; ni < 2; ni++) { bhi[ni][0] = ldB(1, ni + 2, 0); bhi[ni][1] = ldB(1, ni + 2, 1); }
    MFMA16(alo, bhi, 0, 2);
#pragma unroll
    for (int mi = 0; mi < 4; mi++) { ahi[mi][0] = ldA(1, mi + 4, 0); ahi[mi][1] = ldA(1, mi + 4, 1); }
    MFMA16(ahi, bhi, 4, 2);
    MFMA16(ahi, blo, 4, 0);
  }

  // epilogue
#pragma unroll
  for (int ni = 0; ni < 4; ni++) {
    const int col = n0 + wc * 64 + ni * 16 + lane15;
    const float bv = bias[col];
#pragma unroll
    for (int mi = 0; mi < 8; mi++) {
      const int rowb = m0 + wr * 128 + mi * 16 + lg * 4;
      if constexpr (EPI == 0) {
#pragma unroll
        for (int j = 0; j < 4; j++)
          Cf[(size_t)(rowb + j) * 32000 + col] = acc[mi][ni][j] + bv;
      } else {  // EPI == 6
        if (col < 2304) {
#pragma unroll
          for (int j = 0; j < 4; j++)
            Cb[(size_t)(rowb + j) * 2304 + col] = __float2bfloat16(acc[mi][ni][j] + bv);
        } else if (col < 3072) {
          ushort4 pk;
          pk.x = f2bf(acc[mi][ni][0] + bv);
          pk.y = f2bf(acc[mi][ni][1] + bv);
          pk.z = f2bf(acc[mi][ni][2] + bv);
          pk.w = f2bf(acc[mi][ni][3] + bv);
          const int bq = rowb >> 10, s = rowb & (S_ - 1);
          *reinterpret_cast<ushort4*>(
              (unsigned short*)Cb2 + ((size_t)(bq * 768 + (col - 2304))) * S_ + s) = pk;
        } else {
#pragma unroll
          for (int j = 0; j < 4; j++)
            Cb3[(size_t)(rowb + j) * 1536 + (col - 3072)] =
                __float2bfloat16(acc[mi][ni][j] + bv);
        }
      }
    }
  }
}

// ---------------------------------------------------------------- flash attention
__global__ __launch_bounds__(256) void k_attn(
    const bf16* __restrict__ qkv, const bf16* __restrict__ vT,
    const bf16* __restrict__ memkv, bf16* __restrict__ ctx, int layer) {
  const int bh = blockIdx.x;
  const int b = bh / H_, h = bh % H_;
  const int qt = (int)gridDim.y - 1 - (int)blockIdx.y;   // big q first
  const int tid = threadIdx.x;
  const int w = tid >> 6, l = tid & 63;
  const int lane15 = l & 15, lg = l >> 4;
  const float inv = 0.125f;

  __shared__ char plds[4][2048];
  __shared__ float wlp[4][16][16];
  char* pl = plds[w];

  const int qrow0 = qt * 64 + w * 16;
  const size_t rowA = (size_t)(b * S_ + qrow0 + lane15);
  const bf16* qp = qkv + rowA * 2304 + h * 64 + lg * 8;
  auto scale8 = [](bf16x8 v) {
    bf16x8 r;
#pragma unroll
    for (int e = 0; e < 8; e++)
      r[e] = (short)f2bf(bf2f((unsigned short)v[e]) * 0.125f);
    return r;
  };
  const bf16x8 qf0 = scale8(*(const bf16x8*)(qp));
  const bf16x8 qf1 = scale8(*(const bf16x8*)(qp + 32));

  const bf16* kbase = qkv + (size_t)(b * S_) * 2304 + 768 + h * 64 + lg * 8;
  const bf16* vbase = vT + ((size_t)(b * 768 + h * 64 + lane15)) * S_;

  float mrow[4], dsum[4];
  f32x4 acc[4];
#pragma unroll
  for (int j = 0; j < 4; j++) { mrow[j] = -INFINITY; dsum[j] = 0.f; }
#pragma unroll
  for (int ni = 0; ni < 4; ni++) acc[ni] = (f32x4){0.f, 0.f, 0.f, 0.f};

  const int ntile = ((qrow0 + 15) >> 6) + 1;
  for (int kt64 = 0; kt64 < ntile; kt64++) {
    const int k0 = kt64 * 64;
    f32x4 sc[4];
#pragma unroll
    for (int kt = 0; kt < 4; kt++) {
      const bf16* kp = kbase + (size_t)(k0 + kt * 16 + lane15) * 2304;
      bf16x8 kf0 = *(const bf16x8*)(kp);
      bf16x8 kf1 = *(const bf16x8*)(kp + 32);
      f32x4 z = (f32x4){0.f, 0.f, 0.f, 0.f};
      z = __builtin_amdgcn_mfma_f32_16x16x32_bf16(qf0, kf0, z, 0, 0, 0);
      sc[kt] = __builtin_amdgcn_mfma_f32_16x16x32_bf16(qf1, kf1, z, 0, 0, 0);
    }
    float tmax[4];
#pragma unroll
    for (int j = 0; j < 4; j++) tmax[j] = -INFINITY;
    const bool needMask = (k0 + 63 > qrow0);
    if (needMask) {
#pragma unroll
      for (int kt = 0; kt < 4; kt++) {
        const int kabs = k0 + kt * 16 + lane15;
#pragma unroll
        for (int j = 0; j < 4; j++) {
          const int qabs = qrow0 + lg * 4 + j;
          float v = (kabs <= qabs) ? sc[kt][j] : -INFINITY;
          sc[kt][j] = v;
          tmax[j] = fmaxf(tmax[j], v);
        }
      }
    } else {
#pragma unroll
      for (int kt = 0; kt < 4; kt++)
#pragma unroll
        for (int j = 0; j < 4; j++) tmax[j] = fmaxf(tmax[j], sc[kt][j]);
    }
#pragma unroll
    for (int off = 1; off < 16; off <<= 1)
#pragma unroll
      for (int j = 0; j < 4; j++) tmax[j] = fmaxf(tmax[j], __shfl_xor(tmax[j], off, 16));

    bool grow = false;
#pragma unroll
    for (int j = 0; j < 4; j++) grow |= (tmax[j] > mrow[j]);
    if (__ballot(grow) != 0ull) {
#pragma unroll
      for (int j = 0; j < 4; j++) {
        const float mnew = fmaxf(mrow[j], tmax[j]);
        const float alpha = __expf(mrow[j] - mnew);
        mrow[j] = mnew;
        dsum[j] *= alpha;
#pragma unroll
        for (int ni = 0; ni < 4; ni++) acc[ni][j] *= alpha;
      }
    }
    float psum[4] = {0.f, 0.f, 0.f, 0.f};
#pragma unroll
    for (int kt = 0; kt < 4; kt++) {
      const int gsl = kt * 2 + (lane15 >> 3);
      const int ebyte = (lane15 & 7) * 2;
#pragma unroll
      for (int j = 0; j < 4; j++) {
        const float p = __expf(sc[kt][j] - mrow[j]);
        psum[j] += p;
        const int r = lg * 4 + j;
        *(unsigned short*)(pl + r * 128 + ((gsl ^ (r & 7)) << 4) + ebyte) = f2bf(p);
      }
    }
#pragma unroll
    for (int off = 1; off < 16; off <<= 1)
#pragma unroll
      for (int j = 0; j < 4; j++) psum[j] += __shfl_xor(psum[j], off, 16);
#pragma unroll
    for (int j = 0; j < 4; j++) dsum[j] += psum[j];

#pragma unroll
    for (int ks = 0; ks < 2; ks++) {
      bf16x8 pa = *(const bf16x8*)(pl + lane15 * 128 +
                                   ((((ks << 2) + lg) ^ (lane15 & 7)) << 4));
      const bf16* vp = vbase + k0 + ks * 32 + lg * 8;
#pragma unroll
      for (int ni = 0; ni < 4; ni++) {
        bf16x8 vf = *(const bf16x8*)(vp + (size_t)ni * 16 * S_);
        acc[ni] = __builtin_amdgcn_mfma_f32_16x16x32_bf16(pa, vf, acc[ni], 0, 0, 0);
      }
    }
  }

  const int r4 = lg * 4;
  if (lane15 < layer) {
    const int ml = lane15;
#pragma unroll
    for (int j = 0; j < 4; j++) {
      const size_t rowB = (size_t)(b * S_) + qrow0 + r4 + j;
      const bf16* qc = qkv + rowB * 2304 + 1536 + h * 64;
      const bf16* mk = memkv + ((size_t)ml * BS_ + rowB) * 1536 + h * 64;
      float d_ = 0.f;
#pragma unroll
      for (int t = 0; t < 8; t++) {
        bf16x8 qv = *(const bf16x8*)(qc + t * 8);
        bf16x8 kv = *(const bf16x8*)(mk + t * 8);
#pragma unroll
        for (int e = 0; e < 8; e++)
          d_ += bf2f((unsigned short)qv[e]) * bf2f((unsigned short)kv[e]);
      }
      wlp[w][r4 + j][ml] = d_ * inv;
    }
  }
  if (layer > 0) {
#pragma unroll
    for (int j = 0; j < 4; j++) {
      const int r = r4 + j;
      float mm = -INFINITY;
      for (int ml = 0; ml < layer; ml++) mm = fmaxf(mm, wlp[w][r][ml]);
      const float mnew = fmaxf(mrow[j], mm);
      const float alpha = __expf(mrow[j] - mnew);
      mrow[j] = mnew;
      dsum[j] *= alpha;
#pragma unroll
      for (int ni = 0; ni < 4; ni++) acc[ni][j] *= alpha;
      const size_t rowB = (size_t)(b * S_) + qrow0 + r;
      for (int ml = 0; ml < layer; ml++) {
        const float p = __expf(wlp[w][r][ml] - mnew);
        dsum[j] += p;
        const unsigned short* mv = (const unsigned short*)(memkv +
            ((size_t)ml * BS_ + rowB) * 1536 + 768 + h * 64 + lane15);
#pragma unroll
        for (int ni = 0; ni < 4; ni++)
          acc[ni][j] += p * bf2f(mv[ni * 16]);
      }
    }
  }

#pragma unroll
  for (int j = 0; j < 4; j++) {
    const float rd = 1.f / dsum[j];
    const size_t rowB = (size_t)(b * S_) + qrow0 + r4 + j;
    bf16* cp = ctx + rowB * 768 + h * 64 + lane15;
#pragma unroll
    for (int ni = 0; ni < 4; ni++)
      cp[ni * 16] = __float2bfloat16(acc[ni][j] * rd);
  }
}

// ---------------------------------------------------------------- launch
extern "C" void kernel_launch(void* const* d_in, const int* in_sizes, int n_in,
                              void* d_out, int out_size, void* d_ws, size_t ws_size,
                              hipStream_t stream) {
  const int*   tokens  = (const int*)d_in[0];
  const float* tok_emb = (const float*)d_in[1];
  const float* pos_emb = (const float*)d_in[2];
  const float *Wq_row, *Wk_row, *Wv_row, *Wq_col, *Wo;
  const float *bq_row, *bk_row, *bv_row, *bq_col, *bo;
  if (in_sizes[4] == L_ * D_ * D_) {  // dict order
    Wq_row = (const float*)d_in[3];  Wk_row = (const float*)d_in[4];
    Wv_row = (const float*)d_in[5];  Wq_col = (const float*)d_in[6];
    Wo     = (const float*)d_in[7];
    bq_row = (const float*)d_in[8];  bk_row = (const float*)d_in[9];
    bv_row = (const float*)d_in[10]; bq_col = (const float*)d_in[11];
    bo     = (const float*)d_in[12];
  } else {  // signature order fallback
    Wq_row = (const float*)d_in[3];  bq_row = (const float*)d_in[4];
    Wk_row = (const float*)d_in[5];  bk_row = (const float*)d_in[6];
    Wv_row = (const float*)d_in[7];  bv_row = (const float*)d_in[8];
    Wq_col = (const float*)d_in[9];  bq_col = (const float*)d_in[10];
    Wo     = (const float*)d_in[11]; bo     = (const float*)d_in[12];
  }
  const float* ln1_g = (const float*)d_in[13]; const float* ln1_b = (const float*)d_in[14];
  const float* ln2_g = (const float*)d_in[15]; const float* ln2_b = (const float*)d_in[16];
  const float* W1    = (const float*)d_in[17]; const float* b1    = (const float*)d_in[18];
  const float* W2    = (const float*)d_in[19]; const float* b2    = (const float*)d_in[20];
  const float* Wk_sh = (const float*)d_in[21]; const float* bk_sh = (const float*)d_in[22];
  const float* Wv_sh = (const float*)d_in[23]; const float* bv_sh = (const float*)d_in[24];
  const float* lnf_g = (const float*)d_in[25]; const float* lnf_b = (const float*)d_in[26];
  const float* Whead = (const float*)d_in[27]; const float* bhead = (const float*)d_in[28];

  // ---- workspace carve-up
  char* p = (char*)d_ws;
  float* x      = (float*)p; p += (size_t)BS_ * D_ * 4;
  bf16*  h_bf   = (bf16*)p;  p += (size_t)BS_ * D_ * 2;
  bf16*  qkv3   = (bf16*)p;  p += (size_t)BS_ * 2304 * 2;
  bf16*  vTb    = (bf16*)p;  p += (size_t)B_ * 768 * S_ * 2;
  bf16*  memkv  = (bf16*)p;  p += (size_t)L_ * BS_ * 1536 * 2;
  bf16*  ctx_bf = (bf16*)p;  p += (size_t)BS_ * D_ * 2;
  bf16*  mlp_bf = (bf16*)p;  p += (size_t)BS_ * DFF_ * 2;
  float* pkbuf  = (float*)p; p += (size_t)2 * BS_ * D_ * 4;   // split-K partials
  float* b6cat  = (float*)p; p += (size_t)L_ * 4608 * 4;
  bf16* tW6    = (bf16*)p; p += (size_t)L_ * 3072 * D_ * 2;   // q|k|qc|v rows
  bf16* tWsh   = (bf16*)p; p += (size_t)1536 * D_ * 2;        // ksh|vsh rows
  bf16* tWo    = (bf16*)p; p += (size_t)L_ * D_ * D_ * 2;
  bf16* tW1    = (bf16*)p; p += (size_t)L_ * DFF_ * D_ * 2;
  bf16* tW2    = (bf16*)p; p += (size_t)L_ * D_ * DFF_ * 2;
  bf16* tWhead = (bf16*)p; p += (size_t)V_ * D_ * 2;

  // ---- single-launch weight conversion + bias concat
  k_wconv<<<dim3(C_BIAS), 256, 0, stream>>>(
      Wq_row, Wk_row, Wq_col, Wv_row, Wk_sh, Wv_sh, Wo, W1, W2, Whead,
      tW6, tWsh, tWo, tW1, tW2, tWhead,
      bq_row, bk_row, bq_col, bv_row, bk_sh, bv_sh, b6cat);

  // fused embed + layer-0 ln1
  k_embedln<<<dim3(BS_), 256, 0, stream>>>(tokens, tok_emb, pos_emb,
                                           ln1_g, ln1_b, x, h_bf);

  const size_t DD = (size_t)D_ * D_;
  const size_t W6S = (size_t)3072 * 768;
  for (int i = 0; i < L_; i++) {
    k_g8<6><<<dim3(144), 512, 0, stream>>>(
        h_bf, tW6 + (size_t)i * W6S, tWsh, b6cat + (size_t)i * 4608,
        nullptr, qkv3, vTb, memkv + (size_t)i * BS_ * 1536);
    k_attn<<<dim3(B_ * H_, S_ / 64), 256, 0, stream>>>(qkv3, vTb, memkv, ctx_bf, i);
    k_bgemm<64, 7, 2><<<dim3(384), 256, 0, stream>>>(
        ctx_bf, tWo + (size_t)i * DD, bo + i * D_,
        nullptr, pkbuf, nullptr, 32, BS_, 768, 768);
    k_redln<<<dim3(BS_), 192, 0, stream>>>(x, pkbuf, bo + i * D_,
                                           ln2_g + i * D_, ln2_b + i * D_, h_bf);
    k_bgemm<128, 2, 1><<<dim3(384), 256, 0, stream>>>(
        h_bf, tW1 + (size_t)i * 3072 * 768, b1 + (size_t)i * DFF_,
        nullptr, nullptr, mlp_bf, 16, BS_, 3072, 768);
    k_bgemm<64, 7, 2><<<dim3(384), 256, 0, stream>>>(
        mlp_bf, tW2 + (size_t)i * 768 * 3072, b2 + i * D_,
        nullptr, pkbuf, nullptr, 32, BS_, 768, 3072);
    const float* gn = (i < L_ - 1) ? (ln1_g + (i + 1) * D_) : lnf_g;
    const float* bn = (i < L_ - 1) ? (ln1_b + (i + 1) * D_) : lnf_b;
    k_redln<<<dim3(BS_), 192, 0, stream>>>(x, pkbuf, b2 + i * D_, gn, bn, h_bf);
  }
  k_g8<0><<<dim3(1000), 512, 0, stream>>>(h_bf, tWhead, nullptr, bhead,
                                          (float*)d_out, nullptr, nullptr, nullptr);
}